// Round 14
// baseline (240.467 us; speedup 1.0000x reference)
//
#include <hip/hip_runtime.h>
#include <cstdint>
#include <cstddef>

#define BB   4
#define AA   256
#define NNB  64
#define FF   128
#define NBAS 20
#define NLAY 3
#define BA   (BB*AA)        // 1024 atoms total
#define EDG  (BA*NNB)       // 65536 edges

typedef __attribute__((ext_vector_type(8))) short bf16x8;
typedef __attribute__((ext_vector_type(4))) float f32x4;

__device__ __forceinline__ float silu_f(float x){ return x / (1.0f + __expf(-x)); }

// round-to-nearest-even f32 -> bf16 bits
__device__ __forceinline__ unsigned short f2bf(float x){
  unsigned int u = __float_as_uint(x);
  u += 0x7FFFu + ((u >> 16) & 1u);
  return (unsigned short)(u >> 16);
}
__device__ __forceinline__ unsigned int pk2(float a, float b){
  return (unsigned int)f2bf(a) | ((unsigned int)f2bf(b) << 16);
}

// ------------- weight conversion: eqf_W1, eqf_W2, eme_W1, eme_W2 (+ padded me_W) ------------
__global__ void k_cvtw(const float* __restrict__ a, const float* __restrict__ b,
                       const float* __restrict__ c, const float* __restrict__ d,
                       const float* __restrict__ me, unsigned short* __restrict__ out){
  int id = blockIdx.x*256 + threadIdx.x;
  if (id < 196608){
    int reg = id / 49152, off = id - reg*49152;
    const float* src = (reg==0)?a:(reg==1)?b:(reg==2)?c:d;
    out[id] = f2bf(src[off]);
  } else if (id < 196608 + 12288){
    int p = id - 196608;
    int l = p >> 12;            // layer
    int rem = p & 4095;
    int row = rem >> 5, k = rem & 31;
    float v = (k < NBAS) ? me[((size_t)l*FF + row)*NBAS + k] : 0.0f;
    out[id] = f2bf(v);
  }
}

// ---------------- f32 two-pass MLP core over 16 rows ----------------
__device__ __forceinline__ void mlp16(const float (*xs)[FF], float (*hs)[FF], int o,
    const float* __restrict__ W1, const float* __restrict__ b1,
    const float* __restrict__ W2, const float* __restrict__ b2, float acc[16]){
  #pragma unroll
  for (int r=0;r<16;++r) acc[r] = b1[o];
  #pragma unroll
  for (int ic=0;ic<4;++ic){
    float4 wv[8];
    #pragma unroll
    for (int j=0;j<8;++j) wv[j] = *reinterpret_cast<const float4*>(&W1[(size_t)o*FF + ic*32 + j*4]);
    #pragma unroll
    for (int r=0;r<16;++r){
      #pragma unroll
      for (int j=0;j<8;++j){
        float4 xv = *reinterpret_cast<const float4*>(&xs[r][ic*32+j*4]);
        acc[r] = fmaf(xv.x, wv[j].x, acc[r]);
        acc[r] = fmaf(xv.y, wv[j].y, acc[r]);
        acc[r] = fmaf(xv.z, wv[j].z, acc[r]);
        acc[r] = fmaf(xv.w, wv[j].w, acc[r]);
      }
    }
  }
  #pragma unroll
  for (int r=0;r<16;++r) hs[r][o] = silu_f(acc[r]);
  __syncthreads();
  #pragma unroll
  for (int r=0;r<16;++r) acc[r] = b2[o];
  #pragma unroll
  for (int ic=0;ic<4;++ic){
    float4 wv[8];
    #pragma unroll
    for (int j=0;j<8;++j) wv[j] = *reinterpret_cast<const float4*>(&W2[(size_t)o*FF + ic*32 + j*4]);
    #pragma unroll
    for (int r=0;r<16;++r){
      #pragma unroll
      for (int j=0;j<8;++j){
        float4 xv = *reinterpret_cast<const float4*>(&hs[r][ic*32+j*4]);
        acc[r] = fmaf(xv.x, wv[j].x, acc[r]);
        acc[r] = fmaf(xv.y, wv[j].y, acc[r]);
        acc[r] = fmaf(xv.z, wv[j].z, acc[r]);
        acc[r] = fmaf(xv.w, wv[j].w, acc[r]);
      }
    }
  }
}

// ------- initial node kernel: emb gather + inv_node write + 3 node MLPs (layer 0) -------
__global__ __launch_bounds__(128) void k_node3_first(
    const int* __restrict__ z, const float* __restrict__ emb, float* __restrict__ inv_node,
    const float* W1a, const float* b1a, const float* W2a, const float* b2a, float* Ya,
    const float* W1b, const float* b1b, const float* W2b, const float* b2b, float* Yb,
    const float* W1c, const float* b1c, const float* W2c, const float* b2c, float* Yc){
  const float *W1,*b1,*W2,*b2; float* Y;
  if (blockIdx.y==0){ W1=W1a;b1=b1a;W2=W2a;b2=b2a;Y=Ya; }
  else if (blockIdx.y==1){ W1=W1b;b1=b1b;W2=W2b;b2=b2b;Y=Yb; }
  else { W1=W1c;b1=b1c;W2=W2c;b2=b2c;Y=Yc; }
  __shared__ __align__(16) float xs[16][FF];
  __shared__ __align__(16) float hs[16][FF];
  const int o = threadIdx.x;
  const int row0 = blockIdx.x * 16;
  #pragma unroll
  for (int r=0;r<16;++r){
    float v = emb[(size_t)z[row0+r]*FF + o];
    xs[r][o] = v;
    if (blockIdx.y==0) inv_node[(size_t)(row0+r)*FF + o] = v;
  }
  __syncthreads();
  float acc[16];
  mlp16(xs, hs, o, W1, b1, W2, b2, acc);
  #pragma unroll
  for (int r=0;r<16;++r) Y[(size_t)(row0+r)*FF + o] = acc[r];
}

// ---------------- three node MLPs in one dispatch (layers 1,2) ----------------
__global__ __launch_bounds__(128) void k_mlp_node3(const float* __restrict__ X,
    const float* W1a, const float* b1a, const float* W2a, const float* b2a, float* Ya,
    const float* W1b, const float* b1b, const float* W2b, const float* b2b, float* Yb,
    const float* W1c, const float* b1c, const float* W2c, const float* b2c, float* Yc){
  const float *W1,*b1,*W2,*b2; float* Y;
  if (blockIdx.y==0){ W1=W1a;b1=b1a;W2=W2a;b2=b2a;Y=Ya; }
  else if (blockIdx.y==1){ W1=W1b;b1=b1b;W2=W2b;b2=b2b;Y=Yb; }
  else { W1=W1c;b1=b1c;W2=W2c;b2=b2c;Y=Yc; }
  __shared__ __align__(16) float xs[16][FF];
  __shared__ __align__(16) float hs[16][FF];
  const int o = threadIdx.x;
  const int row0 = blockIdx.x * 16;
  #pragma unroll
  for (int r=0;r<16;++r) xs[r][o] = X[(size_t)(row0+r)*FF + o];
  __syncthreads();
  float acc[16];
  mlp16(xs, hs, o, W1, b1, W2, b2, acc);
  #pragma unroll
  for (int r=0;r<16;++r) Y[(size_t)(row0+r)*FF + o] = acc[r];
}

// =====================================================================
// k_layer: merged edge pipeline, grid 512, 2 atoms per block.
// W stagings SOFTWARE-PIPELINED: each W prefetched to registers one
// phase ahead (R11-validated mechanism); ds_write-only on critical path.
// =====================================================================
__global__ __launch_bounds__(256) void k_layer(
    const float* __restrict__ dist, const float* __restrict__ dvec,
    const float* __restrict__ maskp, const int* __restrict__ nbrs,
    const float* __restrict__ msg_node,
    const unsigned short* __restrict__ meWb, const float* __restrict__ meb,
    const float* __restrict__ eqcW,
    const unsigned short* __restrict__ W1eq, const float* __restrict__ b1eq,
    const unsigned short* __restrict__ W1me,
    const unsigned short* __restrict__ W2eq, const float* __restrict__ b2eq,
    const unsigned short* __restrict__ W2me,
    unsigned short* __restrict__ H1, unsigned short* __restrict__ H2,
    const float* __restrict__ eqdrT_prev, float* __restrict__ eqdrT_next,
    const float* __restrict__ esu, const float* __restrict__ isu,
    float* __restrict__ eqF, float* __restrict__ eqf_out,
    float* __restrict__ eqdr, float* __restrict__ inv_node, int first){
  __shared__ unsigned short Xs[128*136];      // 34.8 KB (inv_msg, then W stagings)
  __shared__ float scal[128][4];
  __shared__ int   nbq[128];
  __shared__ float eqFred[4][2][3];
  __shared__ float afl1[4][384];
  __shared__ float afl2[4][384];
  __shared__ float prod[2][384];
  const int t = threadIdx.x, w = t>>6, l = t&63;
  const int bid = blockIdx.x, a0 = bid*2;
  const int g = l&15, kg = (l>>4)<<3, r0 = (l>>4)<<2;
  const float c5 = 0.6283185307179586f;      // pi/5

  // ---- prefetch W1eq into registers (latency hides under phase A) ----
  int4 wpre[8];
  #pragma unroll
  for (int i=0;i<8;++i) wpre[i] = *(const int4*)(W1eq + (size_t)(t + i*256)*8);

  if (t < 128){
    int e2 = a0*NNB + t;
    int atomt = a0 + (t>>6);
    nbq[t] = (atomt/AA)*AA + nbrs[e2];
  }

  // ---------------- phase A: geometry + me-MLP + inv_msg -> Xs, scal, eqF ----------------
  #pragma unroll
  for (int p=0;p<2;++p){
    const int atom = a0 + p;
    const int eg = atom*NNB + w*16 + g;
    const float d = dist[eg];
    const float dinv = 1.0f/(d + 1e-8f);
    const float xx = d*0.2f;
    float x2=xx*xx, x4=x2*x2, x6=x4*x2, x7=x6*xx, x8=x7*xx;
    float ct = 1.0f - 28.0f*x6 + 48.0f*x7 - 21.0f*x8;
    ct = (xx < 1.0f) ? ct : 0.0f;
    bf16x8 rfr;
    #pragma unroll
    for (int i=0;i<8;++i){
      int k = kg + i;
      float v = (k < NBAS) ? __sinf((float)(k+1)*c5*d)*dinv : 0.0f;
      rfr[i] = (short)f2bf(v);
    }
    f32x4 acc[8];
    #pragma unroll
    for (int nt=0;nt<8;++nt){
      bf16x8 wfr = *(const bf16x8*)(meWb + (nt*16 + g)*32 + kg);
      acc[nt] = __builtin_amdgcn_mfma_f32_16x16x32_bf16(wfr, rfr, f32x4{0.f,0.f,0.f,0.f}, 0,0,0);
    }
    const int bbase = (atom/AA)*AA;
    const int nbv = bbase + nbrs[eg];
    float pv = 0.f;
    #pragma unroll
    for (int nt=0;nt<8;++nt){
      int o0 = nt*16 + r0;
      float4 mb = *(const float4*)(meb + o0);
      float4 mi = *(const float4*)(msg_node + (size_t)atom*FF + o0);
      float4 mf = *(const float4*)(msg_node + (size_t)nbv*FF + o0);
      float4 ec = *(const float4*)(eqcW + o0);
      float v0 = (acc[nt][0]+mb.x)*ct*mi.x*mf.x;
      float v1 = (acc[nt][1]+mb.y)*ct*mi.y*mf.y;
      float v2 = (acc[nt][2]+mb.z)*ct*mi.z*mf.z;
      float v3 = (acc[nt][3]+mb.w)*ct*mi.w*mf.w;
      pv = fmaf(v0,ec.x, fmaf(v1,ec.y, fmaf(v2,ec.z, fmaf(v3,ec.w, pv))));
      uint2 u; u.x = pk2(v0,v1); u.y = pk2(v2,v3);
      *(uint2*)(&Xs[(p*64 + w*16 + g)*136 + o0]) = u;
    }
    pv += __shfl_xor(pv,16); pv += __shfl_xor(pv,32);
    float cf0=0.f, cf1=0.f, cf2=0.f;
    if (l < 16){
      float m  = maskp[eg];
      float s0 = pv*dvec[(size_t)eg*3+0]*dinv;
      float s1 = pv*dvec[(size_t)eg*3+1]*dinv;
      float s2 = pv*dvec[(size_t)eg*3+2]*dinv;
      int lr = p*64 + w*16 + g;
      scal[lr][0]=s0; scal[lr][1]=s1; scal[lr][2]=s2; scal[lr][3]=m;
      cf0 = s0*m; cf1 = s1*m; cf2 = s2*m;
    }
    #pragma unroll
    for (int s2=1; s2<16; s2<<=1){
      cf0 += __shfl_xor(cf0,s2); cf1 += __shfl_xor(cf1,s2); cf2 += __shfl_xor(cf2,s2);
    }
    if (l == 0){ eqFred[w][p][0]=cf0; eqFred[w][p][1]=cf1; eqFred[w][p][2]=cf2; }
  }
  __syncthreads();                           // (1) Xs/scal complete

  // X fragments -> registers; eq_F final write
  bf16x8 xf[2][4];
  #pragma unroll
  for (int ms=0;ms<2;++ms)
    #pragma unroll
    for (int ks=0;ks<4;++ks)
      xf[ms][ks] = *(const bf16x8*)(&Xs[(w*32 + ms*16 + g)*136 + ks*32 + kg]);
  if (t < 6){
    int p = t/3, c = t - p*3;
    float s = eqFred[0][p][c]+eqFred[1][p][c]+eqFred[2][p][c]+eqFred[3][p][c];
    eqF[(a0+p)*3 + c] = first ? s : (eqF[(a0+p)*3 + c] + s);
  }
  __syncthreads();                           // (2) Xs free

  // ---- write prefetched W1eq -> Xs; issue next prefetch ----
  #pragma unroll
  for (int i=0;i<8;++i){
    int j = t + i*256; int row = j>>4, ko = (j&15)<<3;
    *(int4*)(&Xs[row*136 + ko]) = wpre[i];
  }
  {
    const unsigned short* nxt = first ? W2eq : W1me;
    #pragma unroll
    for (int i=0;i<8;++i) wpre[i] = *(const int4*)(nxt + (size_t)(t + i*256)*8);
  }
  __syncthreads();                           // (3)
  f32x4 acc2[2][8];
  #pragma unroll
  for (int ms=0;ms<2;++ms)
    #pragma unroll
    for (int nt=0;nt<8;++nt) acc2[ms][nt] = f32x4{0.f,0.f,0.f,0.f};
  #pragma unroll
  for (int nt=0;nt<8;++nt)
    #pragma unroll
    for (int ks=0;ks<4;++ks){
      bf16x8 wfr = *(const bf16x8*)(&Xs[(nt*16+g)*136 + ks*32 + kg]);
      #pragma unroll
      for (int ms=0;ms<2;++ms)
        acc2[ms][nt] = __builtin_amdgcn_mfma_f32_16x16x32_bf16(wfr, xf[ms][ks], acc2[ms][nt], 0,0,0);
    }
  #pragma unroll
  for (int ms=0;ms<2;++ms)
    #pragma unroll
    for (int nt=0;nt<8;++nt){
      int o0 = nt*16 + r0;
      float4 bb = *(const float4*)(b1eq + o0);
      uint2 u;
      u.x = pk2(silu_f(acc2[ms][nt][0]+bb.x), silu_f(acc2[ms][nt][1]+bb.y));
      u.y = pk2(silu_f(acc2[ms][nt][2]+bb.z), silu_f(acc2[ms][nt][3]+bb.w));
      *(uint2*)(H1 + (size_t)(bid*128 + w*32 + ms*16 + g)*FF + o0) = u;
    }

  if (!first){
    __syncthreads();                         // (4)
    // ---- write prefetched W1me -> Xs; issue W2eq prefetch ----
    #pragma unroll
    for (int i=0;i<8;++i){
      int j = t + i*256; int row = j>>4, ko = (j&15)<<3;
      *(int4*)(&Xs[row*136 + ko]) = wpre[i];
    }
    #pragma unroll
    for (int i=0;i<8;++i) wpre[i] = *(const int4*)(W2eq + (size_t)(t + i*256)*8);
    __syncthreads();                         // (5)
    #pragma unroll
    for (int ms=0;ms<2;++ms)
      #pragma unroll
      for (int nt=0;nt<8;++nt) acc2[ms][nt] = f32x4{0.f,0.f,0.f,0.f};
    #pragma unroll
    for (int nt=0;nt<8;++nt)
      #pragma unroll
      for (int ks=0;ks<4;++ks){
        bf16x8 wfr = *(const bf16x8*)(&Xs[(nt*16+g)*136 + ks*32 + kg]);
        #pragma unroll
        for (int ms=0;ms<2;++ms)
          acc2[ms][nt] = __builtin_amdgcn_mfma_f32_16x16x32_bf16(wfr, xf[ms][ks], acc2[ms][nt], 0,0,0);
      }
    #pragma unroll
    for (int ms=0;ms<2;++ms)
      #pragma unroll
      for (int nt=0;nt<8;++nt){
        int o0 = nt*16 + r0;
        uint2 u;
        u.x = pk2(silu_f(acc2[ms][nt][0]), silu_f(acc2[ms][nt][1]));
        u.y = pk2(silu_f(acc2[ms][nt][2]), silu_f(acc2[ms][nt][3]));
        *(uint2*)(H2 + (size_t)(bid*128 + w*32 + ms*16 + g)*FF + o0) = u;
      }
  }
  __syncthreads();                           // (6) drains H stores; Xs free

  // ================= GEMM2 half =================
  bf16x8 hfr1[2][4];
  #pragma unroll
  for (int ms=0;ms<2;++ms)
    #pragma unroll
    for (int ks=0;ks<4;++ks)
      hfr1[ms][ks] = *(const bf16x8*)(H1 + (size_t)(bid*128 + w*32 + ms*16 + g)*FF + ks*32 + kg);
  // ---- write prefetched W2eq -> Xs; issue W2me prefetch ----
  #pragma unroll
  for (int i=0;i<8;++i){
    int j = t + i*256; int row = j>>4, ko = (j&15)<<3;
    *(int4*)(&Xs[row*136 + ko]) = wpre[i];
  }
  if (!first){
    #pragma unroll
    for (int i=0;i<8;++i) wpre[i] = *(const int4*)(W2me + (size_t)(t + i*256)*8);
  }
  __syncthreads();                           // (7)
  f32x4 acc[2][8];
  #pragma unroll
  for (int ms=0;ms<2;++ms)
    #pragma unroll
    for (int nt=0;nt<8;++nt) acc[ms][nt] = f32x4{0.f,0.f,0.f,0.f};
  #pragma unroll
  for (int nt=0;nt<8;++nt)
    #pragma unroll
    for (int ks=0;ks<4;++ks){
      bf16x8 wfr = *(const bf16x8*)(&Xs[(nt*16+g)*136 + ks*32 + kg]);
      #pragma unroll
      for (int ms=0;ms<2;++ms)
        acc[ms][nt] = __builtin_amdgcn_mfma_f32_16x16x32_bf16(hfr1[ms][ks], wfr, acc[ms][nt], 0,0,0);
    }
  #pragma unroll
  for (int nt=0;nt<8;++nt){
    int col = nt*16 + g;
    float bb = b2eq[col];
    float q0=0.f,q1=0.f,q2=0.f;
    #pragma unroll
    for (int ms=0;ms<2;++ms)
      #pragma unroll
      for (int r=0;r<4;++r){
        int row = w*32 + ms*16 + r0 + r;
        float ym = (acc[ms][nt][r] + bb) * scal[row][3];
        q0 = fmaf(ym, scal[row][0], q0);
        q1 = fmaf(ym, scal[row][1], q1);
        q2 = fmaf(ym, scal[row][2], q2);
      }
    q0 += __shfl_xor(q0,16); q0 += __shfl_xor(q0,32);
    q1 += __shfl_xor(q1,16); q1 += __shfl_xor(q1,32);
    q2 += __shfl_xor(q2,16); q2 += __shfl_xor(q2,32);
    if (l < 16){
      afl1[w][0*128+col] = q0; afl1[w][1*128+col] = q1; afl1[w][2*128+col] = q2;
    }
  }
  if (!first){
    bf16x8 hfr2[2][4];
    #pragma unroll
    for (int ms=0;ms<2;++ms)
      #pragma unroll
      for (int ks=0;ks<4;++ks)
        hfr2[ms][ks] = *(const bf16x8*)(H2 + (size_t)(bid*128 + w*32 + ms*16 + g)*FF + ks*32 + kg);
    __syncthreads();                         // (8)
    // ---- write prefetched W2me -> Xs ----
    #pragma unroll
    for (int i=0;i<8;++i){
      int j = t + i*256; int row = j>>4, ko = (j&15)<<3;
      *(int4*)(&Xs[row*136 + ko]) = wpre[i];
    }
    __syncthreads();                         // (9)
    #pragma unroll
    for (int ms=0;ms<2;++ms)
      #pragma unroll
      for (int nt=0;nt<8;++nt) acc[ms][nt] = f32x4{0.f,0.f,0.f,0.f};
    #pragma unroll
    for (int nt=0;nt<8;++nt)
      #pragma unroll
      for (int ks=0;ks<4;++ks){
        bf16x8 wfr = *(const bf16x8*)(&Xs[(nt*16+g)*136 + ks*32 + kg]);
        #pragma unroll
        for (int ms=0;ms<2;++ms)
          acc[ms][nt] = __builtin_amdgcn_mfma_f32_16x16x32_bf16(hfr2[ms][ks], wfr, acc[ms][nt], 0,0,0);
      }
    #pragma unroll
    for (int nt=0;nt<8;++nt){
      int col = nt*16 + g;
      float q0=0.f,q1=0.f,q2=0.f;
      #pragma unroll
      for (int ms=0;ms<2;++ms)
        #pragma unroll
        for (int r=0;r<4;++r){
          int row = w*32 + ms*16 + r0 + r;
          float ym = acc[ms][nt][r] * scal[row][3];
          float4 gv = *(const float4*)(eqdrT_prev + ((size_t)nbq[row]*FF + col)*4);
          q0 = fmaf(ym, gv.x, q0);
          q1 = fmaf(ym, gv.y, q1);
          q2 = fmaf(ym, gv.z, q2);
        }
      q0 += __shfl_xor(q0,16); q0 += __shfl_xor(q0,32);
      q1 += __shfl_xor(q1,16); q1 += __shfl_xor(q1,32);
      q2 += __shfl_xor(q2,16); q2 += __shfl_xor(q2,32);
      if (l < 16){
        afl2[w][0*128+col] = q0; afl2[w][1*128+col] = q1; afl2[w][2*128+col] = q2;
      }
    }
  }
  __syncthreads();                           // (10)
  // ---- merged finalize for both atoms (768 elems) ----
  for (int i=t; i<768; i+=256){
    int p = (i >= 384) ? 1 : 0;
    int j = i - p*384;
    int o = j & 127;
    int c = j >> 7;
    float s1 = afl1[2*p][j] + afl1[2*p+1][j];
    float s2 = first ? 0.0f : (afl2[2*p][j] + afl2[2*p+1][j]);
    size_t idx = (size_t)(a0+p)*384 + j;
    float ef = first ? s1 : (eqf_out[idx] + s1);
    eqf_out[idx] = ef;
    float es = esu[(size_t)(a0+p)*FF + o];
    float v = (first ? 0.0f : eqdr[idx]) + s2 + es*s1;
    eqdr[idx] = v;
    eqdrT_next[((size_t)(a0+p)*FF + o)*4 + c] = v;
    prod[p][j] = ef * v;
  }
  __syncthreads();
  {
    int p = t >> 7, o = t & 127;
    float sum3 = prod[p][o] + prod[p][128+o] + prod[p][256+o];
    size_t idx = (size_t)(a0+p)*FF + o;
    inv_node[idx] = fmaf(-isu[idx], sum3, inv_node[idx]);
  }
}

extern "C" void kernel_launch(void* const* d_in, const int* in_sizes, int n_in,
                              void* d_out, int out_size, void* d_ws, size_t ws_size,
                              hipStream_t stream){
  const int*   z     = (const int*)  d_in[0];
  const int*   nbrs  = (const int*)  d_in[2];
  const float* maskp = (const float*)d_in[3];
  const float* dist  = (const float*)d_in[4];
  const float* dvec  = (const float*)d_in[5];
  const float* emb   = (const float*)d_in[6];
  const float* me_W  = (const float*)d_in[7];
  const float* me_b  = (const float*)d_in[8];
  const float* mn_W1 = (const float*)d_in[9];
  const float* mn_b1 = (const float*)d_in[10];
  const float* mn_W2 = (const float*)d_in[11];
  const float* mn_b2 = (const float*)d_in[12];
  const float* eqc_W = (const float*)d_in[13];
  const float* eqf_W1= (const float*)d_in[14];
  const float* eqf_b1= (const float*)d_in[15];
  const float* eqf_W2= (const float*)d_in[16];
  const float* eqf_b2= (const float*)d_in[17];
  const float* esu_W1= (const float*)d_in[18];
  const float* esu_b1= (const float*)d_in[19];
  const float* esu_W2= (const float*)d_in[20];
  const float* esu_b2= (const float*)d_in[21];
  const float* eme_W1= (const float*)d_in[22];
  const float* eme_W2= (const float*)d_in[23];
  const float* isu_W1= (const float*)d_in[24];
  const float* isu_b1= (const float*)d_in[25];
  const float* isu_W2= (const float*)d_in[26];
  const float* isu_b2= (const float*)d_in[27];

  float* out      = (float*)d_out;
  float* inv_node = out;                        // BA*FF   = 131072
  float* eqF      = out + 131072;               // BA*3    = 3072
  float* eqf      = out + 134144;               // BA*3*FF = 393216
  float* eqdr     = out + 527360;               // BA*3*FF = 393216

  // workspace layout (floats)
  float* w        = (float*)d_ws;
  float* msg_node = w;                          //   131,072
  float* esu_o    = w + 131072;                 //   131,072
  float* isu_o    = w + 262144;                 //   131,072
  float* eqdrT_A  = w + 393216;                 //   524,288 (BA*FF*4)
  float* eqdrT_B  = w + 917504;                 //   524,288
  unsigned short* wbf = (unsigned short*)(w + 1441792); // 208,896 us
  unsigned short* H1  = (unsigned short*)(w + 1546240); // EDG*FF us
  unsigned short* H2  = (unsigned short*)(w + 5740544); // EDG*FF us

  k_cvtw<<<817, 256, 0, stream>>>(eqf_W1, eqf_W2, eme_W1, eme_W2, me_W, wbf);
  k_node3_first<<<dim3(BA/16, 3), 128, 0, stream>>>(z, emb, inv_node,
      mn_W1,  mn_b1,  mn_W2,  mn_b2,  msg_node,
      esu_W1, esu_b1, esu_W2, esu_b2, esu_o,
      isu_W1, isu_b1, isu_W2, isu_b2, isu_o);

  for (int l=0; l<NLAY; ++l){
    size_t oB = (size_t)l*FF;
    const unsigned short* eqfW1b = wbf + 0*49152 + l*16384;
    const unsigned short* eqfW2b = wbf + 1*49152 + l*16384;
    const unsigned short* emeW1b = wbf + 2*49152 + l*16384;
    const unsigned short* emeW2b = wbf + 3*49152 + l*16384;
    const unsigned short* meWb   = wbf + 196608  + l*4096;
    float* dT_prev = (l & 1) ? eqdrT_B : eqdrT_A;   // unused at l==0 (first)
    float* dT_next = (l & 1) ? eqdrT_A : eqdrT_B;
    int first = (l==0);

    k_layer<<<BA/2, 256, 0, stream>>>(dist, dvec, maskp, nbrs, msg_node,
        meWb, me_b+oB, eqc_W+oB,
        eqfW1b, eqf_b1+oB, emeW1b,
        eqfW2b, eqf_b2+oB, emeW2b,
        H1, H2, dT_prev, dT_next, esu_o, isu_o,
        eqF, eqf, eqdr, inv_node, first);
    if (l < NLAY-1){
      size_t oWn = (size_t)(l+1)*FF*FF, oBn = (size_t)(l+1)*FF;
      k_mlp_node3<<<dim3(BA/16, 3), 128, 0, stream>>>(inv_node,
          mn_W1+oWn,  mn_b1+oBn,  mn_W2+oWn,  mn_b2+oBn,  msg_node,
          esu_W1+oWn, esu_b1+oBn, esu_W2+oWn, esu_b2+oBn, esu_o,
          isu_W1+oWn, isu_b1+oBn, isu_W2+oWn, isu_b2+oBn, isu_o);
    }
  }
}

// Round 15
// 225.044 us; speedup vs baseline: 1.0685x; 1.0685x over previous
//
#include <hip/hip_runtime.h>
#include <cstdint>
#include <cstddef>

#define BB   4
#define AA   256
#define NNB  64
#define FF   128
#define NBAS 20
#define NLAY 3
#define BA   (BB*AA)        // 1024 atoms total
#define EDG  (BA*NNB)       // 65536 edges

typedef __attribute__((ext_vector_type(8))) short bf16x8;
typedef __attribute__((ext_vector_type(4))) float f32x4;

__device__ __forceinline__ float silu_f(float x){ return x / (1.0f + __expf(-x)); }

// round-to-nearest-even f32 -> bf16 bits
__device__ __forceinline__ unsigned short f2bf(float x){
  unsigned int u = __float_as_uint(x);
  u += 0x7FFFu + ((u >> 16) & 1u);
  return (unsigned short)(u >> 16);
}
__device__ __forceinline__ unsigned int pk2(float a, float b){
  return (unsigned int)f2bf(a) | ((unsigned int)f2bf(b) << 16);
}

// ------------- weight conversion: eqf_W1, eqf_W2, eme_W1, eme_W2 (+ padded me_W) ------------
__global__ void k_cvtw(const float* __restrict__ a, const float* __restrict__ b,
                       const float* __restrict__ c, const float* __restrict__ d,
                       const float* __restrict__ me, unsigned short* __restrict__ out){
  int id = blockIdx.x*256 + threadIdx.x;
  if (id < 196608){
    int reg = id / 49152, off = id - reg*49152;
    const float* src = (reg==0)?a:(reg==1)?b:(reg==2)?c:d;
    out[id] = f2bf(src[off]);
  } else if (id < 196608 + 12288){
    int p = id - 196608;
    int l = p >> 12;            // layer
    int rem = p & 4095;
    int row = rem >> 5, k = rem & 31;
    float v = (k < NBAS) ? me[((size_t)l*FF + row)*NBAS + k] : 0.0f;
    out[id] = f2bf(v);
  }
}

// ---------------- f32 two-pass MLP core over 16 rows ----------------
__device__ __forceinline__ void mlp16(const float (*xs)[FF], float (*hs)[FF], int o,
    const float* __restrict__ W1, const float* __restrict__ b1,
    const float* __restrict__ W2, const float* __restrict__ b2, float acc[16]){
  #pragma unroll
  for (int r=0;r<16;++r) acc[r] = b1[o];
  #pragma unroll
  for (int ic=0;ic<4;++ic){
    float4 wv[8];
    #pragma unroll
    for (int j=0;j<8;++j) wv[j] = *reinterpret_cast<const float4*>(&W1[(size_t)o*FF + ic*32 + j*4]);
    #pragma unroll
    for (int r=0;r<16;++r){
      #pragma unroll
      for (int j=0;j<8;++j){
        float4 xv = *reinterpret_cast<const float4*>(&xs[r][ic*32+j*4]);
        acc[r] = fmaf(xv.x, wv[j].x, acc[r]);
        acc[r] = fmaf(xv.y, wv[j].y, acc[r]);
        acc[r] = fmaf(xv.z, wv[j].z, acc[r]);
        acc[r] = fmaf(xv.w, wv[j].w, acc[r]);
      }
    }
  }
  #pragma unroll
  for (int r=0;r<16;++r) hs[r][o] = silu_f(acc[r]);
  __syncthreads();
  #pragma unroll
  for (int r=0;r<16;++r) acc[r] = b2[o];
  #pragma unroll
  for (int ic=0;ic<4;++ic){
    float4 wv[8];
    #pragma unroll
    for (int j=0;j<8;++j) wv[j] = *reinterpret_cast<const float4*>(&W2[(size_t)o*FF + ic*32 + j*4]);
    #pragma unroll
    for (int r=0;r<16;++r){
      #pragma unroll
      for (int j=0;j<8;++j){
        float4 xv = *reinterpret_cast<const float4*>(&hs[r][ic*32+j*4]);
        acc[r] = fmaf(xv.x, wv[j].x, acc[r]);
        acc[r] = fmaf(xv.y, wv[j].y, acc[r]);
        acc[r] = fmaf(xv.z, wv[j].z, acc[r]);
        acc[r] = fmaf(xv.w, wv[j].w, acc[r]);
      }
    }
  }
}

// ------- initial node kernel: emb gather + inv_node write + 3 node MLPs (layer 0) -------
__global__ __launch_bounds__(128) void k_node3_first(
    const int* __restrict__ z, const float* __restrict__ emb, float* __restrict__ inv_node,
    const float* W1a, const float* b1a, const float* W2a, const float* b2a, float* Ya,
    const float* W1b, const float* b1b, const float* W2b, const float* b2b, float* Yb,
    const float* W1c, const float* b1c, const float* W2c, const float* b2c, float* Yc){
  const float *W1,*b1,*W2,*b2; float* Y;
  if (blockIdx.y==0){ W1=W1a;b1=b1a;W2=W2a;b2=b2a;Y=Ya; }
  else if (blockIdx.y==1){ W1=W1b;b1=b1b;W2=W2b;b2=b2b;Y=Yb; }
  else { W1=W1c;b1=b1c;W2=W2c;b2=b2c;Y=Yc; }
  __shared__ __align__(16) float xs[16][FF];
  __shared__ __align__(16) float hs[16][FF];
  const int o = threadIdx.x;
  const int row0 = blockIdx.x * 16;
  #pragma unroll
  for (int r=0;r<16;++r){
    float v = emb[(size_t)z[row0+r]*FF + o];
    xs[r][o] = v;
    if (blockIdx.y==0) inv_node[(size_t)(row0+r)*FF + o] = v;
  }
  __syncthreads();
  float acc[16];
  mlp16(xs, hs, o, W1, b1, W2, b2, acc);
  #pragma unroll
  for (int r=0;r<16;++r) Y[(size_t)(row0+r)*FF + o] = acc[r];
}

// ---------------- three node MLPs in one dispatch (layers 1,2) ----------------
__global__ __launch_bounds__(128) void k_mlp_node3(const float* __restrict__ X,
    const float* W1a, const float* b1a, const float* W2a, const float* b2a, float* Ya,
    const float* W1b, const float* b1b, const float* W2b, const float* b2b, float* Yb,
    const float* W1c, const float* b1c, const float* W2c, const float* b2c, float* Yc){
  const float *W1,*b1,*W2,*b2; float* Y;
  if (blockIdx.y==0){ W1=W1a;b1=b1a;W2=W2a;b2=b2a;Y=Ya; }
  else if (blockIdx.y==1){ W1=W1b;b1=b1b;W2=W2b;b2=b2b;Y=Yb; }
  else { W1=W1c;b1=b1c;W2=W2c;b2=b2c;Y=Yc; }
  __shared__ __align__(16) float xs[16][FF];
  __shared__ __align__(16) float hs[16][FF];
  const int o = threadIdx.x;
  const int row0 = blockIdx.x * 16;
  #pragma unroll
  for (int r=0;r<16;++r) xs[r][o] = X[(size_t)(row0+r)*FF + o];
  __syncthreads();
  float acc[16];
  mlp16(xs, hs, o, W1, b1, W2, b2, acc);
  #pragma unroll
  for (int r=0;r<16;++r) Y[(size_t)(row0+r)*FF + o] = acc[r];
}

// =====================================================================
// k_layer: merged edge pipeline, grid 512, 2 atoms per block.
// W stagings software-pipelined (reg-prefetch one phase ahead).
// __launch_bounds__(256,2): allow up to ~256 VGPR (2 waves/EU) so the
// prefetch registers do NOT spill (R14's 65 MB scratch-write regression),
// while preserving the required 2 blocks/CU occupancy.
// =====================================================================
__global__ __launch_bounds__(256, 2) void k_layer(
    const float* __restrict__ dist, const float* __restrict__ dvec,
    const float* __restrict__ maskp, const int* __restrict__ nbrs,
    const float* __restrict__ msg_node,
    const unsigned short* __restrict__ meWb, const float* __restrict__ meb,
    const float* __restrict__ eqcW,
    const unsigned short* __restrict__ W1eq, const float* __restrict__ b1eq,
    const unsigned short* __restrict__ W1me,
    const unsigned short* __restrict__ W2eq, const float* __restrict__ b2eq,
    const unsigned short* __restrict__ W2me,
    unsigned short* __restrict__ H1, unsigned short* __restrict__ H2,
    const float* __restrict__ eqdrT_prev, float* __restrict__ eqdrT_next,
    const float* __restrict__ esu, const float* __restrict__ isu,
    float* __restrict__ eqF, float* __restrict__ eqf_out,
    float* __restrict__ eqdr, float* __restrict__ inv_node, int first){
  __shared__ unsigned short Xs[128*136];      // 34.8 KB (inv_msg, then W stagings)
  __shared__ float scal[128][4];
  __shared__ int   nbq[128];
  __shared__ float eqFred[4][2][3];
  __shared__ float afl1[4][384];
  __shared__ float afl2[4][384];
  __shared__ float prod[2][384];
  const int t = threadIdx.x, w = t>>6, l = t&63;
  const int bid = blockIdx.x, a0 = bid*2;
  const int g = l&15, kg = (l>>4)<<3, r0 = (l>>4)<<2;
  const float c5 = 0.6283185307179586f;      // pi/5

  // ---- prefetch W1eq into registers (latency hides under phase A) ----
  int4 wpre[8];
  #pragma unroll
  for (int i=0;i<8;++i) wpre[i] = *(const int4*)(W1eq + (size_t)(t + i*256)*8);

  if (t < 128){
    int e2 = a0*NNB + t;
    int atomt = a0 + (t>>6);
    nbq[t] = (atomt/AA)*AA + nbrs[e2];
  }

  // ---------------- phase A: geometry + me-MLP + inv_msg -> Xs, scal, eqF ----------------
  #pragma unroll
  for (int p=0;p<2;++p){
    const int atom = a0 + p;
    const int eg = atom*NNB + w*16 + g;
    const float d = dist[eg];
    const float dinv = 1.0f/(d + 1e-8f);
    const float xx = d*0.2f;
    float x2=xx*xx, x4=x2*x2, x6=x4*x2, x7=x6*xx, x8=x7*xx;
    float ct = 1.0f - 28.0f*x6 + 48.0f*x7 - 21.0f*x8;
    ct = (xx < 1.0f) ? ct : 0.0f;
    bf16x8 rfr;
    #pragma unroll
    for (int i=0;i<8;++i){
      int k = kg + i;
      float v = (k < NBAS) ? __sinf((float)(k+1)*c5*d)*dinv : 0.0f;
      rfr[i] = (short)f2bf(v);
    }
    f32x4 acc[8];
    #pragma unroll
    for (int nt=0;nt<8;++nt){
      bf16x8 wfr = *(const bf16x8*)(meWb + (nt*16 + g)*32 + kg);
      acc[nt] = __builtin_amdgcn_mfma_f32_16x16x32_bf16(wfr, rfr, f32x4{0.f,0.f,0.f,0.f}, 0,0,0);
    }
    const int bbase = (atom/AA)*AA;
    const int nbv = bbase + nbrs[eg];
    float pv = 0.f;
    #pragma unroll
    for (int nt=0;nt<8;++nt){
      int o0 = nt*16 + r0;
      float4 mb = *(const float4*)(meb + o0);
      float4 mi = *(const float4*)(msg_node + (size_t)atom*FF + o0);
      float4 mf = *(const float4*)(msg_node + (size_t)nbv*FF + o0);
      float4 ec = *(const float4*)(eqcW + o0);
      float v0 = (acc[nt][0]+mb.x)*ct*mi.x*mf.x;
      float v1 = (acc[nt][1]+mb.y)*ct*mi.y*mf.y;
      float v2 = (acc[nt][2]+mb.z)*ct*mi.z*mf.z;
      float v3 = (acc[nt][3]+mb.w)*ct*mi.w*mf.w;
      pv = fmaf(v0,ec.x, fmaf(v1,ec.y, fmaf(v2,ec.z, fmaf(v3,ec.w, pv))));
      uint2 u; u.x = pk2(v0,v1); u.y = pk2(v2,v3);
      *(uint2*)(&Xs[(p*64 + w*16 + g)*136 + o0]) = u;
    }
    pv += __shfl_xor(pv,16); pv += __shfl_xor(pv,32);
    float cf0=0.f, cf1=0.f, cf2=0.f;
    if (l < 16){
      float m  = maskp[eg];
      float s0 = pv*dvec[(size_t)eg*3+0]*dinv;
      float s1 = pv*dvec[(size_t)eg*3+1]*dinv;
      float s2 = pv*dvec[(size_t)eg*3+2]*dinv;
      int lr = p*64 + w*16 + g;
      scal[lr][0]=s0; scal[lr][1]=s1; scal[lr][2]=s2; scal[lr][3]=m;
      cf0 = s0*m; cf1 = s1*m; cf2 = s2*m;
    }
    #pragma unroll
    for (int s2=1; s2<16; s2<<=1){
      cf0 += __shfl_xor(cf0,s2); cf1 += __shfl_xor(cf1,s2); cf2 += __shfl_xor(cf2,s2);
    }
    if (l == 0){ eqFred[w][p][0]=cf0; eqFred[w][p][1]=cf1; eqFred[w][p][2]=cf2; }
  }
  __syncthreads();                           // (1) Xs/scal complete

  // X fragments -> registers; eq_F final write
  bf16x8 xf[2][4];
  #pragma unroll
  for (int ms=0;ms<2;++ms)
    #pragma unroll
    for (int ks=0;ks<4;++ks)
      xf[ms][ks] = *(const bf16x8*)(&Xs[(w*32 + ms*16 + g)*136 + ks*32 + kg]);
  if (t < 6){
    int p = t/3, c = t - p*3;
    float s = eqFred[0][p][c]+eqFred[1][p][c]+eqFred[2][p][c]+eqFred[3][p][c];
    eqF[(a0+p)*3 + c] = first ? s : (eqF[(a0+p)*3 + c] + s);
  }
  __syncthreads();                           // (2) Xs free

  // ---- write prefetched W1eq -> Xs; issue next prefetch ----
  #pragma unroll
  for (int i=0;i<8;++i){
    int j = t + i*256; int row = j>>4, ko = (j&15)<<3;
    *(int4*)(&Xs[row*136 + ko]) = wpre[i];
  }
  {
    const unsigned short* nxt = first ? W2eq : W1me;
    #pragma unroll
    for (int i=0;i<8;++i) wpre[i] = *(const int4*)(nxt + (size_t)(t + i*256)*8);
  }
  __syncthreads();                           // (3)
  f32x4 acc2[2][8];
  #pragma unroll
  for (int ms=0;ms<2;++ms)
    #pragma unroll
    for (int nt=0;nt<8;++nt) acc2[ms][nt] = f32x4{0.f,0.f,0.f,0.f};
  #pragma unroll
  for (int nt=0;nt<8;++nt)
    #pragma unroll
    for (int ks=0;ks<4;++ks){
      bf16x8 wfr = *(const bf16x8*)(&Xs[(nt*16+g)*136 + ks*32 + kg]);
      #pragma unroll
      for (int ms=0;ms<2;++ms)
        acc2[ms][nt] = __builtin_amdgcn_mfma_f32_16x16x32_bf16(wfr, xf[ms][ks], acc2[ms][nt], 0,0,0);
    }
  #pragma unroll
  for (int ms=0;ms<2;++ms)
    #pragma unroll
    for (int nt=0;nt<8;++nt){
      int o0 = nt*16 + r0;
      float4 bb = *(const float4*)(b1eq + o0);
      uint2 u;
      u.x = pk2(silu_f(acc2[ms][nt][0]+bb.x), silu_f(acc2[ms][nt][1]+bb.y));
      u.y = pk2(silu_f(acc2[ms][nt][2]+bb.z), silu_f(acc2[ms][nt][3]+bb.w));
      *(uint2*)(H1 + (size_t)(bid*128 + w*32 + ms*16 + g)*FF + o0) = u;
    }

  if (!first){
    __syncthreads();                         // (4)
    // ---- write prefetched W1me -> Xs; issue W2eq prefetch ----
    #pragma unroll
    for (int i=0;i<8;++i){
      int j = t + i*256; int row = j>>4, ko = (j&15)<<3;
      *(int4*)(&Xs[row*136 + ko]) = wpre[i];
    }
    #pragma unroll
    for (int i=0;i<8;++i) wpre[i] = *(const int4*)(W2eq + (size_t)(t + i*256)*8);
    __syncthreads();                         // (5)
    #pragma unroll
    for (int ms=0;ms<2;++ms)
      #pragma unroll
      for (int nt=0;nt<8;++nt) acc2[ms][nt] = f32x4{0.f,0.f,0.f,0.f};
    #pragma unroll
    for (int nt=0;nt<8;++nt)
      #pragma unroll
      for (int ks=0;ks<4;++ks){
        bf16x8 wfr = *(const bf16x8*)(&Xs[(nt*16+g)*136 + ks*32 + kg]);
        #pragma unroll
        for (int ms=0;ms<2;++ms)
          acc2[ms][nt] = __builtin_amdgcn_mfma_f32_16x16x32_bf16(wfr, xf[ms][ks], acc2[ms][nt], 0,0,0);
      }
    #pragma unroll
    for (int ms=0;ms<2;++ms)
      #pragma unroll
      for (int nt=0;nt<8;++nt){
        int o0 = nt*16 + r0;
        uint2 u;
        u.x = pk2(silu_f(acc2[ms][nt][0]), silu_f(acc2[ms][nt][1]));
        u.y = pk2(silu_f(acc2[ms][nt][2]), silu_f(acc2[ms][nt][3]));
        *(uint2*)(H2 + (size_t)(bid*128 + w*32 + ms*16 + g)*FF + o0) = u;
      }
  }
  __syncthreads();                           // (6) drains H stores; Xs free

  // ================= GEMM2 half =================
  bf16x8 hfr1[2][4];
  #pragma unroll
  for (int ms=0;ms<2;++ms)
    #pragma unroll
    for (int ks=0;ks<4;++ks)
      hfr1[ms][ks] = *(const bf16x8*)(H1 + (size_t)(bid*128 + w*32 + ms*16 + g)*FF + ks*32 + kg);
  // ---- write prefetched W2eq -> Xs; issue W2me prefetch ----
  #pragma unroll
  for (int i=0;i<8;++i){
    int j = t + i*256; int row = j>>4, ko = (j&15)<<3;
    *(int4*)(&Xs[row*136 + ko]) = wpre[i];
  }
  if (!first){
    #pragma unroll
    for (int i=0;i<8;++i) wpre[i] = *(const int4*)(W2me + (size_t)(t + i*256)*8);
  }
  __syncthreads();                           // (7)
  f32x4 acc[2][8];
  #pragma unroll
  for (int ms=0;ms<2;++ms)
    #pragma unroll
    for (int nt=0;nt<8;++nt) acc[ms][nt] = f32x4{0.f,0.f,0.f,0.f};
  #pragma unroll
  for (int nt=0;nt<8;++nt)
    #pragma unroll
    for (int ks=0;ks<4;++ks){
      bf16x8 wfr = *(const bf16x8*)(&Xs[(nt*16+g)*136 + ks*32 + kg]);
      #pragma unroll
      for (int ms=0;ms<2;++ms)
        acc[ms][nt] = __builtin_amdgcn_mfma_f32_16x16x32_bf16(hfr1[ms][ks], wfr, acc[ms][nt], 0,0,0);
    }
  #pragma unroll
  for (int nt=0;nt<8;++nt){
    int col = nt*16 + g;
    float bb = b2eq[col];
    float q0=0.f,q1=0.f,q2=0.f;
    #pragma unroll
    for (int ms=0;ms<2;++ms)
      #pragma unroll
      for (int r=0;r<4;++r){
        int row = w*32 + ms*16 + r0 + r;
        float ym = (acc[ms][nt][r] + bb) * scal[row][3];
        q0 = fmaf(ym, scal[row][0], q0);
        q1 = fmaf(ym, scal[row][1], q1);
        q2 = fmaf(ym, scal[row][2], q2);
      }
    q0 += __shfl_xor(q0,16); q0 += __shfl_xor(q0,32);
    q1 += __shfl_xor(q1,16); q1 += __shfl_xor(q1,32);
    q2 += __shfl_xor(q2,16); q2 += __shfl_xor(q2,32);
    if (l < 16){
      afl1[w][0*128+col] = q0; afl1[w][1*128+col] = q1; afl1[w][2*128+col] = q2;
    }
  }
  if (!first){
    bf16x8 hfr2[2][4];
    #pragma unroll
    for (int ms=0;ms<2;++ms)
      #pragma unroll
      for (int ks=0;ks<4;++ks)
        hfr2[ms][ks] = *(const bf16x8*)(H2 + (size_t)(bid*128 + w*32 + ms*16 + g)*FF + ks*32 + kg);
    __syncthreads();                         // (8)
    // ---- write prefetched W2me -> Xs ----
    #pragma unroll
    for (int i=0;i<8;++i){
      int j = t + i*256; int row = j>>4, ko = (j&15)<<3;
      *(int4*)(&Xs[row*136 + ko]) = wpre[i];
    }
    __syncthreads();                         // (9)
    #pragma unroll
    for (int ms=0;ms<2;++ms)
      #pragma unroll
      for (int nt=0;nt<8;++nt) acc[ms][nt] = f32x4{0.f,0.f,0.f,0.f};
    #pragma unroll
    for (int nt=0;nt<8;++nt)
      #pragma unroll
      for (int ks=0;ks<4;++ks){
        bf16x8 wfr = *(const bf16x8*)(&Xs[(nt*16+g)*136 + ks*32 + kg]);
        #pragma unroll
        for (int ms=0;ms<2;++ms)
          acc[ms][nt] = __builtin_amdgcn_mfma_f32_16x16x32_bf16(hfr2[ms][ks], wfr, acc[ms][nt], 0,0,0);
      }
    #pragma unroll
    for (int nt=0;nt<8;++nt){
      int col = nt*16 + g;
      float q0=0.f,q1=0.f,q2=0.f;
      #pragma unroll
      for (int ms=0;ms<2;++ms)
        #pragma unroll
        for (int r=0;r<4;++r){
          int row = w*32 + ms*16 + r0 + r;
          float ym = acc[ms][nt][r] * scal[row][3];
          float4 gv = *(const float4*)(eqdrT_prev + ((size_t)nbq[row]*FF + col)*4);
          q0 = fmaf(ym, gv.x, q0);
          q1 = fmaf(ym, gv.y, q1);
          q2 = fmaf(ym, gv.z, q2);
        }
      q0 += __shfl_xor(q0,16); q0 += __shfl_xor(q0,32);
      q1 += __shfl_xor(q1,16); q1 += __shfl_xor(q1,32);
      q2 += __shfl_xor(q2,16); q2 += __shfl_xor(q2,32);
      if (l < 16){
        afl2[w][0*128+col] = q0; afl2[w][1*128+col] = q1; afl2[w][2*128+col] = q2;
      }
    }
  }
  __syncthreads();                           // (10)
  // ---- merged finalize for both atoms (768 elems) ----
  for (int i=t; i<768; i+=256){
    int p = (i >= 384) ? 1 : 0;
    int j = i - p*384;
    int o = j & 127;
    int c = j >> 7;
    float s1 = afl1[2*p][j] + afl1[2*p+1][j];
    float s2 = first ? 0.0f : (afl2[2*p][j] + afl2[2*p+1][j]);
    size_t idx = (size_t)(a0+p)*384 + j;
    float ef = first ? s1 : (eqf_out[idx] + s1);
    eqf_out[idx] = ef;
    float es = esu[(size_t)(a0+p)*FF + o];
    float v = (first ? 0.0f : eqdr[idx]) + s2 + es*s1;
    eqdr[idx] = v;
    eqdrT_next[((size_t)(a0+p)*FF + o)*4 + c] = v;
    prod[p][j] = ef * v;
  }
  __syncthreads();
  {
    int p = t >> 7, o = t & 127;
    float sum3 = prod[p][o] + prod[p][128+o] + prod[p][256+o];
    size_t idx = (size_t)(a0+p)*FF + o;
    inv_node[idx] = fmaf(-isu[idx], sum3, inv_node[idx]);
  }
}

extern "C" void kernel_launch(void* const* d_in, const int* in_sizes, int n_in,
                              void* d_out, int out_size, void* d_ws, size_t ws_size,
                              hipStream_t stream){
  const int*   z     = (const int*)  d_in[0];
  const int*   nbrs  = (const int*)  d_in[2];
  const float* maskp = (const float*)d_in[3];
  const float* dist  = (const float*)d_in[4];
  const float* dvec  = (const float*)d_in[5];
  const float* emb   = (const float*)d_in[6];
  const float* me_W  = (const float*)d_in[7];
  const float* me_b  = (const float*)d_in[8];
  const float* mn_W1 = (const float*)d_in[9];
  const float* mn_b1 = (const float*)d_in[10];
  const float* mn_W2 = (const float*)d_in[11];
  const float* mn_b2 = (const float*)d_in[12];
  const float* eqc_W = (const float*)d_in[13];
  const float* eqf_W1= (const float*)d_in[14];
  const float* eqf_b1= (const float*)d_in[15];
  const float* eqf_W2= (const float*)d_in[16];
  const float* eqf_b2= (const float*)d_in[17];
  const float* esu_W1= (const float*)d_in[18];
  const float* esu_b1= (const float*)d_in[19];
  const float* esu_W2= (const float*)d_in[20];
  const float* esu_b2= (const float*)d_in[21];
  const float* eme_W1= (const float*)d_in[22];
  const float* eme_W2= (const float*)d_in[23];
  const float* isu_W1= (const float*)d_in[24];
  const float* isu_b1= (const float*)d_in[25];
  const float* isu_W2= (const float*)d_in[26];
  const float* isu_b2= (const float*)d_in[27];

  float* out      = (float*)d_out;
  float* inv_node = out;                        // BA*FF   = 131072
  float* eqF      = out + 131072;               // BA*3    = 3072
  float* eqf      = out + 134144;               // BA*3*FF = 393216
  float* eqdr     = out + 527360;               // BA*3*FF = 393216

  // workspace layout (floats)
  float* w        = (float*)d_ws;
  float* msg_node = w;                          //   131,072
  float* esu_o    = w + 131072;                 //   131,072
  float* isu_o    = w + 262144;                 //   131,072
  float* eqdrT_A  = w + 393216;                 //   524,288 (BA*FF*4)
  float* eqdrT_B  = w + 917504;                 //   524,288
  unsigned short* wbf = (unsigned short*)(w + 1441792); // 208,896 us
  unsigned short* H1  = (unsigned short*)(w + 1546240); // EDG*FF us
  unsigned short* H2  = (unsigned short*)(w + 5740544); // EDG*FF us

  k_cvtw<<<817, 256, 0, stream>>>(eqf_W1, eqf_W2, eme_W1, eme_W2, me_W, wbf);
  k_node3_first<<<dim3(BA/16, 3), 128, 0, stream>>>(z, emb, inv_node,
      mn_W1,  mn_b1,  mn_W2,  mn_b2,  msg_node,
      esu_W1, esu_b1, esu_W2, esu_b2, esu_o,
      isu_W1, isu_b1, isu_W2, isu_b2, isu_o);

  for (int l=0; l<NLAY; ++l){
    size_t oB = (size_t)l*FF;
    const unsigned short* eqfW1b = wbf + 0*49152 + l*16384;
    const unsigned short* eqfW2b = wbf + 1*49152 + l*16384;
    const unsigned short* emeW1b = wbf + 2*49152 + l*16384;
    const unsigned short* emeW2b = wbf + 3*49152 + l*16384;
    const unsigned short* meWb   = wbf + 196608  + l*4096;
    float* dT_prev = (l & 1) ? eqdrT_B : eqdrT_A;   // unused at l==0 (first)
    float* dT_next = (l & 1) ? eqdrT_A : eqdrT_B;
    int first = (l==0);

    k_layer<<<BA/2, 256, 0, stream>>>(dist, dvec, maskp, nbrs, msg_node,
        meWb, me_b+oB, eqc_W+oB,
        eqfW1b, eqf_b1+oB, emeW1b,
        eqfW2b, eqf_b2+oB, emeW2b,
        H1, H2, dT_prev, dT_next, esu_o, isu_o,
        eqF, eqf, eqdr, inv_node, first);
    if (l < NLAY-1){
      size_t oWn = (size_t)(l+1)*FF*FF, oBn = (size_t)(l+1)*FF;
      k_mlp_node3<<<dim3(BA/16, 3), 128, 0, stream>>>(inv_node,
          mn_W1+oWn,  mn_b1+oBn,  mn_W2+oWn,  mn_b2+oBn,  msg_node,
          esu_W1+oWn, esu_b1+oBn, esu_W2+oWn, esu_b2+oBn, esu_o,
          isu_W1+oWn, isu_b1+oBn, isu_W2+oWn, isu_b2+oBn, isu_o);
    }
  }
}

// Round 16
// 203.919 us; speedup vs baseline: 1.1792x; 1.1036x over previous
//
#include <hip/hip_runtime.h>
#include <cstdint>
#include <cstddef>

#define BB   4
#define AA   256
#define NNB  64
#define FF   128
#define NBAS 20
#define NLAY 3
#define BA   (BB*AA)        // 1024 atoms total
#define EDG  (BA*NNB)       // 65536 edges

typedef __attribute__((ext_vector_type(8))) short bf16x8;
typedef __attribute__((ext_vector_type(4))) float f32x4;

__device__ __forceinline__ float silu_f(float x){ return x / (1.0f + __expf(-x)); }

// round-to-nearest-even f32 -> bf16 bits
__device__ __forceinline__ unsigned short f2bf(float x){
  unsigned int u = __float_as_uint(x);
  u += 0x7FFFu + ((u >> 16) & 1u);
  return (unsigned short)(u >> 16);
}
__device__ __forceinline__ unsigned int pk2(float a, float b){
  return (unsigned int)f2bf(a) | ((unsigned int)f2bf(b) << 16);
}

// ------------- weight conversion: eqf_W1, eqf_W2, eme_W1, eme_W2 (+ padded me_W) ------------
__global__ void k_cvtw(const float* __restrict__ a, const float* __restrict__ b,
                       const float* __restrict__ c, const float* __restrict__ d,
                       const float* __restrict__ me, unsigned short* __restrict__ out){
  int id = blockIdx.x*256 + threadIdx.x;
  if (id < 196608){
    int reg = id / 49152, off = id - reg*49152;
    const float* src = (reg==0)?a:(reg==1)?b:(reg==2)?c:d;
    out[id] = f2bf(src[off]);
  } else if (id < 196608 + 12288){
    int p = id - 196608;
    int l = p >> 12;            // layer
    int rem = p & 4095;
    int row = rem >> 5, k = rem & 31;
    float v = (k < NBAS) ? me[((size_t)l*FF + row)*NBAS + k] : 0.0f;
    out[id] = f2bf(v);
  }
}

// ---------------- f32 two-pass MLP core over 16 rows ----------------
__device__ __forceinline__ void mlp16(const float (*xs)[FF], float (*hs)[FF], int o,
    const float* __restrict__ W1, const float* __restrict__ b1,
    const float* __restrict__ W2, const float* __restrict__ b2, float acc[16]){
  #pragma unroll
  for (int r=0;r<16;++r) acc[r] = b1[o];
  #pragma unroll
  for (int ic=0;ic<4;++ic){
    float4 wv[8];
    #pragma unroll
    for (int j=0;j<8;++j) wv[j] = *reinterpret_cast<const float4*>(&W1[(size_t)o*FF + ic*32 + j*4]);
    #pragma unroll
    for (int r=0;r<16;++r){
      #pragma unroll
      for (int j=0;j<8;++j){
        float4 xv = *reinterpret_cast<const float4*>(&xs[r][ic*32+j*4]);
        acc[r] = fmaf(xv.x, wv[j].x, acc[r]);
        acc[r] = fmaf(xv.y, wv[j].y, acc[r]);
        acc[r] = fmaf(xv.z, wv[j].z, acc[r]);
        acc[r] = fmaf(xv.w, wv[j].w, acc[r]);
      }
    }
  }
  #pragma unroll
  for (int r=0;r<16;++r) hs[r][o] = silu_f(acc[r]);
  __syncthreads();
  #pragma unroll
  for (int r=0;r<16;++r) acc[r] = b2[o];
  #pragma unroll
  for (int ic=0;ic<4;++ic){
    float4 wv[8];
    #pragma unroll
    for (int j=0;j<8;++j) wv[j] = *reinterpret_cast<const float4*>(&W2[(size_t)o*FF + ic*32 + j*4]);
    #pragma unroll
    for (int r=0;r<16;++r){
      #pragma unroll
      for (int j=0;j<8;++j){
        float4 xv = *reinterpret_cast<const float4*>(&hs[r][ic*32+j*4]);
        acc[r] = fmaf(xv.x, wv[j].x, acc[r]);
        acc[r] = fmaf(xv.y, wv[j].y, acc[r]);
        acc[r] = fmaf(xv.z, wv[j].z, acc[r]);
        acc[r] = fmaf(xv.w, wv[j].w, acc[r]);
      }
    }
  }
}

// ------- initial node kernel: emb gather + inv_node write + 3 node MLPs (layer 0) -------
__global__ __launch_bounds__(128) void k_node3_first(
    const int* __restrict__ z, const float* __restrict__ emb, float* __restrict__ inv_node,
    const float* W1a, const float* b1a, const float* W2a, const float* b2a, float* Ya,
    const float* W1b, const float* b1b, const float* W2b, const float* b2b, float* Yb,
    const float* W1c, const float* b1c, const float* W2c, const float* b2c, float* Yc){
  const float *W1,*b1,*W2,*b2; float* Y;
  if (blockIdx.y==0){ W1=W1a;b1=b1a;W2=W2a;b2=b2a;Y=Ya; }
  else if (blockIdx.y==1){ W1=W1b;b1=b1b;W2=W2b;b2=b2b;Y=Yb; }
  else { W1=W1c;b1=b1c;W2=W2c;b2=b2c;Y=Yc; }
  __shared__ __align__(16) float xs[16][FF];
  __shared__ __align__(16) float hs[16][FF];
  const int o = threadIdx.x;
  const int row0 = blockIdx.x * 16;
  #pragma unroll
  for (int r=0;r<16;++r){
    float v = emb[(size_t)z[row0+r]*FF + o];
    xs[r][o] = v;
    if (blockIdx.y==0) inv_node[(size_t)(row0+r)*FF + o] = v;
  }
  __syncthreads();
  float acc[16];
  mlp16(xs, hs, o, W1, b1, W2, b2, acc);
  #pragma unroll
  for (int r=0;r<16;++r) Y[(size_t)(row0+r)*FF + o] = acc[r];
}

// ---------------- three node MLPs in one dispatch (layers 1,2) ----------------
__global__ __launch_bounds__(128) void k_mlp_node3(const float* __restrict__ X,
    const float* W1a, const float* b1a, const float* W2a, const float* b2a, float* Ya,
    const float* W1b, const float* b1b, const float* W2b, const float* b2b, float* Yb,
    const float* W1c, const float* b1c, const float* W2c, const float* b2c, float* Yc){
  const float *W1,*b1,*W2,*b2; float* Y;
  if (blockIdx.y==0){ W1=W1a;b1=b1a;W2=W2a;b2=b2a;Y=Ya; }
  else if (blockIdx.y==1){ W1=W1b;b1=b1b;W2=W2b;b2=b2b;Y=Yb; }
  else { W1=W1c;b1=b1c;W2=W2c;b2=b2c;Y=Yc; }
  __shared__ __align__(16) float xs[16][FF];
  __shared__ __align__(16) float hs[16][FF];
  const int o = threadIdx.x;
  const int row0 = blockIdx.x * 16;
  #pragma unroll
  for (int r=0;r<16;++r) xs[r][o] = X[(size_t)(row0+r)*FF + o];
  __syncthreads();
  float acc[16];
  mlp16(xs, hs, o, W1, b1, W2, b2, acc);
  #pragma unroll
  for (int r=0;r<16;++r) Y[(size_t)(row0+r)*FF + o] = acc[r];
}

// =====================================================================
// k_layer: merged k_edge1 + k_z (R13-proven). Grid 512, 2 atoms per block.
// Plain LDS W stagings (reg-prefetch variants spill -> R14/R15 regressions).
// =====================================================================
__global__ __launch_bounds__(256) void k_layer(
    const float* __restrict__ dist, const float* __restrict__ dvec,
    const float* __restrict__ maskp, const int* __restrict__ nbrs,
    const float* __restrict__ msg_node,
    const unsigned short* __restrict__ meWb, const float* __restrict__ meb,
    const float* __restrict__ eqcW,
    const unsigned short* __restrict__ W1eq, const float* __restrict__ b1eq,
    const unsigned short* __restrict__ W1me,
    const unsigned short* __restrict__ W2eq, const float* __restrict__ b2eq,
    const unsigned short* __restrict__ W2me,
    unsigned short* __restrict__ H1, unsigned short* __restrict__ H2,
    const float* __restrict__ eqdrT_prev, float* __restrict__ eqdrT_next,
    const float* __restrict__ esu, const float* __restrict__ isu,
    float* __restrict__ eqF, float* __restrict__ eqf_out,
    float* __restrict__ eqdr, float* __restrict__ inv_node, int first){
  __shared__ unsigned short Xs[128*136];      // 34.8 KB (inv_msg, then W stagings)
  __shared__ float scal[128][4];
  __shared__ int   nbq[128];
  __shared__ float eqFred[4][2][3];
  __shared__ float afl1[4][384];
  __shared__ float afl2[4][384];
  __shared__ float prod[2][384];
  const int t = threadIdx.x, w = t>>6, l = t&63;
  const int bid = blockIdx.x, a0 = bid*2;
  const int g = l&15, kg = (l>>4)<<3, r0 = (l>>4)<<2;
  const float c5 = 0.6283185307179586f;      // pi/5

  if (t < 128){
    int e2 = a0*NNB + t;
    int atomt = a0 + (t>>6);
    nbq[t] = (atomt/AA)*AA + nbrs[e2];
  }

  // ---------------- phase A: geometry + me-MLP + inv_msg -> Xs, scal, eqF ----------------
  #pragma unroll
  for (int p=0;p<2;++p){
    const int atom = a0 + p;
    const int eg = atom*NNB + w*16 + g;
    const float d = dist[eg];
    const float dinv = 1.0f/(d + 1e-8f);
    const float xx = d*0.2f;
    float x2=xx*xx, x4=x2*x2, x6=x4*x2, x7=x6*xx, x8=x7*xx;
    float ct = 1.0f - 28.0f*x6 + 48.0f*x7 - 21.0f*x8;
    ct = (xx < 1.0f) ? ct : 0.0f;
    bf16x8 rfr;
    #pragma unroll
    for (int i=0;i<8;++i){
      int k = kg + i;
      float v = (k < NBAS) ? __sinf((float)(k+1)*c5*d)*dinv : 0.0f;
      rfr[i] = (short)f2bf(v);
    }
    f32x4 acc[8];
    #pragma unroll
    for (int nt=0;nt<8;++nt){
      bf16x8 wfr = *(const bf16x8*)(meWb + (nt*16 + g)*32 + kg);
      acc[nt] = __builtin_amdgcn_mfma_f32_16x16x32_bf16(wfr, rfr, f32x4{0.f,0.f,0.f,0.f}, 0,0,0);
    }
    const int bbase = (atom/AA)*AA;
    const int nbv = bbase + nbrs[eg];
    float pv = 0.f;
    #pragma unroll
    for (int nt=0;nt<8;++nt){
      int o0 = nt*16 + r0;
      float4 mb = *(const float4*)(meb + o0);
      float4 mi = *(const float4*)(msg_node + (size_t)atom*FF + o0);
      float4 mf = *(const float4*)(msg_node + (size_t)nbv*FF + o0);
      float4 ec = *(const float4*)(eqcW + o0);
      float v0 = (acc[nt][0]+mb.x)*ct*mi.x*mf.x;
      float v1 = (acc[nt][1]+mb.y)*ct*mi.y*mf.y;
      float v2 = (acc[nt][2]+mb.z)*ct*mi.z*mf.z;
      float v3 = (acc[nt][3]+mb.w)*ct*mi.w*mf.w;
      pv = fmaf(v0,ec.x, fmaf(v1,ec.y, fmaf(v2,ec.z, fmaf(v3,ec.w, pv))));
      uint2 u; u.x = pk2(v0,v1); u.y = pk2(v2,v3);
      *(uint2*)(&Xs[(p*64 + w*16 + g)*136 + o0]) = u;
    }
    pv += __shfl_xor(pv,16); pv += __shfl_xor(pv,32);
    float cf0=0.f, cf1=0.f, cf2=0.f;
    if (l < 16){
      float m  = maskp[eg];
      float s0 = pv*dvec[(size_t)eg*3+0]*dinv;
      float s1 = pv*dvec[(size_t)eg*3+1]*dinv;
      float s2 = pv*dvec[(size_t)eg*3+2]*dinv;
      int lr = p*64 + w*16 + g;
      scal[lr][0]=s0; scal[lr][1]=s1; scal[lr][2]=s2; scal[lr][3]=m;
      cf0 = s0*m; cf1 = s1*m; cf2 = s2*m;
    }
    #pragma unroll
    for (int s2=1; s2<16; s2<<=1){
      cf0 += __shfl_xor(cf0,s2); cf1 += __shfl_xor(cf1,s2); cf2 += __shfl_xor(cf2,s2);
    }
    if (l == 0){ eqFred[w][p][0]=cf0; eqFred[w][p][1]=cf1; eqFred[w][p][2]=cf2; }
  }
  __syncthreads();                           // (1) Xs/scal complete

  // X fragments -> registers; eq_F final write
  bf16x8 xf[2][4];
  #pragma unroll
  for (int ms=0;ms<2;++ms)
    #pragma unroll
    for (int ks=0;ks<4;++ks)
      xf[ms][ks] = *(const bf16x8*)(&Xs[(w*32 + ms*16 + g)*136 + ks*32 + kg]);
  if (t < 6){
    int p = t/3, c = t - p*3;
    float s = eqFred[0][p][c]+eqFred[1][p][c]+eqFred[2][p][c]+eqFred[3][p][c];
    eqF[(a0+p)*3 + c] = first ? s : (eqF[(a0+p)*3 + c] + s);
  }
  __syncthreads();                           // (2) Xs free

  // ---- stage W1eq; GEMM1-eqf -> H1 (global write-through) ----
  #pragma unroll
  for (int c=t; c<2048; c+=256){
    int row = c >> 4, ko = (c & 15) << 3;
    *(int4*)(&Xs[row*136 + ko]) = *(const int4*)(W1eq + row*FF + ko);
  }
  __syncthreads();                           // (3)
  f32x4 acc2[2][8];
  #pragma unroll
  for (int ms=0;ms<2;++ms)
    #pragma unroll
    for (int nt=0;nt<8;++nt) acc2[ms][nt] = f32x4{0.f,0.f,0.f,0.f};
  #pragma unroll
  for (int nt=0;nt<8;++nt)
    #pragma unroll
    for (int ks=0;ks<4;++ks){
      bf16x8 wfr = *(const bf16x8*)(&Xs[(nt*16+g)*136 + ks*32 + kg]);
      #pragma unroll
      for (int ms=0;ms<2;++ms)
        acc2[ms][nt] = __builtin_amdgcn_mfma_f32_16x16x32_bf16(wfr, xf[ms][ks], acc2[ms][nt], 0,0,0);
    }
  #pragma unroll
  for (int ms=0;ms<2;++ms)
    #pragma unroll
    for (int nt=0;nt<8;++nt){
      int o0 = nt*16 + r0;
      float4 bb = *(const float4*)(b1eq + o0);
      uint2 u;
      u.x = pk2(silu_f(acc2[ms][nt][0]+bb.x), silu_f(acc2[ms][nt][1]+bb.y));
      u.y = pk2(silu_f(acc2[ms][nt][2]+bb.z), silu_f(acc2[ms][nt][3]+bb.w));
      *(uint2*)(H1 + (size_t)(bid*128 + w*32 + ms*16 + g)*FF + o0) = u;
    }

  if (!first){
    __syncthreads();                         // (4)
    // ---- stage W1me; GEMM1-eme -> H2 ----
    #pragma unroll
    for (int c=t; c<2048; c+=256){
      int row = c >> 4, ko = (c & 15) << 3;
      *(int4*)(&Xs[row*136 + ko]) = *(const int4*)(W1me + row*FF + ko);
    }
    __syncthreads();                         // (5)
    #pragma unroll
    for (int ms=0;ms<2;++ms)
      #pragma unroll
      for (int nt=0;nt<8;++nt) acc2[ms][nt] = f32x4{0.f,0.f,0.f,0.f};
    #pragma unroll
    for (int nt=0;nt<8;++nt)
      #pragma unroll
      for (int ks=0;ks<4;++ks){
        bf16x8 wfr = *(const bf16x8*)(&Xs[(nt*16+g)*136 + ks*32 + kg]);
        #pragma unroll
        for (int ms=0;ms<2;++ms)
          acc2[ms][nt] = __builtin_amdgcn_mfma_f32_16x16x32_bf16(wfr, xf[ms][ks], acc2[ms][nt], 0,0,0);
      }
    #pragma unroll
    for (int ms=0;ms<2;++ms)
      #pragma unroll
      for (int nt=0;nt<8;++nt){
        int o0 = nt*16 + r0;
        uint2 u;
        u.x = pk2(silu_f(acc2[ms][nt][0]), silu_f(acc2[ms][nt][1]));
        u.y = pk2(silu_f(acc2[ms][nt][2]), silu_f(acc2[ms][nt][3]));
        *(uint2*)(H2 + (size_t)(bid*128 + w*32 + ms*16 + g)*FF + o0) = u;
      }
  }
  __syncthreads();                           // (6) drains H stores; Xs free

  // ================= GEMM2 half =================
  bf16x8 hfr1[2][4];
  #pragma unroll
  for (int ms=0;ms<2;++ms)
    #pragma unroll
    for (int ks=0;ks<4;++ks)
      hfr1[ms][ks] = *(const bf16x8*)(H1 + (size_t)(bid*128 + w*32 + ms*16 + g)*FF + ks*32 + kg);
  // ---- stage W2eq; GEMM2-eqf + masked scal reduce -> afl1 ----
  #pragma unroll
  for (int c=t; c<2048; c+=256){
    int row = c >> 4, ko = (c & 15) << 3;
    *(int4*)(&Xs[row*136 + ko]) = *(const int4*)(W2eq + row*FF + ko);
  }
  __syncthreads();                           // (7)
  f32x4 acc[2][8];
  #pragma unroll
  for (int ms=0;ms<2;++ms)
    #pragma unroll
    for (int nt=0;nt<8;++nt) acc[ms][nt] = f32x4{0.f,0.f,0.f,0.f};
  #pragma unroll
  for (int nt=0;nt<8;++nt)
    #pragma unroll
    for (int ks=0;ks<4;++ks){
      bf16x8 wfr = *(const bf16x8*)(&Xs[(nt*16+g)*136 + ks*32 + kg]);
      #pragma unroll
      for (int ms=0;ms<2;++ms)
        acc[ms][nt] = __builtin_amdgcn_mfma_f32_16x16x32_bf16(hfr1[ms][ks], wfr, acc[ms][nt], 0,0,0);
    }
  #pragma unroll
  for (int nt=0;nt<8;++nt){
    int col = nt*16 + g;
    float bb = b2eq[col];
    float q0=0.f,q1=0.f,q2=0.f;
    #pragma unroll
    for (int ms=0;ms<2;++ms)
      #pragma unroll
      for (int r=0;r<4;++r){
        int row = w*32 + ms*16 + r0 + r;
        float ym = (acc[ms][nt][r] + bb) * scal[row][3];
        q0 = fmaf(ym, scal[row][0], q0);
        q1 = fmaf(ym, scal[row][1], q1);
        q2 = fmaf(ym, scal[row][2], q2);
      }
    q0 += __shfl_xor(q0,16); q0 += __shfl_xor(q0,32);
    q1 += __shfl_xor(q1,16); q1 += __shfl_xor(q1,32);
    q2 += __shfl_xor(q2,16); q2 += __shfl_xor(q2,32);
    if (l < 16){
      afl1[w][0*128+col] = q0; afl1[w][1*128+col] = q1; afl1[w][2*128+col] = q2;
    }
  }
  if (!first){
    bf16x8 hfr2[2][4];
    #pragma unroll
    for (int ms=0;ms<2;++ms)
      #pragma unroll
      for (int ks=0;ks<4;++ks)
        hfr2[ms][ks] = *(const bf16x8*)(H2 + (size_t)(bid*128 + w*32 + ms*16 + g)*FF + ks*32 + kg);
    __syncthreads();                         // (8)
    // ---- stage W2me; GEMM2-eme + eqdrT_prev gather reduce -> afl2 ----
    #pragma unroll
    for (int c=t; c<2048; c+=256){
      int row = c >> 4, ko = (c & 15) << 3;
      *(int4*)(&Xs[row*136 + ko]) = *(const int4*)(W2me + row*FF + ko);
    }
    __syncthreads();                         // (9)
    #pragma unroll
    for (int ms=0;ms<2;++ms)
      #pragma unroll
      for (int nt=0;nt<8;++nt) acc[ms][nt] = f32x4{0.f,0.f,0.f,0.f};
    #pragma unroll
    for (int nt=0;nt<8;++nt)
      #pragma unroll
      for (int ks=0;ks<4;++ks){
        bf16x8 wfr = *(const bf16x8*)(&Xs[(nt*16+g)*136 + ks*32 + kg]);
        #pragma unroll
        for (int ms=0;ms<2;++ms)
          acc[ms][nt] = __builtin_amdgcn_mfma_f32_16x16x32_bf16(hfr2[ms][ks], wfr, acc[ms][nt], 0,0,0);
      }
    #pragma unroll
    for (int nt=0;nt<8;++nt){
      int col = nt*16 + g;
      float q0=0.f,q1=0.f,q2=0.f;
      #pragma unroll
      for (int ms=0;ms<2;++ms)
        #pragma unroll
        for (int r=0;r<4;++r){
          int row = w*32 + ms*16 + r0 + r;
          float ym = acc[ms][nt][r] * scal[row][3];
          float4 gv = *(const float4*)(eqdrT_prev + ((size_t)nbq[row]*FF + col)*4);
          q0 = fmaf(ym, gv.x, q0);
          q1 = fmaf(ym, gv.y, q1);
          q2 = fmaf(ym, gv.z, q2);
        }
      q0 += __shfl_xor(q0,16); q0 += __shfl_xor(q0,32);
      q1 += __shfl_xor(q1,16); q1 += __shfl_xor(q1,32);
      q2 += __shfl_xor(q2,16); q2 += __shfl_xor(q2,32);
      if (l < 16){
        afl2[w][0*128+col] = q0; afl2[w][1*128+col] = q1; afl2[w][2*128+col] = q2;
      }
    }
  }
  __syncthreads();                           // (10)
  // ---- merged finalize for both atoms (768 elems) ----
  for (int i=t; i<768; i+=256){
    int p = (i >= 384) ? 1 : 0;
    int j = i - p*384;
    int o = j & 127;
    int c = j >> 7;
    float s1 = afl1[2*p][j] + afl1[2*p+1][j];
    float s2 = first ? 0.0f : (afl2[2*p][j] + afl2[2*p+1][j]);
    size_t idx = (size_t)(a0+p)*384 + j;
    float ef = first ? s1 : (eqf_out[idx] + s1);
    eqf_out[idx] = ef;
    float es = esu[(size_t)(a0+p)*FF + o];
    float v = (first ? 0.0f : eqdr[idx]) + s2 + es*s1;
    eqdr[idx] = v;
    eqdrT_next[((size_t)(a0+p)*FF + o)*4 + c] = v;
    prod[p][j] = ef * v;
  }
  __syncthreads();
  {
    int p = t >> 7, o = t & 127;
    float sum3 = prod[p][o] + prod[p][128+o] + prod[p][256+o];
    size_t idx = (size_t)(a0+p)*FF + o;
    inv_node[idx] = fmaf(-isu[idx], sum3, inv_node[idx]);
  }
}

extern "C" void kernel_launch(void* const* d_in, const int* in_sizes, int n_in,
                              void* d_out, int out_size, void* d_ws, size_t ws_size,
                              hipStream_t stream){
  const int*   z     = (const int*)  d_in[0];
  const int*   nbrs  = (const int*)  d_in[2];
  const float* maskp = (const float*)d_in[3];
  const float* dist  = (const float*)d_in[4];
  const float* dvec  = (const float*)d_in[5];
  const float* emb   = (const float*)d_in[6];
  const float* me_W  = (const float*)d_in[7];
  const float* me_b  = (const float*)d_in[8];
  const float* mn_W1 = (const float*)d_in[9];
  const float* mn_b1 = (const float*)d_in[10];
  const float* mn_W2 = (const float*)d_in[11];
  const float* mn_b2 = (const float*)d_in[12];
  const float* eqc_W = (const float*)d_in[13];
  const float* eqf_W1= (const float*)d_in[14];
  const float* eqf_b1= (const float*)d_in[15];
  const float* eqf_W2= (const float*)d_in[16];
  const float* eqf_b2= (const float*)d_in[17];
  const float* esu_W1= (const float*)d_in[18];
  const float* esu_b1= (const float*)d_in[19];
  const float* esu_W2= (const float*)d_in[20];
  const float* esu_b2= (const float*)d_in[21];
  const float* eme_W1= (const float*)d_in[22];
  const float* eme_W2= (const float*)d_in[23];
  const float* isu_W1= (const float*)d_in[24];
  const float* isu_b1= (const float*)d_in[25];
  const float* isu_W2= (const float*)d_in[26];
  const float* isu_b2= (const float*)d_in[27];

  float* out      = (float*)d_out;
  float* inv_node = out;                        // BA*FF   = 131072
  float* eqF      = out + 131072;               // BA*3    = 3072
  float* eqf      = out + 134144;               // BA*3*FF = 393216
  float* eqdr     = out + 527360;               // BA*3*FF = 393216

  // workspace layout (floats)
  float* w        = (float*)d_ws;
  float* msg_node = w;                          //   131,072
  float* esu_o    = w + 131072;                 //   131,072
  float* isu_o    = w + 262144;                 //   131,072
  float* eqdrT_A  = w + 393216;                 //   524,288 (BA*FF*4)
  float* eqdrT_B  = w + 917504;                 //   524,288
  unsigned short* wbf = (unsigned short*)(w + 1441792); // 208,896 us
  unsigned short* H1  = (unsigned short*)(w + 1546240); // EDG*FF us
  unsigned short* H2  = (unsigned short*)(w + 5740544); // EDG*FF us

  k_cvtw<<<817, 256, 0, stream>>>(eqf_W1, eqf_W2, eme_W1, eme_W2, me_W, wbf);
  k_node3_first<<<dim3(BA/16, 3), 128, 0, stream>>>(z, emb, inv_node,
      mn_W1,  mn_b1,  mn_W2,  mn_b2,  msg_node,
      esu_W1, esu_b1, esu_W2, esu_b2, esu_o,
      isu_W1, isu_b1, isu_W2, isu_b2, isu_o);

  for (int l=0; l<NLAY; ++l){
    size_t oB = (size_t)l*FF;
    const unsigned short* eqfW1b = wbf + 0*49152 + l*16384;
    const unsigned short* eqfW2b = wbf + 1*49152 + l*16384;
    const unsigned short* emeW1b = wbf + 2*49152 + l*16384;
    const unsigned short* emeW2b = wbf + 3*49152 + l*16384;
    const unsigned short* meWb   = wbf + 196608  + l*4096;
    float* dT_prev = (l & 1) ? eqdrT_B : eqdrT_A;   // unused at l==0 (first)
    float* dT_next = (l & 1) ? eqdrT_A : eqdrT_B;
    int first = (l==0);

    k_layer<<<BA/2, 256, 0, stream>>>(dist, dvec, maskp, nbrs, msg_node,
        meWb, me_b+oB, eqc_W+oB,
        eqfW1b, eqf_b1+oB, emeW1b,
        eqfW2b, eqf_b2+oB, emeW2b,
        H1, H2, dT_prev, dT_next, esu_o, isu_o,
        eqF, eqf, eqdr, inv_node, first);
    if (l < NLAY-1){
      size_t oWn = (size_t)(l+1)*FF*FF, oBn = (size_t)(l+1)*FF;
      k_mlp_node3<<<dim3(BA/16, 3), 128, 0, stream>>>(inv_node,
          mn_W1+oWn,  mn_b1+oBn,  mn_W2+oWn,  mn_b2+oBn,  msg_node,
          esu_W1+oWn, esu_b1+oBn, esu_W2+oWn, esu_b2+oBn, esu_o,
          isu_W1+oWn, isu_b1+oBn, isu_W2+oWn, isu_b2+oBn, isu_o);
    }
  }
}

// Round 17
// 164.558 us; speedup vs baseline: 1.4613x; 1.2392x over previous
//
#include <hip/hip_runtime.h>
#include <cstdint>
#include <cstddef>

#define BB   4
#define AA   256
#define NNB  64
#define FF   128
#define NBAS 20
#define NLAY 3
#define BA   (BB*AA)        // 1024 atoms total
#define EDG  (BA*NNB)       // 65536 edges

typedef __attribute__((ext_vector_type(8))) short bf16x8;
typedef __attribute__((ext_vector_type(4))) float f32x4;

__device__ __forceinline__ float silu_f(float x){ return x / (1.0f + __expf(-x)); }

// round-to-nearest-even f32 -> bf16 bits
__device__ __forceinline__ unsigned short f2bf(float x){
  unsigned int u = __float_as_uint(x);
  u += 0x7FFFu + ((u >> 16) & 1u);
  return (unsigned short)(u >> 16);
}
__device__ __forceinline__ unsigned int pk2(float a, float b){
  return (unsigned int)f2bf(a) | ((unsigned int)f2bf(b) << 16);
}

// ------------- weight conversion: edge mats + padded me_W + 6 node mats ------------
// layout (ushorts): 0 eqfW1 | 49152 eqfW2 | 98304 emeW1 | 147456 emeW2 |
// 196608 meW(pad,12288) | 208896 mnW1 | 258048 mnW2 | 307200 esuW1 |
// 356352 esuW2 | 405504 isuW1 | 454656 isuW2 | total 503808
__global__ void k_cvtw(const float* __restrict__ a, const float* __restrict__ b,
                       const float* __restrict__ c, const float* __restrict__ d,
                       const float* __restrict__ me,
                       const float* __restrict__ mnW1, const float* __restrict__ mnW2,
                       const float* __restrict__ esW1, const float* __restrict__ esW2,
                       const float* __restrict__ isW1, const float* __restrict__ isW2,
                       unsigned short* __restrict__ out){
  int id = blockIdx.x*256 + threadIdx.x;
  if (id < 196608){
    int reg = id / 49152, off = id - reg*49152;
    const float* src = (reg==0)?a:(reg==1)?b:(reg==2)?c:d;
    out[id] = f2bf(src[off]);
  } else if (id < 208896){
    int p = id - 196608;
    int l = p >> 12;            // layer
    int rem = p & 4095;
    int row = rem >> 5, k = rem & 31;
    float v = (k < NBAS) ? me[((size_t)l*FF + row)*NBAS + k] : 0.0f;
    out[id] = f2bf(v);
  } else if (id < 503808){
    int p = id - 208896;
    int mat = p / 49152, rem = p - mat*49152;
    const float* src = (mat==0)?mnW1:(mat==1)?mnW2:(mat==2)?esW1:(mat==3)?esW2:(mat==4)?isW1:isW2;
    out[id] = f2bf(src[rem]);
  }
}

// =====================================================================
// k_node_mfma: node MLPs via MFMA. grid (BA/64, 3), 256 threads.
// 64 rows/block; y selects {msg, esu, isu}. Swapped GEMM1 -> H (LDS,
// packed bf16) -> swapped GEMM2 -> f32 out. do_emb: X = emb[z[row]]
// (y==0 also writes inv_node exactly, f32).
// =====================================================================
__global__ __launch_bounds__(256) void k_node_mfma(
    const float* __restrict__ X, const int* __restrict__ z,
    const float* __restrict__ emb, float* __restrict__ inv_node,
    const unsigned short* W1a, const float* b1a, const unsigned short* W2a, const float* b2a, float* Ya,
    const unsigned short* W1b, const float* b1b, const unsigned short* W2b, const float* b2b, float* Yb,
    const unsigned short* W1c, const float* b1c, const unsigned short* W2c, const float* b2c, float* Yc,
    int do_emb){
  const unsigned short *W1,*W2; const float *b1,*b2; float* Y;
  if (blockIdx.y==0){ W1=W1a;b1=b1a;W2=W2a;b2=b2a;Y=Ya; }
  else if (blockIdx.y==1){ W1=W1b;b1=b1b;W2=W2b;b2=b2b;Y=Yb; }
  else { W1=W1c;b1=b1c;W2=W2c;b2=b2c;Y=Yc; }
  __shared__ unsigned short Ws[128*136];     // 34.8 KB
  __shared__ unsigned short Xs[64*136];      // 17.4 KB (X, then H)
  const int t = threadIdx.x, w = t>>6, l = t&63;
  const int g = l&15, kg = (l>>4)<<3, r0 = (l>>4)<<2;
  const int gr0 = blockIdx.x*64;
  const int le = w*16 + g;

  // ---- stage X (f32 -> bf16), 4 threads/row ----
  {
    int row = t>>2, c0 = (t&3)*32;
    const float* src = do_emb ? (emb + (size_t)z[gr0+row]*FF + c0)
                              : (X   + (size_t)(gr0+row)*FF + c0);
    #pragma unroll
    for (int j=0;j<8;++j){
      float4 v = *(const float4*)(src + j*4);
      if (do_emb && blockIdx.y==0)
        *(float4*)(inv_node + (size_t)(gr0+row)*FF + c0 + j*4) = v;
      uint2 u; u.x = pk2(v.x,v.y); u.y = pk2(v.z,v.w);
      *(uint2*)(&Xs[row*136 + c0 + j*4]) = u;
    }
  }
  // ---- stage W1 ----
  #pragma unroll
  for (int c=t; c<2048; c+=256){
    int row = c >> 4, ko = (c & 15) << 3;
    *(int4*)(&Ws[row*136 + ko]) = *(const int4*)(W1 + row*FF + ko);
  }
  __syncthreads();                           // (1)
  bf16x8 xf[4];
  #pragma unroll
  for (int ks=0;ks<4;++ks) xf[ks] = *(const bf16x8*)(&Xs[le*136 + ks*32 + kg]);
  __syncthreads();                           // (2) all X reads done before H overwrite
  // ---- GEMM1 (swapped) -> H in Xs ----
  f32x4 acc[8];
  #pragma unroll
  for (int nt=0;nt<8;++nt) acc[nt] = f32x4{0.f,0.f,0.f,0.f};
  #pragma unroll
  for (int nt=0;nt<8;++nt)
    #pragma unroll
    for (int ks=0;ks<4;++ks){
      bf16x8 wfr = *(const bf16x8*)(&Ws[(nt*16+g)*136 + ks*32 + kg]);
      acc[nt] = __builtin_amdgcn_mfma_f32_16x16x32_bf16(wfr, xf[ks], acc[nt], 0,0,0);
    }
  #pragma unroll
  for (int nt=0;nt<8;++nt){
    int o0 = nt*16 + r0;
    float4 bb = *(const float4*)(b1 + o0);
    uint2 u;
    u.x = pk2(silu_f(acc[nt][0]+bb.x), silu_f(acc[nt][1]+bb.y));
    u.y = pk2(silu_f(acc[nt][2]+bb.z), silu_f(acc[nt][3]+bb.w));
    *(uint2*)(&Xs[le*136 + o0]) = u;
  }
  __syncthreads();                           // (3) GEMM1 done (Ws free), H complete
  // ---- stage W2 ----
  #pragma unroll
  for (int c=t; c<2048; c+=256){
    int row = c >> 4, ko = (c & 15) << 3;
    *(int4*)(&Ws[row*136 + ko]) = *(const int4*)(W2 + row*FF + ko);
  }
  __syncthreads();                           // (4)
  bf16x8 hf[4];
  #pragma unroll
  for (int ks=0;ks<4;++ks) hf[ks] = *(const bf16x8*)(&Xs[le*136 + ks*32 + kg]);
  #pragma unroll
  for (int nt=0;nt<8;++nt) acc[nt] = f32x4{0.f,0.f,0.f,0.f};
  #pragma unroll
  for (int nt=0;nt<8;++nt)
    #pragma unroll
    for (int ks=0;ks<4;++ks){
      bf16x8 wfr = *(const bf16x8*)(&Ws[(nt*16+g)*136 + ks*32 + kg]);
      acc[nt] = __builtin_amdgcn_mfma_f32_16x16x32_bf16(wfr, hf[ks], acc[nt], 0,0,0);
    }
  #pragma unroll
  for (int nt=0;nt<8;++nt){
    int o0 = nt*16 + r0;
    float4 bb = *(const float4*)(b2 + o0);
    float4 o;
    o.x = acc[nt][0]+bb.x; o.y = acc[nt][1]+bb.y;
    o.z = acc[nt][2]+bb.z; o.w = acc[nt][3]+bb.w;
    *(float4*)(Y + (size_t)(gr0 + le)*FF + o0) = o;
  }
}

// =====================================================================
// k_layer: merged k_edge1 + k_z (R13-proven). Grid 512, 2 atoms per block.
// Plain LDS W stagings (reg-prefetch variants spill -> R14/R15 regressions).
// =====================================================================
__global__ __launch_bounds__(256) void k_layer(
    const float* __restrict__ dist, const float* __restrict__ dvec,
    const float* __restrict__ maskp, const int* __restrict__ nbrs,
    const float* __restrict__ msg_node,
    const unsigned short* __restrict__ meWb, const float* __restrict__ meb,
    const float* __restrict__ eqcW,
    const unsigned short* __restrict__ W1eq, const float* __restrict__ b1eq,
    const unsigned short* __restrict__ W1me,
    const unsigned short* __restrict__ W2eq, const float* __restrict__ b2eq,
    const unsigned short* __restrict__ W2me,
    unsigned short* __restrict__ H1, unsigned short* __restrict__ H2,
    const float* __restrict__ eqdrT_prev, float* __restrict__ eqdrT_next,
    const float* __restrict__ esu, const float* __restrict__ isu,
    float* __restrict__ eqF, float* __restrict__ eqf_out,
    float* __restrict__ eqdr, float* __restrict__ inv_node, int first){
  __shared__ unsigned short Xs[128*136];      // 34.8 KB (inv_msg, then W stagings)
  __shared__ float scal[128][4];
  __shared__ int   nbq[128];
  __shared__ float eqFred[4][2][3];
  __shared__ float afl1[4][384];
  __shared__ float afl2[4][384];
  __shared__ float prod[2][384];
  const int t = threadIdx.x, w = t>>6, l = t&63;
  const int bid = blockIdx.x, a0 = bid*2;
  const int g = l&15, kg = (l>>4)<<3, r0 = (l>>4)<<2;
  const float c5 = 0.6283185307179586f;      // pi/5

  if (t < 128){
    int e2 = a0*NNB + t;
    int atomt = a0 + (t>>6);
    nbq[t] = (atomt/AA)*AA + nbrs[e2];
  }

  // ---------------- phase A: geometry + me-MLP + inv_msg -> Xs, scal, eqF ----------------
  #pragma unroll
  for (int p=0;p<2;++p){
    const int atom = a0 + p;
    const int eg = atom*NNB + w*16 + g;
    const float d = dist[eg];
    const float dinv = 1.0f/(d + 1e-8f);
    const float xx = d*0.2f;
    float x2=xx*xx, x4=x2*x2, x6=x4*x2, x7=x6*xx, x8=x7*xx;
    float ct = 1.0f - 28.0f*x6 + 48.0f*x7 - 21.0f*x8;
    ct = (xx < 1.0f) ? ct : 0.0f;
    bf16x8 rfr;
    #pragma unroll
    for (int i=0;i<8;++i){
      int k = kg + i;
      float v = (k < NBAS) ? __sinf((float)(k+1)*c5*d)*dinv : 0.0f;
      rfr[i] = (short)f2bf(v);
    }
    f32x4 acc[8];
    #pragma unroll
    for (int nt=0;nt<8;++nt){
      bf16x8 wfr = *(const bf16x8*)(meWb + (nt*16 + g)*32 + kg);
      acc[nt] = __builtin_amdgcn_mfma_f32_16x16x32_bf16(wfr, rfr, f32x4{0.f,0.f,0.f,0.f}, 0,0,0);
    }
    const int bbase = (atom/AA)*AA;
    const int nbv = bbase + nbrs[eg];
    float pv = 0.f;
    #pragma unroll
    for (int nt=0;nt<8;++nt){
      int o0 = nt*16 + r0;
      float4 mb = *(const float4*)(meb + o0);
      float4 mi = *(const float4*)(msg_node + (size_t)atom*FF + o0);
      float4 mf = *(const float4*)(msg_node + (size_t)nbv*FF + o0);
      float4 ec = *(const float4*)(eqcW + o0);
      float v0 = (acc[nt][0]+mb.x)*ct*mi.x*mf.x;
      float v1 = (acc[nt][1]+mb.y)*ct*mi.y*mf.y;
      float v2 = (acc[nt][2]+mb.z)*ct*mi.z*mf.z;
      float v3 = (acc[nt][3]+mb.w)*ct*mi.w*mf.w;
      pv = fmaf(v0,ec.x, fmaf(v1,ec.y, fmaf(v2,ec.z, fmaf(v3,ec.w, pv))));
      uint2 u; u.x = pk2(v0,v1); u.y = pk2(v2,v3);
      *(uint2*)(&Xs[(p*64 + w*16 + g)*136 + o0]) = u;
    }
    pv += __shfl_xor(pv,16); pv += __shfl_xor(pv,32);
    float cf0=0.f, cf1=0.f, cf2=0.f;
    if (l < 16){
      float m  = maskp[eg];
      float s0 = pv*dvec[(size_t)eg*3+0]*dinv;
      float s1 = pv*dvec[(size_t)eg*3+1]*dinv;
      float s2 = pv*dvec[(size_t)eg*3+2]*dinv;
      int lr = p*64 + w*16 + g;
      scal[lr][0]=s0; scal[lr][1]=s1; scal[lr][2]=s2; scal[lr][3]=m;
      cf0 = s0*m; cf1 = s1*m; cf2 = s2*m;
    }
    #pragma unroll
    for (int s2=1; s2<16; s2<<=1){
      cf0 += __shfl_xor(cf0,s2); cf1 += __shfl_xor(cf1,s2); cf2 += __shfl_xor(cf2,s2);
    }
    if (l == 0){ eqFred[w][p][0]=cf0; eqFred[w][p][1]=cf1; eqFred[w][p][2]=cf2; }
  }
  __syncthreads();                           // (1) Xs/scal complete

  // X fragments -> registers; eq_F final write
  bf16x8 xf[2][4];
  #pragma unroll
  for (int ms=0;ms<2;++ms)
    #pragma unroll
    for (int ks=0;ks<4;++ks)
      xf[ms][ks] = *(const bf16x8*)(&Xs[(w*32 + ms*16 + g)*136 + ks*32 + kg]);
  if (t < 6){
    int p = t/3, c = t - p*3;
    float s = eqFred[0][p][c]+eqFred[1][p][c]+eqFred[2][p][c]+eqFred[3][p][c];
    eqF[(a0+p)*3 + c] = first ? s : (eqF[(a0+p)*3 + c] + s);
  }
  __syncthreads();                           // (2) Xs free

  // ---- stage W1eq; GEMM1-eqf -> H1 (global write-through) ----
  #pragma unroll
  for (int c=t; c<2048; c+=256){
    int row = c >> 4, ko = (c & 15) << 3;
    *(int4*)(&Xs[row*136 + ko]) = *(const int4*)(W1eq + row*FF + ko);
  }
  __syncthreads();                           // (3)
  f32x4 acc2[2][8];
  #pragma unroll
  for (int ms=0;ms<2;++ms)
    #pragma unroll
    for (int nt=0;nt<8;++nt) acc2[ms][nt] = f32x4{0.f,0.f,0.f,0.f};
  #pragma unroll
  for (int nt=0;nt<8;++nt)
    #pragma unroll
    for (int ks=0;ks<4;++ks){
      bf16x8 wfr = *(const bf16x8*)(&Xs[(nt*16+g)*136 + ks*32 + kg]);
      #pragma unroll
      for (int ms=0;ms<2;++ms)
        acc2[ms][nt] = __builtin_amdgcn_mfma_f32_16x16x32_bf16(wfr, xf[ms][ks], acc2[ms][nt], 0,0,0);
    }
  #pragma unroll
  for (int ms=0;ms<2;++ms)
    #pragma unroll
    for (int nt=0;nt<8;++nt){
      int o0 = nt*16 + r0;
      float4 bb = *(const float4*)(b1eq + o0);
      uint2 u;
      u.x = pk2(silu_f(acc2[ms][nt][0]+bb.x), silu_f(acc2[ms][nt][1]+bb.y));
      u.y = pk2(silu_f(acc2[ms][nt][2]+bb.z), silu_f(acc2[ms][nt][3]+bb.w));
      *(uint2*)(H1 + (size_t)(bid*128 + w*32 + ms*16 + g)*FF + o0) = u;
    }

  if (!first){
    __syncthreads();                         // (4)
    // ---- stage W1me; GEMM1-eme -> H2 ----
    #pragma unroll
    for (int c=t; c<2048; c+=256){
      int row = c >> 4, ko = (c & 15) << 3;
      *(int4*)(&Xs[row*136 + ko]) = *(const int4*)(W1me + row*FF + ko);
    }
    __syncthreads();                         // (5)
    #pragma unroll
    for (int ms=0;ms<2;++ms)
      #pragma unroll
      for (int nt=0;nt<8;++nt) acc2[ms][nt] = f32x4{0.f,0.f,0.f,0.f};
    #pragma unroll
    for (int nt=0;nt<8;++nt)
      #pragma unroll
      for (int ks=0;ks<4;++ks){
        bf16x8 wfr = *(const bf16x8*)(&Xs[(nt*16+g)*136 + ks*32 + kg]);
        #pragma unroll
        for (int ms=0;ms<2;++ms)
          acc2[ms][nt] = __builtin_amdgcn_mfma_f32_16x16x32_bf16(wfr, xf[ms][ks], acc2[ms][nt], 0,0,0);
      }
    #pragma unroll
    for (int ms=0;ms<2;++ms)
      #pragma unroll
      for (int nt=0;nt<8;++nt){
        int o0 = nt*16 + r0;
        uint2 u;
        u.x = pk2(silu_f(acc2[ms][nt][0]), silu_f(acc2[ms][nt][1]));
        u.y = pk2(silu_f(acc2[ms][nt][2]), silu_f(acc2[ms][nt][3]));
        *(uint2*)(H2 + (size_t)(bid*128 + w*32 + ms*16 + g)*FF + o0) = u;
      }
  }
  __syncthreads();                           // (6) drains H stores; Xs free

  // ================= GEMM2 half =================
  bf16x8 hfr1[2][4];
  #pragma unroll
  for (int ms=0;ms<2;++ms)
    #pragma unroll
    for (int ks=0;ks<4;++ks)
      hfr1[ms][ks] = *(const bf16x8*)(H1 + (size_t)(bid*128 + w*32 + ms*16 + g)*FF + ks*32 + kg);
  // ---- stage W2eq; GEMM2-eqf + masked scal reduce -> afl1 ----
  #pragma unroll
  for (int c=t; c<2048; c+=256){
    int row = c >> 4, ko = (c & 15) << 3;
    *(int4*)(&Xs[row*136 + ko]) = *(const int4*)(W2eq + row*FF + ko);
  }
  __syncthreads();                           // (7)
  f32x4 acc[2][8];
  #pragma unroll
  for (int ms=0;ms<2;++ms)
    #pragma unroll
    for (int nt=0;nt<8;++nt) acc[ms][nt] = f32x4{0.f,0.f,0.f,0.f};
  #pragma unroll
  for (int nt=0;nt<8;++nt)
    #pragma unroll
    for (int ks=0;ks<4;++ks){
      bf16x8 wfr = *(const bf16x8*)(&Xs[(nt*16+g)*136 + ks*32 + kg]);
      #pragma unroll
      for (int ms=0;ms<2;++ms)
        acc[ms][nt] = __builtin_amdgcn_mfma_f32_16x16x32_bf16(hfr1[ms][ks], wfr, acc[ms][nt], 0,0,0);
    }
  #pragma unroll
  for (int nt=0;nt<8;++nt){
    int col = nt*16 + g;
    float bb = b2eq[col];
    float q0=0.f,q1=0.f,q2=0.f;
    #pragma unroll
    for (int ms=0;ms<2;++ms)
      #pragma unroll
      for (int r=0;r<4;++r){
        int row = w*32 + ms*16 + r0 + r;
        float ym = (acc[ms][nt][r] + bb) * scal[row][3];
        q0 = fmaf(ym, scal[row][0], q0);
        q1 = fmaf(ym, scal[row][1], q1);
        q2 = fmaf(ym, scal[row][2], q2);
      }
    q0 += __shfl_xor(q0,16); q0 += __shfl_xor(q0,32);
    q1 += __shfl_xor(q1,16); q1 += __shfl_xor(q1,32);
    q2 += __shfl_xor(q2,16); q2 += __shfl_xor(q2,32);
    if (l < 16){
      afl1[w][0*128+col] = q0; afl1[w][1*128+col] = q1; afl1[w][2*128+col] = q2;
    }
  }
  if (!first){
    bf16x8 hfr2[2][4];
    #pragma unroll
    for (int ms=0;ms<2;++ms)
      #pragma unroll
      for (int ks=0;ks<4;++ks)
        hfr2[ms][ks] = *(const bf16x8*)(H2 + (size_t)(bid*128 + w*32 + ms*16 + g)*FF + ks*32 + kg);
    __syncthreads();                         // (8)
    // ---- stage W2me; GEMM2-eme + eqdrT_prev gather reduce -> afl2 ----
    #pragma unroll
    for (int c=t; c<2048; c+=256){
      int row = c >> 4, ko = (c & 15) << 3;
      *(int4*)(&Xs[row*136 + ko]) = *(const int4*)(W2me + row*FF + ko);
    }
    __syncthreads();                         // (9)
    #pragma unroll
    for (int ms=0;ms<2;++ms)
      #pragma unroll
      for (int nt=0;nt<8;++nt) acc[ms][nt] = f32x4{0.f,0.f,0.f,0.f};
    #pragma unroll
    for (int nt=0;nt<8;++nt)
      #pragma unroll
      for (int ks=0;ks<4;++ks){
        bf16x8 wfr = *(const bf16x8*)(&Xs[(nt*16+g)*136 + ks*32 + kg]);
        #pragma unroll
        for (int ms=0;ms<2;++ms)
          acc[ms][nt] = __builtin_amdgcn_mfma_f32_16x16x32_bf16(hfr2[ms][ks], wfr, acc[ms][nt], 0,0,0);
      }
    #pragma unroll
    for (int nt=0;nt<8;++nt){
      int col = nt*16 + g;
      float q0=0.f,q1=0.f,q2=0.f;
      #pragma unroll
      for (int ms=0;ms<2;++ms)
        #pragma unroll
        for (int r=0;r<4;++r){
          int row = w*32 + ms*16 + r0 + r;
          float ym = acc[ms][nt][r] * scal[row][3];
          float4 gv = *(const float4*)(eqdrT_prev + ((size_t)nbq[row]*FF + col)*4);
          q0 = fmaf(ym, gv.x, q0);
          q1 = fmaf(ym, gv.y, q1);
          q2 = fmaf(ym, gv.z, q2);
        }
      q0 += __shfl_xor(q0,16); q0 += __shfl_xor(q0,32);
      q1 += __shfl_xor(q1,16); q1 += __shfl_xor(q1,32);
      q2 += __shfl_xor(q2,16); q2 += __shfl_xor(q2,32);
      if (l < 16){
        afl2[w][0*128+col] = q0; afl2[w][1*128+col] = q1; afl2[w][2*128+col] = q2;
      }
    }
  }
  __syncthreads();                           // (10)
  // ---- merged finalize for both atoms (768 elems) ----
  for (int i=t; i<768; i+=256){
    int p = (i >= 384) ? 1 : 0;
    int j = i - p*384;
    int o = j & 127;
    int c = j >> 7;
    float s1 = afl1[2*p][j] + afl1[2*p+1][j];
    float s2 = first ? 0.0f : (afl2[2*p][j] + afl2[2*p+1][j]);
    size_t idx = (size_t)(a0+p)*384 + j;
    float ef = first ? s1 : (eqf_out[idx] + s1);
    eqf_out[idx] = ef;
    float es = esu[(size_t)(a0+p)*FF + o];
    float v = (first ? 0.0f : eqdr[idx]) + s2 + es*s1;
    eqdr[idx] = v;
    eqdrT_next[((size_t)(a0+p)*FF + o)*4 + c] = v;
    prod[p][j] = ef * v;
  }
  __syncthreads();
  {
    int p = t >> 7, o = t & 127;
    float sum3 = prod[p][o] + prod[p][128+o] + prod[p][256+o];
    size_t idx = (size_t)(a0+p)*FF + o;
    inv_node[idx] = fmaf(-isu[idx], sum3, inv_node[idx]);
  }
}

extern "C" void kernel_launch(void* const* d_in, const int* in_sizes, int n_in,
                              void* d_out, int out_size, void* d_ws, size_t ws_size,
                              hipStream_t stream){
  const int*   z     = (const int*)  d_in[0];
  const int*   nbrs  = (const int*)  d_in[2];
  const float* maskp = (const float*)d_in[3];
  const float* dist  = (const float*)d_in[4];
  const float* dvec  = (const float*)d_in[5];
  const float* emb   = (const float*)d_in[6];
  const float* me_W  = (const float*)d_in[7];
  const float* me_b  = (const float*)d_in[8];
  const float* mn_W1 = (const float*)d_in[9];
  const float* mn_b1 = (const float*)d_in[10];
  const float* mn_W2 = (const float*)d_in[11];
  const float* mn_b2 = (const float*)d_in[12];
  const float* eqc_W = (const float*)d_in[13];
  const float* eqf_W1= (const float*)d_in[14];
  const float* eqf_b1= (const float*)d_in[15];
  const float* eqf_W2= (const float*)d_in[16];
  const float* eqf_b2= (const float*)d_in[17];
  const float* esu_W1= (const float*)d_in[18];
  const float* esu_b1= (const float*)d_in[19];
  const float* esu_W2= (const float*)d_in[20];
  const float* esu_b2= (const float*)d_in[21];
  const float* eme_W1= (const float*)d_in[22];
  const float* eme_W2= (const float*)d_in[23];
  const float* isu_W1= (const float*)d_in[24];
  const float* isu_b1= (const float*)d_in[25];
  const float* isu_W2= (const float*)d_in[26];
  const float* isu_b2= (const float*)d_in[27];

  float* out      = (float*)d_out;
  float* inv_node = out;                        // BA*FF   = 131072
  float* eqF      = out + 131072;               // BA*3    = 3072
  float* eqf      = out + 134144;               // BA*3*FF = 393216
  float* eqdr     = out + 527360;               // BA*3*FF = 393216

  // workspace layout (floats); total 10,082,304 f = 40.3 MB
  float* w        = (float*)d_ws;
  float* msg_node = w;                          //   131,072
  float* esu_o    = w + 131072;                 //   131,072
  float* isu_o    = w + 262144;                 //   131,072
  float* eqdrT_A  = w + 393216;                 //   524,288 (BA*FF*4)
  float* eqdrT_B  = w + 917504;                 //   524,288
  unsigned short* wbf = (unsigned short*)(w + 1441792); // 503,808 us = 251,904 f
  unsigned short* H1  = (unsigned short*)(w + 1693696); // EDG*FF us
  unsigned short* H2  = (unsigned short*)(w + 5888000); // EDG*FF us

  k_cvtw<<<1968, 256, 0, stream>>>(eqf_W1, eqf_W2, eme_W1, eme_W2, me_W,
      mn_W1, mn_W2, esu_W1, esu_W2, isu_W1, isu_W2, wbf);

  const unsigned short* mnW1b0  = wbf + 208896;
  const unsigned short* mnW2b0  = wbf + 258048;
  const unsigned short* esW1b0  = wbf + 307200;
  const unsigned short* esW2b0  = wbf + 356352;
  const unsigned short* isW1b0  = wbf + 405504;
  const unsigned short* isW2b0  = wbf + 454656;

  k_node_mfma<<<dim3(BA/64, 3), 256, 0, stream>>>(nullptr, z, emb, inv_node,
      mnW1b0, mn_b1,  mnW2b0, mn_b2,  msg_node,
      esW1b0, esu_b1, esW2b0, esu_b2, esu_o,
      isW1b0, isu_b1, isW2b0, isu_b2, isu_o, 1);

  for (int l=0; l<NLAY; ++l){
    size_t oB = (size_t)l*FF;
    const unsigned short* eqfW1b = wbf + 0*49152 + l*16384;
    const unsigned short* eqfW2b = wbf + 1*49152 + l*16384;
    const unsigned short* emeW1b = wbf + 2*49152 + l*16384;
    const unsigned short* emeW2b = wbf + 3*49152 + l*16384;
    const unsigned short* meWb   = wbf + 196608  + l*4096;
    float* dT_prev = (l & 1) ? eqdrT_B : eqdrT_A;   // unused at l==0 (first)
    float* dT_next = (l & 1) ? eqdrT_A : eqdrT_B;
    int first = (l==0);

    k_layer<<<BA/2, 256, 0, stream>>>(dist, dvec, maskp, nbrs, msg_node,
        meWb, me_b+oB, eqc_W+oB,
        eqfW1b, eqf_b1+oB, emeW1b,
        eqfW2b, eqf_b2+oB, emeW2b,
        H1, H2, dT_prev, dT_next, esu_o, isu_o,
        eqF, eqf, eqdr, inv_node, first);
    if (l < NLAY-1){
      size_t oBn = (size_t)(l+1)*FF;
      k_node_mfma<<<dim3(BA/64, 3), 256, 0, stream>>>(inv_node, nullptr, nullptr, nullptr,
          mnW1b0 + (l+1)*16384, mn_b1+oBn,  mnW2b0 + (l+1)*16384, mn_b2+oBn,  msg_node,
          esW1b0 + (l+1)*16384, esu_b1+oBn, esW2b0 + (l+1)*16384, esu_b2+oBn, esu_o,
          isW1b0 + (l+1)*16384, isu_b1+oBn, isW2b0 + (l+1)*16384, isu_b2+oBn, isu_o, 0);
    }
  }
}

// Round 18
// 142.388 us; speedup vs baseline: 1.6888x; 1.1557x over previous
//
#include <hip/hip_runtime.h>
#include <cstdint>
#include <cstddef>

#define BB   4
#define AA   256
#define NNB  64
#define FF   128
#define NBAS 20
#define NLAY 3
#define BA   (BB*AA)        // 1024 atoms total
#define EDG  (BA*NNB)       // 65536 edges

typedef __attribute__((ext_vector_type(8))) short bf16x8;
typedef __attribute__((ext_vector_type(4))) float f32x4;

__device__ __forceinline__ float silu_f(float x){ return x / (1.0f + __expf(-x)); }

// round-to-nearest-even f32 -> bf16 bits
__device__ __forceinline__ unsigned short f2bf(float x){
  unsigned int u = __float_as_uint(x);
  u += 0x7FFFu + ((u >> 16) & 1u);
  return (unsigned short)(u >> 16);
}
__device__ __forceinline__ unsigned int pk2(float a, float b){
  return (unsigned int)f2bf(a) | ((unsigned int)f2bf(b) << 16);
}

// ------------- weight conversion: edge mats + padded me_W + 6 node mats ------------
__global__ void k_cvtw(const float* __restrict__ a, const float* __restrict__ b,
                       const float* __restrict__ c, const float* __restrict__ d,
                       const float* __restrict__ me,
                       const float* __restrict__ mnW1, const float* __restrict__ mnW2,
                       const float* __restrict__ esW1, const float* __restrict__ esW2,
                       const float* __restrict__ isW1, const float* __restrict__ isW2,
                       unsigned short* __restrict__ out){
  int id = blockIdx.x*256 + threadIdx.x;
  if (id < 196608){
    int reg = id / 49152, off = id - reg*49152;
    const float* src = (reg==0)?a:(reg==1)?b:(reg==2)?c:d;
    out[id] = f2bf(src[off]);
  } else if (id < 208896){
    int p = id - 196608;
    int l = p >> 12;            // layer
    int rem = p & 4095;
    int row = rem >> 5, k = rem & 31;
    float v = (k < NBAS) ? me[((size_t)l*FF + row)*NBAS + k] : 0.0f;
    out[id] = f2bf(v);
  } else if (id < 503808){
    int p = id - 208896;
    int mat = p / 49152, rem = p - mat*49152;
    const float* src = (mat==0)?mnW1:(mat==1)?mnW2:(mat==2)?esW1:(mat==3)?esW2:(mat==4)?isW1:isW2;
    out[id] = f2bf(src[rem]);
  }
}

// =====================================================================
// k_node_mfma: node MLPs via MFMA (R17-proven). grid (BA/64, 3), 256 thr.
// =====================================================================
__global__ __launch_bounds__(256) void k_node_mfma(
    const float* __restrict__ X, const int* __restrict__ z,
    const float* __restrict__ emb, float* __restrict__ inv_node,
    const unsigned short* W1a, const float* b1a, const unsigned short* W2a, const float* b2a, float* Ya,
    const unsigned short* W1b, const float* b1b, const unsigned short* W2b, const float* b2b, float* Yb,
    const unsigned short* W1c, const float* b1c, const unsigned short* W2c, const float* b2c, float* Yc,
    int do_emb){
  const unsigned short *W1,*W2; const float *b1,*b2; float* Y;
  if (blockIdx.y==0){ W1=W1a;b1=b1a;W2=W2a;b2=b2a;Y=Ya; }
  else if (blockIdx.y==1){ W1=W1b;b1=b1b;W2=W2b;b2=b2b;Y=Yb; }
  else { W1=W1c;b1=b1c;W2=W2c;b2=b2c;Y=Yc; }
  __shared__ unsigned short Ws[128*136];     // 34.8 KB
  __shared__ unsigned short Xs[64*136];      // 17.4 KB (X, then H)
  const int t = threadIdx.x, w = t>>6, l = t&63;
  const int g = l&15, kg = (l>>4)<<3, r0 = (l>>4)<<2;
  const int gr0 = blockIdx.x*64;
  const int le = w*16 + g;

  {
    int row = t>>2, c0 = (t&3)*32;
    const float* src = do_emb ? (emb + (size_t)z[gr0+row]*FF + c0)
                              : (X   + (size_t)(gr0+row)*FF + c0);
    #pragma unroll
    for (int j=0;j<8;++j){
      float4 v = *(const float4*)(src + j*4);
      if (do_emb && blockIdx.y==0)
        *(float4*)(inv_node + (size_t)(gr0+row)*FF + c0 + j*4) = v;
      uint2 u; u.x = pk2(v.x,v.y); u.y = pk2(v.z,v.w);
      *(uint2*)(&Xs[row*136 + c0 + j*4]) = u;
    }
  }
  #pragma unroll
  for (int c=t; c<2048; c+=256){
    int row = c >> 4, ko = (c & 15) << 3;
    *(int4*)(&Ws[row*136 + ko]) = *(const int4*)(W1 + row*FF + ko);
  }
  __syncthreads();
  bf16x8 xf[4];
  #pragma unroll
  for (int ks=0;ks<4;++ks) xf[ks] = *(const bf16x8*)(&Xs[le*136 + ks*32 + kg]);
  __syncthreads();
  f32x4 acc[8];
  #pragma unroll
  for (int nt=0;nt<8;++nt) acc[nt] = f32x4{0.f,0.f,0.f,0.f};
  #pragma unroll
  for (int nt=0;nt<8;++nt)
    #pragma unroll
    for (int ks=0;ks<4;++ks){
      bf16x8 wfr = *(const bf16x8*)(&Ws[(nt*16+g)*136 + ks*32 + kg]);
      acc[nt] = __builtin_amdgcn_mfma_f32_16x16x32_bf16(wfr, xf[ks], acc[nt], 0,0,0);
    }
  #pragma unroll
  for (int nt=0;nt<8;++nt){
    int o0 = nt*16 + r0;
    float4 bb = *(const float4*)(b1 + o0);
    uint2 u;
    u.x = pk2(silu_f(acc[nt][0]+bb.x), silu_f(acc[nt][1]+bb.y));
    u.y = pk2(silu_f(acc[nt][2]+bb.z), silu_f(acc[nt][3]+bb.w));
    *(uint2*)(&Xs[le*136 + o0]) = u;
  }
  __syncthreads();
  #pragma unroll
  for (int c=t; c<2048; c+=256){
    int row = c >> 4, ko = (c & 15) << 3;
    *(int4*)(&Ws[row*136 + ko]) = *(const int4*)(W2 + row*FF + ko);
  }
  __syncthreads();
  bf16x8 hf[4];
  #pragma unroll
  for (int ks=0;ks<4;++ks) hf[ks] = *(const bf16x8*)(&Xs[le*136 + ks*32 + kg]);
  #pragma unroll
  for (int nt=0;nt<8;++nt) acc[nt] = f32x4{0.f,0.f,0.f,0.f};
  #pragma unroll
  for (int nt=0;nt<8;++nt)
    #pragma unroll
    for (int ks=0;ks<4;++ks){
      bf16x8 wfr = *(const bf16x8*)(&Ws[(nt*16+g)*136 + ks*32 + kg]);
      acc[nt] = __builtin_amdgcn_mfma_f32_16x16x32_bf16(wfr, hf[ks], acc[nt], 0,0,0);
    }
  #pragma unroll
  for (int nt=0;nt<8;++nt){
    int o0 = nt*16 + r0;
    float4 bb = *(const float4*)(b2 + o0);
    float4 o;
    o.x = acc[nt][0]+bb.x; o.y = acc[nt][1]+bb.y;
    o.z = acc[nt][2]+bb.z; o.w = acc[nt][3]+bb.w;
    *(float4*)(Y + (size_t)(gr0 + le)*FF + o0) = o;
  }
}

// =====================================================================
// k_layer: merged edge pipeline with H kept in LDS (no global H round
// trip). Grid 512, 2 atoms/block, 76.6 KB LDS -> 2 blocks/CU.
// Order: phase A -> eqf (GEMM1->Hs->GEMM2->flush, ef/s1 in regs) ->
// eme (GEMM1->Hs->GEMM2, red reused) -> finalize.
// =====================================================================
__global__ __launch_bounds__(256) void k_layer(
    const float* __restrict__ dist, const float* __restrict__ dvec,
    const float* __restrict__ maskp, const int* __restrict__ nbrs,
    const float* __restrict__ msg_node,
    const unsigned short* __restrict__ meWb, const float* __restrict__ meb,
    const float* __restrict__ eqcW,
    const unsigned short* __restrict__ W1eq, const float* __restrict__ b1eq,
    const unsigned short* __restrict__ W1me,
    const unsigned short* __restrict__ W2eq, const float* __restrict__ b2eq,
    const unsigned short* __restrict__ W2me,
    const float* __restrict__ eqdrT_prev, float* __restrict__ eqdrT_next,
    const float* __restrict__ esu, const float* __restrict__ isu,
    float* __restrict__ eqF, float* __restrict__ eqf_out,
    float* __restrict__ eqdr, float* __restrict__ inv_node, int first){
  __shared__ unsigned short Ws[128*136];     // 34.8 KB: inv_msg, then W stagings
  __shared__ unsigned short Hs[128*136];     // 34.8 KB: H tile (eqf, then eme)
  __shared__ float scal[128][4];
  __shared__ int   nbq[128];
  __shared__ float red[4][384];              // per-wave reduce; reused 3x
  __shared__ float eqFred[4][2][3];
  const int t = threadIdx.x, w = t>>6, l = t&63;
  const int bid = blockIdx.x, a0 = bid*2;
  const int g = l&15, kg = (l>>4)<<3, r0 = (l>>4)<<2;
  const float c5 = 0.6283185307179586f;      // pi/5

  if (t < 128){
    int e2 = a0*NNB + t;
    int atomt = a0 + (t>>6);
    nbq[t] = (atomt/AA)*AA + nbrs[e2];
  }

  // ---------------- phase A: geometry + me-MLP + inv_msg -> Ws, scal, eqF ----------------
  #pragma unroll
  for (int p=0;p<2;++p){
    const int atom = a0 + p;
    const int eg = atom*NNB + w*16 + g;
    const float d = dist[eg];
    const float dinv = 1.0f/(d + 1e-8f);
    const float xx = d*0.2f;
    float x2=xx*xx, x4=x2*x2, x6=x4*x2, x7=x6*xx, x8=x7*xx;
    float ct = 1.0f - 28.0f*x6 + 48.0f*x7 - 21.0f*x8;
    ct = (xx < 1.0f) ? ct : 0.0f;
    bf16x8 rfr;
    #pragma unroll
    for (int i=0;i<8;++i){
      int k = kg + i;
      float v = (k < NBAS) ? __sinf((float)(k+1)*c5*d)*dinv : 0.0f;
      rfr[i] = (short)f2bf(v);
    }
    f32x4 acc[8];
    #pragma unroll
    for (int nt=0;nt<8;++nt){
      bf16x8 wfr = *(const bf16x8*)(meWb + (nt*16 + g)*32 + kg);
      acc[nt] = __builtin_amdgcn_mfma_f32_16x16x32_bf16(wfr, rfr, f32x4{0.f,0.f,0.f,0.f}, 0,0,0);
    }
    const int bbase = (atom/AA)*AA;
    const int nbv = bbase + nbrs[eg];
    float pv = 0.f;
    #pragma unroll
    for (int nt=0;nt<8;++nt){
      int o0 = nt*16 + r0;
      float4 mb = *(const float4*)(meb + o0);
      float4 mi = *(const float4*)(msg_node + (size_t)atom*FF + o0);
      float4 mf = *(const float4*)(msg_node + (size_t)nbv*FF + o0);
      float4 ec = *(const float4*)(eqcW + o0);
      float v0 = (acc[nt][0]+mb.x)*ct*mi.x*mf.x;
      float v1 = (acc[nt][1]+mb.y)*ct*mi.y*mf.y;
      float v2 = (acc[nt][2]+mb.z)*ct*mi.z*mf.z;
      float v3 = (acc[nt][3]+mb.w)*ct*mi.w*mf.w;
      pv = fmaf(v0,ec.x, fmaf(v1,ec.y, fmaf(v2,ec.z, fmaf(v3,ec.w, pv))));
      uint2 u; u.x = pk2(v0,v1); u.y = pk2(v2,v3);
      *(uint2*)(&Ws[(p*64 + w*16 + g)*136 + o0]) = u;
    }
    pv += __shfl_xor(pv,16); pv += __shfl_xor(pv,32);
    float cf0=0.f, cf1=0.f, cf2=0.f;
    if (l < 16){
      float m  = maskp[eg];
      float s0 = pv*dvec[(size_t)eg*3+0]*dinv;
      float s1 = pv*dvec[(size_t)eg*3+1]*dinv;
      float s2 = pv*dvec[(size_t)eg*3+2]*dinv;
      int lr = p*64 + w*16 + g;
      scal[lr][0]=s0; scal[lr][1]=s1; scal[lr][2]=s2; scal[lr][3]=m;
      cf0 = s0*m; cf1 = s1*m; cf2 = s2*m;
    }
    #pragma unroll
    for (int s2=1; s2<16; s2<<=1){
      cf0 += __shfl_xor(cf0,s2); cf1 += __shfl_xor(cf1,s2); cf2 += __shfl_xor(cf2,s2);
    }
    if (l == 0){ eqFred[w][p][0]=cf0; eqFred[w][p][1]=cf1; eqFred[w][p][2]=cf2; }
  }
  __syncthreads();                           // B1: Ws(inv_msg)/scal complete

  // X fragments -> registers (held all kernel); eq_F write
  bf16x8 xf[2][4];
  #pragma unroll
  for (int ms=0;ms<2;++ms)
    #pragma unroll
    for (int ks=0;ks<4;++ks)
      xf[ms][ks] = *(const bf16x8*)(&Ws[(w*32 + ms*16 + g)*136 + ks*32 + kg]);
  if (t < 6){
    int p = t/3, c = t - p*3;
    float s = eqFred[0][p][c]+eqFred[1][p][c]+eqFred[2][p][c]+eqFred[3][p][c];
    eqF[(a0+p)*3 + c] = first ? s : (eqF[(a0+p)*3 + c] + s);
  }
  __syncthreads();                           // B2: Ws free

  // ================= eqf path =================
  // ---- stage W1eq -> Ws ----
  #pragma unroll
  for (int c=t; c<2048; c+=256){
    int row = c >> 4, ko = (c & 15) << 3;
    *(int4*)(&Ws[row*136 + ko]) = *(const int4*)(W1eq + row*FF + ko);
  }
  __syncthreads();                           // B3
  f32x4 acc2[2][8];
  #pragma unroll
  for (int ms=0;ms<2;++ms)
    #pragma unroll
    for (int nt=0;nt<8;++nt) acc2[ms][nt] = f32x4{0.f,0.f,0.f,0.f};
  #pragma unroll
  for (int nt=0;nt<8;++nt)
    #pragma unroll
    for (int ks=0;ks<4;++ks){
      bf16x8 wfr = *(const bf16x8*)(&Ws[(nt*16+g)*136 + ks*32 + kg]);
      #pragma unroll
      for (int ms=0;ms<2;++ms)
        acc2[ms][nt] = __builtin_amdgcn_mfma_f32_16x16x32_bf16(wfr, xf[ms][ks], acc2[ms][nt], 0,0,0);
    }
  #pragma unroll
  for (int ms=0;ms<2;++ms)
    #pragma unroll
    for (int nt=0;nt<8;++nt){
      int o0 = nt*16 + r0;
      float4 bb = *(const float4*)(b1eq + o0);
      uint2 u;
      u.x = pk2(silu_f(acc2[ms][nt][0]+bb.x), silu_f(acc2[ms][nt][1]+bb.y));
      u.y = pk2(silu_f(acc2[ms][nt][2]+bb.z), silu_f(acc2[ms][nt][3]+bb.w));
      *(uint2*)(&Hs[(w*32 + ms*16 + g)*136 + o0]) = u;
    }
  __syncthreads();                           // B4: Ws reads done, Hs complete
  // ---- stage W2eq -> Ws ----
  #pragma unroll
  for (int c=t; c<2048; c+=256){
    int row = c >> 4, ko = (c & 15) << 3;
    *(int4*)(&Ws[row*136 + ko]) = *(const int4*)(W2eq + row*FF + ko);
  }
  __syncthreads();                           // B5
  {
    bf16x8 hfr[2][4];
    #pragma unroll
    for (int ms=0;ms<2;++ms)
      #pragma unroll
      for (int ks=0;ks<4;++ks)
        hfr[ms][ks] = *(const bf16x8*)(&Hs[(w*32 + ms*16 + g)*136 + ks*32 + kg]);
    #pragma unroll
    for (int ms=0;ms<2;++ms)
      #pragma unroll
      for (int nt=0;nt<8;++nt) acc2[ms][nt] = f32x4{0.f,0.f,0.f,0.f};
    #pragma unroll
    for (int nt=0;nt<8;++nt)
      #pragma unroll
      for (int ks=0;ks<4;++ks){
        bf16x8 wfr = *(const bf16x8*)(&Ws[(nt*16+g)*136 + ks*32 + kg]);
        #pragma unroll
        for (int ms=0;ms<2;++ms)
          acc2[ms][nt] = __builtin_amdgcn_mfma_f32_16x16x32_bf16(hfr[ms][ks], wfr, acc2[ms][nt], 0,0,0);
      }
    #pragma unroll
    for (int nt=0;nt<8;++nt){
      int col = nt*16 + g;
      float bb = b2eq[col];
      float q0=0.f,q1=0.f,q2=0.f;
      #pragma unroll
      for (int ms=0;ms<2;++ms)
        #pragma unroll
        for (int r=0;r<4;++r){
          int row = w*32 + ms*16 + r0 + r;
          float ym = (acc2[ms][nt][r] + bb) * scal[row][3];
          q0 = fmaf(ym, scal[row][0], q0);
          q1 = fmaf(ym, scal[row][1], q1);
          q2 = fmaf(ym, scal[row][2], q2);
        }
      q0 += __shfl_xor(q0,16); q0 += __shfl_xor(q0,32);
      q1 += __shfl_xor(q1,16); q1 += __shfl_xor(q1,32);
      q2 += __shfl_xor(q2,16); q2 += __shfl_xor(q2,32);
      if (l < 16){
        red[w][0*128+col] = q0; red[w][1*128+col] = q1; red[w][2*128+col] = q2;
      }
    }
  }
  __syncthreads();                           // B6: red complete; Hs/Ws free

  // ---- flush eqf: ef/s1 to registers, eqf_out to global ----
  float ef_reg[3], s1_reg[3];
  {
    int k = 0;
    for (int i=t; i<768; i+=256, ++k){
      int p = (i >= 384) ? 1 : 0;
      int j = i - p*384;
      float s1 = red[2*p][j] + red[2*p+1][j];
      size_t idx = (size_t)(a0+p)*384 + j;
      float ef = first ? s1 : (eqf_out[idx] + s1);
      eqf_out[idx] = ef;
      ef_reg[k] = ef; s1_reg[k] = s1;
    }
  }

  // ================= eme path =================
  if (!first){
    // ---- stage W1me -> Ws ----
    #pragma unroll
    for (int c=t; c<2048; c+=256){
      int row = c >> 4, ko = (c & 15) << 3;
      *(int4*)(&Ws[row*136 + ko]) = *(const int4*)(W1me + row*FF + ko);
    }
    __syncthreads();                         // B7
    #pragma unroll
    for (int ms=0;ms<2;++ms)
      #pragma unroll
      for (int nt=0;nt<8;++nt) acc2[ms][nt] = f32x4{0.f,0.f,0.f,0.f};
    #pragma unroll
    for (int nt=0;nt<8;++nt)
      #pragma unroll
      for (int ks=0;ks<4;++ks){
        bf16x8 wfr = *(const bf16x8*)(&Ws[(nt*16+g)*136 + ks*32 + kg]);
        #pragma unroll
        for (int ms=0;ms<2;++ms)
          acc2[ms][nt] = __builtin_amdgcn_mfma_f32_16x16x32_bf16(wfr, xf[ms][ks], acc2[ms][nt], 0,0,0);
      }
    #pragma unroll
    for (int ms=0;ms<2;++ms)
      #pragma unroll
      for (int nt=0;nt<8;++nt){
        int o0 = nt*16 + r0;
        uint2 u;
        u.x = pk2(silu_f(acc2[ms][nt][0]), silu_f(acc2[ms][nt][1]));
        u.y = pk2(silu_f(acc2[ms][nt][2]), silu_f(acc2[ms][nt][3]));
        *(uint2*)(&Hs[(w*32 + ms*16 + g)*136 + o0]) = u;
      }
    __syncthreads();                         // B8: Ws reads done, Hs(eme) complete
    // ---- stage W2me -> Ws ----
    #pragma unroll
    for (int c=t; c<2048; c+=256){
      int row = c >> 4, ko = (c & 15) << 3;
      *(int4*)(&Ws[row*136 + ko]) = *(const int4*)(W2me + row*FF + ko);
    }
    __syncthreads();                         // B9
    bf16x8 hfr[2][4];
    #pragma unroll
    for (int ms=0;ms<2;++ms)
      #pragma unroll
      for (int ks=0;ks<4;++ks)
        hfr[ms][ks] = *(const bf16x8*)(&Hs[(w*32 + ms*16 + g)*136 + ks*32 + kg]);
    #pragma unroll
    for (int ms=0;ms<2;++ms)
      #pragma unroll
      for (int nt=0;nt<8;++nt) acc2[ms][nt] = f32x4{0.f,0.f,0.f,0.f};
    #pragma unroll
    for (int nt=0;nt<8;++nt)
      #pragma unroll
      for (int ks=0;ks<4;++ks){
        bf16x8 wfr = *(const bf16x8*)(&Ws[(nt*16+g)*136 + ks*32 + kg]);
        #pragma unroll
        for (int ms=0;ms<2;++ms)
          acc2[ms][nt] = __builtin_amdgcn_mfma_f32_16x16x32_bf16(hfr[ms][ks], wfr, acc2[ms][nt], 0,0,0);
      }
    #pragma unroll
    for (int nt=0;nt<8;++nt){
      int col = nt*16 + g;
      float q0=0.f,q1=0.f,q2=0.f;
      #pragma unroll
      for (int ms=0;ms<2;++ms)
        #pragma unroll
        for (int r=0;r<4;++r){
          int row = w*32 + ms*16 + r0 + r;
          float ym = acc2[ms][nt][r] * scal[row][3];
          float4 gv = *(const float4*)(eqdrT_prev + ((size_t)nbq[row]*FF + col)*4);
          q0 = fmaf(ym, gv.x, q0);
          q1 = fmaf(ym, gv.y, q1);
          q2 = fmaf(ym, gv.z, q2);
        }
      q0 += __shfl_xor(q0,16); q0 += __shfl_xor(q0,32);
      q1 += __shfl_xor(q1,16); q1 += __shfl_xor(q1,32);
      q2 += __shfl_xor(q2,16); q2 += __shfl_xor(q2,32);
      if (l < 16){
        red[w][0*128+col] = q0; red[w][1*128+col] = q1; red[w][2*128+col] = q2;
      }
    }
    __syncthreads();                         // B10: red(eme) complete
  }

  // ---- finalize: eqdr/eqdrT/prod (prod overlays red[2p]) ----
  {
    int k = 0;
    for (int i=t; i<768; i+=256, ++k){
      int p = (i >= 384) ? 1 : 0;
      int j = i - p*384;
      int o = j & 127;
      int c = j >> 7;
      float s2 = first ? 0.0f : (red[2*p][j] + red[2*p+1][j]);
      size_t idx = (size_t)(a0+p)*384 + j;
      float es = esu[(size_t)(a0+p)*FF + o];
      float v = (first ? 0.0f : eqdr[idx]) + s2 + es*s1_reg[k];
      eqdr[idx] = v;
      eqdrT_next[((size_t)(a0+p)*FF + o)*4 + c] = v;
      red[2*p][j] = ef_reg[k] * v;           // prod
    }
  }
  __syncthreads();                           // B11
  {
    int p = t >> 7, o = t & 127;
    float sum3 = red[2*p][o] + red[2*p][128+o] + red[2*p][256+o];
    size_t idx = (size_t)(a0+p)*FF + o;
    inv_node[idx] = fmaf(-isu[idx], sum3, inv_node[idx]);
  }
}

extern "C" void kernel_launch(void* const* d_in, const int* in_sizes, int n_in,
                              void* d_out, int out_size, void* d_ws, size_t ws_size,
                              hipStream_t stream){
  const int*   z     = (const int*)  d_in[0];
  const int*   nbrs  = (const int*)  d_in[2];
  const float* maskp = (const float*)d_in[3];
  const float* dist  = (const float*)d_in[4];
  const float* dvec  = (const float*)d_in[5];
  const float* emb   = (const float*)d_in[6];
  const float* me_W  = (const float*)d_in[7];
  const float* me_b  = (const float*)d_in[8];
  const float* mn_W1 = (const float*)d_in[9];
  const float* mn_b1 = (const float*)d_in[10];
  const float* mn_W2 = (const float*)d_in[11];
  const float* mn_b2 = (const float*)d_in[12];
  const float* eqc_W = (const float*)d_in[13];
  const float* eqf_W1= (const float*)d_in[14];
  const float* eqf_b1= (const float*)d_in[15];
  const float* eqf_W2= (const float*)d_in[16];
  const float* eqf_b2= (const float*)d_in[17];
  const float* esu_W1= (const float*)d_in[18];
  const float* esu_b1= (const float*)d_in[19];
  const float* esu_W2= (const float*)d_in[20];
  const float* esu_b2= (const float*)d_in[21];
  const float* eme_W1= (const float*)d_in[22];
  const float* eme_W2= (const float*)d_in[23];
  const float* isu_W1= (const float*)d_in[24];
  const float* isu_b1= (const float*)d_in[25];
  const float* isu_W2= (const float*)d_in[26];
  const float* isu_b2= (const float*)d_in[27];

  float* out      = (float*)d_out;
  float* inv_node = out;                        // BA*FF   = 131072
  float* eqF      = out + 131072;               // BA*3    = 3072
  float* eqf      = out + 134144;               // BA*3*FF = 393216
  float* eqdr     = out + 527360;               // BA*3*FF = 393216

  // workspace layout (floats)
  float* w        = (float*)d_ws;
  float* msg_node = w;                          //   131,072
  float* esu_o    = w + 131072;                 //   131,072
  float* isu_o    = w + 262144;                 //   131,072
  float* eqdrT_A  = w + 393216;                 //   524,288 (BA*FF*4)
  float* eqdrT_B  = w + 917504;                 //   524,288
  unsigned short* wbf = (unsigned short*)(w + 1441792); // 503,808 us

  k_cvtw<<<1968, 256, 0, stream>>>(eqf_W1, eqf_W2, eme_W1, eme_W2, me_W,
      mn_W1, mn_W2, esu_W1, esu_W2, isu_W1, isu_W2, wbf);

  const unsigned short* mnW1b0  = wbf + 208896;
  const unsigned short* mnW2b0  = wbf + 258048;
  const unsigned short* esW1b0  = wbf + 307200;
  const unsigned short* esW2b0  = wbf + 356352;
  const unsigned short* isW1b0  = wbf + 405504;
  const unsigned short* isW2b0  = wbf + 454656;

  k_node_mfma<<<dim3(BA/64, 3), 256, 0, stream>>>(nullptr, z, emb, inv_node,
      mnW1b0, mn_b1,  mnW2b0, mn_b2,  msg_node,
      esW1b0, esu_b1, esW2b0, esu_b2, esu_o,
      isW1b0, isu_b1, isW2b0, isu_b2, isu_o, 1);

  for (int l=0; l<NLAY; ++l){
    size_t oB = (size_t)l*FF;
    const unsigned short* eqfW1b = wbf + 0*49152 + l*16384;
    const unsigned short* eqfW2b = wbf + 1*49152 + l*16384;
    const unsigned short* emeW1b = wbf + 2*49152 + l*16384;
    const unsigned short* emeW2b = wbf + 3*49152 + l*16384;
    const unsigned short* meWb   = wbf + 196608  + l*4096;
    float* dT_prev = (l & 1) ? eqdrT_B : eqdrT_A;   // unused at l==0 (first)
    float* dT_next = (l & 1) ? eqdrT_A : eqdrT_B;
    int first = (l==0);

    k_layer<<<BA/2, 256, 0, stream>>>(dist, dvec, maskp, nbrs, msg_node,
        meWb, me_b+oB, eqc_W+oB,
        eqfW1b, eqf_b1+oB, emeW1b,
        eqfW2b, eqf_b2+oB, emeW2b,
        dT_prev, dT_next, esu_o, isu_o,
        eqF, eqf, eqdr, inv_node, first);
    if (l < NLAY-1){
      size_t oBn = (size_t)(l+1)*FF;
      k_node_mfma<<<dim3(BA/64, 3), 256, 0, stream>>>(inv_node, nullptr, nullptr, nullptr,
          mnW1b0 + (l+1)*16384, mn_b1+oBn,  mnW2b0 + (l+1)*16384, mn_b2+oBn,  msg_node,
          esW1b0 + (l+1)*16384, esu_b1+oBn, esW2b0 + (l+1)*16384, esu_b2+oBn, esu_o,
          isW1b0 + (l+1)*16384, isu_b1+oBn, isW2b0 + (l+1)*16384, isu_b2+oBn, isu_o, 0);
    }
  }
}

// Round 19
// 139.457 us; speedup vs baseline: 1.7243x; 1.0210x over previous
//
#include <hip/hip_runtime.h>
#include <cstdint>
#include <cstddef>

#define BB   4
#define AA   256
#define NNB  64
#define FF   128
#define NBAS 20
#define NLAY 3
#define BA   (BB*AA)        // 1024 atoms total
#define EDG  (BA*NNB)       // 65536 edges

typedef __attribute__((ext_vector_type(8))) short bf16x8;
typedef __attribute__((ext_vector_type(4))) float f32x4;

__device__ __forceinline__ float silu_f(float x){ return x / (1.0f + __expf(-x)); }

// round-to-nearest-even f32 -> bf16 bits (scalar path)
__device__ __forceinline__ unsigned short f2bf(float x){
  unsigned int u = __float_as_uint(x);
  u += 0x7FFFu + ((u >> 16) & 1u);
  return (unsigned short)(u >> 16);
}
// packed f32 pair -> 2x bf16 in one VALU op (gfx950 v_cvt_pk_bf16_f32)
__device__ __forceinline__ unsigned int pk2(float a, float b){
  unsigned int r;
  asm("v_cvt_pk_bf16_f32 %0, %1, %2" : "=v"(r) : "v"(a), "v"(b));
  return r;
}

// ------------- weight conversion: edge mats + padded me_W + 6 node mats ------------
__global__ void k_cvtw(const float* __restrict__ a, const float* __restrict__ b,
                       const float* __restrict__ c, const float* __restrict__ d,
                       const float* __restrict__ me,
                       const float* __restrict__ mnW1, const float* __restrict__ mnW2,
                       const float* __restrict__ esW1, const float* __restrict__ esW2,
                       const float* __restrict__ isW1, const float* __restrict__ isW2,
                       unsigned short* __restrict__ out){
  int id = blockIdx.x*256 + threadIdx.x;
  if (id < 196608){
    int reg = id / 49152, off = id - reg*49152;
    const float* src = (reg==0)?a:(reg==1)?b:(reg==2)?c:d;
    out[id] = f2bf(src[off]);
  } else if (id < 208896){
    int p = id - 196608;
    int l = p >> 12;            // layer
    int rem = p & 4095;
    int row = rem >> 5, k = rem & 31;
    float v = (k < NBAS) ? me[((size_t)l*FF + row)*NBAS + k] : 0.0f;
    out[id] = f2bf(v);
  } else if (id < 503808){
    int p = id - 208896;
    int mat = p / 49152, rem = p - mat*49152;
    const float* src = (mat==0)?mnW1:(mat==1)?mnW2:(mat==2)?esW1:(mat==3)?esW2:(mat==4)?isW1:isW2;
    out[id] = f2bf(src[rem]);
  }
}

// =====================================================================
// k_node_mfma: node MLPs via MFMA (R17-proven). grid (BA/64, 3), 256 thr.
// =====================================================================
__global__ __launch_bounds__(256) void k_node_mfma(
    const float* __restrict__ X, const int* __restrict__ z,
    const float* __restrict__ emb, float* __restrict__ inv_node,
    const unsigned short* W1a, const float* b1a, const unsigned short* W2a, const float* b2a, float* Ya,
    const unsigned short* W1b, const float* b1b, const unsigned short* W2b, const float* b2b, float* Yb,
    const unsigned short* W1c, const float* b1c, const unsigned short* W2c, const float* b2c, float* Yc,
    int do_emb){
  const unsigned short *W1,*W2; const float *b1,*b2; float* Y;
  if (blockIdx.y==0){ W1=W1a;b1=b1a;W2=W2a;b2=b2a;Y=Ya; }
  else if (blockIdx.y==1){ W1=W1b;b1=b1b;W2=W2b;b2=b2b;Y=Yb; }
  else { W1=W1c;b1=b1c;W2=W2c;b2=b2c;Y=Yc; }
  __shared__ unsigned short Ws[128*136];     // 34.8 KB
  __shared__ unsigned short Xs[64*136];      // 17.4 KB (X, then H)
  const int t = threadIdx.x, w = t>>6, l = t&63;
  const int g = l&15, kg = (l>>4)<<3, r0 = (l>>4)<<2;
  const int gr0 = blockIdx.x*64;
  const int le = w*16 + g;

  {
    int row = t>>2, c0 = (t&3)*32;
    const float* src = do_emb ? (emb + (size_t)z[gr0+row]*FF + c0)
                              : (X   + (size_t)(gr0+row)*FF + c0);
    #pragma unroll
    for (int j=0;j<8;++j){
      float4 v = *(const float4*)(src + j*4);
      if (do_emb && blockIdx.y==0)
        *(float4*)(inv_node + (size_t)(gr0+row)*FF + c0 + j*4) = v;
      uint2 u; u.x = pk2(v.x,v.y); u.y = pk2(v.z,v.w);
      *(uint2*)(&Xs[row*136 + c0 + j*4]) = u;
    }
  }
  #pragma unroll
  for (int c=t; c<2048; c+=256){
    int row = c >> 4, ko = (c & 15) << 3;
    *(int4*)(&Ws[row*136 + ko]) = *(const int4*)(W1 + row*FF + ko);
  }
  __syncthreads();
  bf16x8 xf[4];
  #pragma unroll
  for (int ks=0;ks<4;++ks) xf[ks] = *(const bf16x8*)(&Xs[le*136 + ks*32 + kg]);
  __syncthreads();
  f32x4 acc[8];
  #pragma unroll
  for (int nt=0;nt<8;++nt) acc[nt] = f32x4{0.f,0.f,0.f,0.f};
  #pragma unroll
  for (int nt=0;nt<8;++nt)
    #pragma unroll
    for (int ks=0;ks<4;++ks){
      bf16x8 wfr = *(const bf16x8*)(&Ws[(nt*16+g)*136 + ks*32 + kg]);
      acc[nt] = __builtin_amdgcn_mfma_f32_16x16x32_bf16(wfr, xf[ks], acc[nt], 0,0,0);
    }
  #pragma unroll
  for (int nt=0;nt<8;++nt){
    int o0 = nt*16 + r0;
    float4 bb = *(const float4*)(b1 + o0);
    uint2 u;
    u.x = pk2(silu_f(acc[nt][0]+bb.x), silu_f(acc[nt][1]+bb.y));
    u.y = pk2(silu_f(acc[nt][2]+bb.z), silu_f(acc[nt][3]+bb.w));
    *(uint2*)(&Xs[le*136 + o0]) = u;
  }
  __syncthreads();
  #pragma unroll
  for (int c=t; c<2048; c+=256){
    int row = c >> 4, ko = (c & 15) << 3;
    *(int4*)(&Ws[row*136 + ko]) = *(const int4*)(W2 + row*FF + ko);
  }
  __syncthreads();
  bf16x8 hf[4];
  #pragma unroll
  for (int ks=0;ks<4;++ks) hf[ks] = *(const bf16x8*)(&Xs[le*136 + ks*32 + kg]);
  #pragma unroll
  for (int nt=0;nt<8;++nt) acc[nt] = f32x4{0.f,0.f,0.f,0.f};
  #pragma unroll
  for (int nt=0;nt<8;++nt)
    #pragma unroll
    for (int ks=0;ks<4;++ks){
      bf16x8 wfr = *(const bf16x8*)(&Ws[(nt*16+g)*136 + ks*32 + kg]);
      acc[nt] = __builtin_amdgcn_mfma_f32_16x16x32_bf16(wfr, hf[ks], acc[nt], 0,0,0);
    }
  #pragma unroll
  for (int nt=0;nt<8;++nt){
    int o0 = nt*16 + r0;
    float4 bb = *(const float4*)(b2 + o0);
    float4 o;
    o.x = acc[nt][0]+bb.x; o.y = acc[nt][1]+bb.y;
    o.z = acc[nt][2]+bb.z; o.w = acc[nt][3]+bb.w;
    *(float4*)(Y + (size_t)(gr0 + le)*FF + o0) = o;
  }
}

// =====================================================================
// k_layer: H-in-LDS edge pipeline (R18) + buffer ping-pong:
//   W1eq staged into Hs at ENTRY (overlaps phase A; one fewer barrier).
//   Roles alternate: GEMM1-eqf Hs(W)->Ws(H); W2eq->Hs; GEMM2-eqf;
//   W1me->Ws; GEMM1-eme Ws(W)->Hs(H); W2me->Ws; GEMM2-eme.
// Grid 512, 2 atoms/block, 76.6 KB LDS -> 2 blocks/CU.
// =====================================================================
__global__ __launch_bounds__(256) void k_layer(
    const float* __restrict__ dist, const float* __restrict__ dvec,
    const float* __restrict__ maskp, const int* __restrict__ nbrs,
    const float* __restrict__ msg_node,
    const unsigned short* __restrict__ meWb, const float* __restrict__ meb,
    const float* __restrict__ eqcW,
    const unsigned short* __restrict__ W1eq, const float* __restrict__ b1eq,
    const unsigned short* __restrict__ W1me,
    const unsigned short* __restrict__ W2eq, const float* __restrict__ b2eq,
    const unsigned short* __restrict__ W2me,
    const float* __restrict__ eqdrT_prev, float* __restrict__ eqdrT_next,
    const float* __restrict__ esu, const float* __restrict__ isu,
    float* __restrict__ eqF, float* __restrict__ eqf_out,
    float* __restrict__ eqdr, float* __restrict__ inv_node, int first){
  __shared__ unsigned short Ws[128*136];     // inv_msg -> H(eqf) -> W1me -> W2me
  __shared__ unsigned short Hs[128*136];     // W1eq -> W2eq -> H(eme)
  __shared__ float scal[128][4];
  __shared__ int   nbq[128];
  __shared__ float red[4][384];
  __shared__ float eqFred[4][2][3];
  const int t = threadIdx.x, w = t>>6, l = t&63;
  const int bid = blockIdx.x, a0 = bid*2;
  const int g = l&15, kg = (l>>4)<<3, r0 = (l>>4)<<2;
  const float c5 = 0.6283185307179586f;      // pi/5

  // ---- entry: stage W1eq -> Hs (schedules against phase A) ----
  #pragma unroll
  for (int c=t; c<2048; c+=256){
    int row = c >> 4, ko = (c & 15) << 3;
    *(int4*)(&Hs[row*136 + ko]) = *(const int4*)(W1eq + row*FF + ko);
  }
  if (t < 128){
    int e2 = a0*NNB + t;
    int atomt = a0 + (t>>6);
    nbq[t] = (atomt/AA)*AA + nbrs[e2];
  }

  // ---------------- phase A: geometry + me-MLP + inv_msg -> Ws, scal, eqF ----------------
  #pragma unroll
  for (int p=0;p<2;++p){
    const int atom = a0 + p;
    const int eg = atom*NNB + w*16 + g;
    const float d = dist[eg];
    const float dinv = 1.0f/(d + 1e-8f);
    const float xx = d*0.2f;
    float x2=xx*xx, x4=x2*x2, x6=x4*x2, x7=x6*xx, x8=x7*xx;
    float ct = 1.0f - 28.0f*x6 + 48.0f*x7 - 21.0f*x8;
    ct = (xx < 1.0f) ? ct : 0.0f;
    bf16x8 rfr;
    #pragma unroll
    for (int i=0;i<8;++i){
      int k = kg + i;
      float v = (k < NBAS) ? __sinf((float)(k+1)*c5*d)*dinv : 0.0f;
      rfr[i] = (short)f2bf(v);
    }
    f32x4 acc[8];
    #pragma unroll
    for (int nt=0;nt<8;++nt){
      bf16x8 wfr = *(const bf16x8*)(meWb + (nt*16 + g)*32 + kg);
      acc[nt] = __builtin_amdgcn_mfma_f32_16x16x32_bf16(wfr, rfr, f32x4{0.f,0.f,0.f,0.f}, 0,0,0);
    }
    const int bbase = (atom/AA)*AA;
    const int nbv = bbase + nbrs[eg];
    float pv = 0.f;
    #pragma unroll
    for (int nt=0;nt<8;++nt){
      int o0 = nt*16 + r0;
      float4 mb = *(const float4*)(meb + o0);
      float4 mi = *(const float4*)(msg_node + (size_t)atom*FF + o0);
      float4 mf = *(const float4*)(msg_node + (size_t)nbv*FF + o0);
      float4 ec = *(const float4*)(eqcW + o0);
      float v0 = (acc[nt][0]+mb.x)*ct*mi.x*mf.x;
      float v1 = (acc[nt][1]+mb.y)*ct*mi.y*mf.y;
      float v2 = (acc[nt][2]+mb.z)*ct*mi.z*mf.z;
      float v3 = (acc[nt][3]+mb.w)*ct*mi.w*mf.w;
      pv = fmaf(v0,ec.x, fmaf(v1,ec.y, fmaf(v2,ec.z, fmaf(v3,ec.w, pv))));
      uint2 u; u.x = pk2(v0,v1); u.y = pk2(v2,v3);
      *(uint2*)(&Ws[(p*64 + w*16 + g)*136 + o0]) = u;
    }
    pv += __shfl_xor(pv,16); pv += __shfl_xor(pv,32);
    float cf0=0.f, cf1=0.f, cf2=0.f;
    if (l < 16){
      float m  = maskp[eg];
      float s0 = pv*dvec[(size_t)eg*3+0]*dinv;
      float s1 = pv*dvec[(size_t)eg*3+1]*dinv;
      float s2 = pv*dvec[(size_t)eg*3+2]*dinv;
      int lr = p*64 + w*16 + g;
      scal[lr][0]=s0; scal[lr][1]=s1; scal[lr][2]=s2; scal[lr][3]=m;
      cf0 = s0*m; cf1 = s1*m; cf2 = s2*m;
    }
    #pragma unroll
    for (int s2=1; s2<16; s2<<=1){
      cf0 += __shfl_xor(cf0,s2); cf1 += __shfl_xor(cf1,s2); cf2 += __shfl_xor(cf2,s2);
    }
    if (l == 0){ eqFred[w][p][0]=cf0; eqFred[w][p][1]=cf1; eqFred[w][p][2]=cf2; }
  }
  __syncthreads();                           // B1: Ws(inv_msg)/scal/Hs(W1eq) complete

  // X fragments -> registers; eq_F write
  bf16x8 xf[2][4];
  #pragma unroll
  for (int ms=0;ms<2;++ms)
    #pragma unroll
    for (int ks=0;ks<4;++ks)
      xf[ms][ks] = *(const bf16x8*)(&Ws[(w*32 + ms*16 + g)*136 + ks*32 + kg]);
  if (t < 6){
    int p = t/3, c = t - p*3;
    float s = eqFred[0][p][c]+eqFred[1][p][c]+eqFred[2][p][c]+eqFred[3][p][c];
    eqF[(a0+p)*3 + c] = first ? s : (eqF[(a0+p)*3 + c] + s);
  }
  __syncthreads();                           // B2: Ws free (xf extracted)

  // ---- GEMM1-eqf: W from Hs, H out -> Ws ----
  f32x4 acc2[2][8];
  #pragma unroll
  for (int ms=0;ms<2;++ms)
    #pragma unroll
    for (int nt=0;nt<8;++nt) acc2[ms][nt] = f32x4{0.f,0.f,0.f,0.f};
  #pragma unroll
  for (int nt=0;nt<8;++nt)
    #pragma unroll
    for (int ks=0;ks<4;++ks){
      bf16x8 wfr = *(const bf16x8*)(&Hs[(nt*16+g)*136 + ks*32 + kg]);
      #pragma unroll
      for (int ms=0;ms<2;++ms)
        acc2[ms][nt] = __builtin_amdgcn_mfma_f32_16x16x32_bf16(wfr, xf[ms][ks], acc2[ms][nt], 0,0,0);
    }
  #pragma unroll
  for (int ms=0;ms<2;++ms)
    #pragma unroll
    for (int nt=0;nt<8;++nt){
      int o0 = nt*16 + r0;
      float4 bb = *(const float4*)(b1eq + o0);
      uint2 u;
      u.x = pk2(silu_f(acc2[ms][nt][0]+bb.x), silu_f(acc2[ms][nt][1]+bb.y));
      u.y = pk2(silu_f(acc2[ms][nt][2]+bb.z), silu_f(acc2[ms][nt][3]+bb.w));
      *(uint2*)(&Ws[(w*32 + ms*16 + g)*136 + o0]) = u;
    }
  __syncthreads();                           // B3: Hs reads done, Ws(H) complete

  // ---- stage W2eq -> Hs ----
  #pragma unroll
  for (int c=t; c<2048; c+=256){
    int row = c >> 4, ko = (c & 15) << 3;
    *(int4*)(&Hs[row*136 + ko]) = *(const int4*)(W2eq + row*FF + ko);
  }
  __syncthreads();                           // B4
  {
    bf16x8 hfr[2][4];
    #pragma unroll
    for (int ms=0;ms<2;++ms)
      #pragma unroll
      for (int ks=0;ks<4;++ks)
        hfr[ms][ks] = *(const bf16x8*)(&Ws[(w*32 + ms*16 + g)*136 + ks*32 + kg]);
    #pragma unroll
    for (int ms=0;ms<2;++ms)
      #pragma unroll
      for (int nt=0;nt<8;++nt) acc2[ms][nt] = f32x4{0.f,0.f,0.f,0.f};
    #pragma unroll
    for (int nt=0;nt<8;++nt)
      #pragma unroll
      for (int ks=0;ks<4;++ks){
        bf16x8 wfr = *(const bf16x8*)(&Hs[(nt*16+g)*136 + ks*32 + kg]);
        #pragma unroll
        for (int ms=0;ms<2;++ms)
          acc2[ms][nt] = __builtin_amdgcn_mfma_f32_16x16x32_bf16(hfr[ms][ks], wfr, acc2[ms][nt], 0,0,0);
      }
    #pragma unroll
    for (int nt=0;nt<8;++nt){
      int col = nt*16 + g;
      float bb = b2eq[col];
      float q0=0.f,q1=0.f,q2=0.f;
      #pragma unroll
      for (int ms=0;ms<2;++ms)
        #pragma unroll
        for (int r=0;r<4;++r){
          int row = w*32 + ms*16 + r0 + r;
          float ym = (acc2[ms][nt][r] + bb) * scal[row][3];
          q0 = fmaf(ym, scal[row][0], q0);
          q1 = fmaf(ym, scal[row][1], q1);
          q2 = fmaf(ym, scal[row][2], q2);
        }
      q0 += __shfl_xor(q0,16); q0 += __shfl_xor(q0,32);
      q1 += __shfl_xor(q1,16); q1 += __shfl_xor(q1,32);
      q2 += __shfl_xor(q2,16); q2 += __shfl_xor(q2,32);
      if (l < 16){
        red[w][0*128+col] = q0; red[w][1*128+col] = q1; red[w][2*128+col] = q2;
      }
    }
  }
  __syncthreads();                           // B5: red complete; Ws/Hs free

  // ---- flush eqf: ef/s1 to registers, eqf_out to global ----
  float ef_reg[3], s1_reg[3];
  {
    int k = 0;
    for (int i=t; i<768; i+=256, ++k){
      int p = (i >= 384) ? 1 : 0;
      int j = i - p*384;
      float s1 = red[2*p][j] + red[2*p+1][j];
      size_t idx = (size_t)(a0+p)*384 + j;
      float ef = first ? s1 : (eqf_out[idx] + s1);
      eqf_out[idx] = ef;
      ef_reg[k] = ef; s1_reg[k] = s1;
    }
  }

  // ================= eme path =================
  if (!first){
    // ---- stage W1me -> Ws ----
    #pragma unroll
    for (int c=t; c<2048; c+=256){
      int row = c >> 4, ko = (c & 15) << 3;
      *(int4*)(&Ws[row*136 + ko]) = *(const int4*)(W1me + row*FF + ko);
    }
    __syncthreads();                         // B6
    #pragma unroll
    for (int ms=0;ms<2;++ms)
      #pragma unroll
      for (int nt=0;nt<8;++nt) acc2[ms][nt] = f32x4{0.f,0.f,0.f,0.f};
    #pragma unroll
    for (int nt=0;nt<8;++nt)
      #pragma unroll
      for (int ks=0;ks<4;++ks){
        bf16x8 wfr = *(const bf16x8*)(&Ws[(nt*16+g)*136 + ks*32 + kg]);
        #pragma unroll
        for (int ms=0;ms<2;++ms)
          acc2[ms][nt] = __builtin_amdgcn_mfma_f32_16x16x32_bf16(wfr, xf[ms][ks], acc2[ms][nt], 0,0,0);
      }
    #pragma unroll
    for (int ms=0;ms<2;++ms)
      #pragma unroll
      for (int nt=0;nt<8;++nt){
        int o0 = nt*16 + r0;
        uint2 u;
        u.x = pk2(silu_f(acc2[ms][nt][0]), silu_f(acc2[ms][nt][1]));
        u.y = pk2(silu_f(acc2[ms][nt][2]), silu_f(acc2[ms][nt][3]));
        *(uint2*)(&Hs[(w*32 + ms*16 + g)*136 + o0]) = u;
      }
    __syncthreads();                         // B7: Ws(W1me) reads done, Hs(H-eme) complete
    // ---- stage W2me -> Ws ----
    #pragma unroll
    for (int c=t; c<2048; c+=256){
      int row = c >> 4, ko = (c & 15) << 3;
      *(int4*)(&Ws[row*136 + ko]) = *(const int4*)(W2me + row*FF + ko);
    }
    __syncthreads();                         // B8
    bf16x8 hfr[2][4];
    #pragma unroll
    for (int ms=0;ms<2;++ms)
      #pragma unroll
      for (int ks=0;ks<4;++ks)
        hfr[ms][ks] = *(const bf16x8*)(&Hs[(w*32 + ms*16 + g)*136 + ks*32 + kg]);
    #pragma unroll
    for (int ms=0;ms<2;++ms)
      #pragma unroll
      for (int nt=0;nt<8;++nt) acc2[ms][nt] = f32x4{0.f,0.f,0.f,0.f};
    #pragma unroll
    for (int nt=0;nt<8;++nt)
      #pragma unroll
      for (int ks=0;ks<4;++ks){
        bf16x8 wfr = *(const bf16x8*)(&Ws[(nt*16+g)*136 + ks*32 + kg]);
        #pragma unroll
        for (int ms=0;ms<2;++ms)
          acc2[ms][nt] = __builtin_amdgcn_mfma_f32_16x16x32_bf16(hfr[ms][ks], wfr, acc2[ms][nt], 0,0,0);
      }
    #pragma unroll
    for (int nt=0;nt<8;++nt){
      int col = nt*16 + g;
      float q0=0.f,q1=0.f,q2=0.f;
      #pragma unroll
      for (int ms=0;ms<2;++ms)
        #pragma unroll
        for (int r=0;r<4;++r){
          int row = w*32 + ms*16 + r0 + r;
          float ym = acc2[ms][nt][r] * scal[row][3];
          float4 gv = *(const float4*)(eqdrT_prev + ((size_t)nbq[row]*FF + col)*4);
          q0 = fmaf(ym, gv.x, q0);
          q1 = fmaf(ym, gv.y, q1);
          q2 = fmaf(ym, gv.z, q2);
        }
      q0 += __shfl_xor(q0,16); q0 += __shfl_xor(q0,32);
      q1 += __shfl_xor(q1,16); q1 += __shfl_xor(q1,32);
      q2 += __shfl_xor(q2,16); q2 += __shfl_xor(q2,32);
      if (l < 16){
        red[w][0*128+col] = q0; red[w][1*128+col] = q1; red[w][2*128+col] = q2;
      }
    }
    __syncthreads();                         // B9: red(eme) complete
  }

  // ---- finalize: eqdr/eqdrT/prod (prod overlays red[2p]) ----
  {
    int k = 0;
    for (int i=t; i<768; i+=256, ++k){
      int p = (i >= 384) ? 1 : 0;
      int j = i - p*384;
      int o = j & 127;
      int c = j >> 7;
      float s2 = first ? 0.0f : (red[2*p][j] + red[2*p+1][j]);
      size_t idx = (size_t)(a0+p)*384 + j;
      float es = esu[(size_t)(a0+p)*FF + o];
      float v = (first ? 0.0f : eqdr[idx]) + s2 + es*s1_reg[k];
      eqdr[idx] = v;
      eqdrT_next[((size_t)(a0+p)*FF + o)*4 + c] = v;
      red[2*p][j] = ef_reg[k] * v;           // prod
    }
  }
  __syncthreads();                           // B10
  {
    int p = t >> 7, o = t & 127;
    float sum3 = red[2*p][o] + red[2*p][128+o] + red[2*p][256+o];
    size_t idx = (size_t)(a0+p)*FF + o;
    inv_node[idx] = fmaf(-isu[idx], sum3, inv_node[idx]);
  }
}

extern "C" void kernel_launch(void* const* d_in, const int* in_sizes, int n_in,
                              void* d_out, int out_size, void* d_ws, size_t ws_size,
                              hipStream_t stream){
  const int*   z     = (const int*)  d_in[0];
  const int*   nbrs  = (const int*)  d_in[2];
  const float* maskp = (const float*)d_in[3];
  const float* dist  = (const float*)d_in[4];
  const float* dvec  = (const float*)d_in[5];
  const float* emb   = (const float*)d_in[6];
  const float* me_W  = (const float*)d_in[7];
  const float* me_b  = (const float*)d_in[8];
  const float* mn_W1 = (const float*)d_in[9];
  const float* mn_b1 = (const float*)d_in[10];
  const float* mn_W2 = (const float*)d_in[11];
  const float* mn_b2 = (const float*)d_in[12];
  const float* eqc_W = (const float*)d_in[13];
  const float* eqf_W1= (const float*)d_in[14];
  const float* eqf_b1= (const float*)d_in[15];
  const float* eqf_W2= (const float*)d_in[16];
  const float* eqf_b2= (const float*)d_in[17];
  const float* esu_W1= (const float*)d_in[18];
  const float* esu_b1= (const float*)d_in[19];
  const float* esu_W2= (const float*)d_in[20];
  const float* esu_b2= (const float*)d_in[21];
  const float* eme_W1= (const float*)d_in[22];
  const float* eme_W2= (const float*)d_in[23];
  const float* isu_W1= (const float*)d_in[24];
  const float* isu_b1= (const float*)d_in[25];
  const float* isu_W2= (const float*)d_in[26];
  const float* isu_b2= (const float*)d_in[27];

  float* out      = (float*)d_out;
  float* inv_node = out;                        // BA*FF   = 131072
  float* eqF      = out + 131072;               // BA*3    = 3072
  float* eqf      = out + 134144;               // BA*3*FF = 393216
  float* eqdr     = out + 527360;               // BA*3*FF = 393216

  // workspace layout (floats)
  float* w        = (float*)d_ws;
  float* msg_node = w;                          //   131,072
  float* esu_o    = w + 131072;                 //   131,072
  float* isu_o    = w + 262144;                 //   131,072
  float* eqdrT_A  = w + 393216;                 //   524,288 (BA*FF*4)
  float* eqdrT_B  = w + 917504;                 //   524,288
  unsigned short* wbf = (unsigned short*)(w + 1441792); // 503,808 us

  k_cvtw<<<1968, 256, 0, stream>>>(eqf_W1, eqf_W2, eme_W1, eme_W2, me_W,
      mn_W1, mn_W2, esu_W1, esu_W2, isu_W1, isu_W2, wbf);

  const unsigned short* mnW1b0  = wbf + 208896;
  const unsigned short* mnW2b0  = wbf + 258048;
  const unsigned short* esW1b0  = wbf + 307200;
  const unsigned short* esW2b0  = wbf + 356352;
  const unsigned short* isW1b0  = wbf + 405504;
  const unsigned short* isW2b0  = wbf + 454656;

  k_node_mfma<<<dim3(BA/64, 3), 256, 0, stream>>>(nullptr, z, emb, inv_node,
      mnW1b0, mn_b1,  mnW2b0, mn_b2,  msg_node,
      esW1b0, esu_b1, esW2b0, esu_b2, esu_o,
      isW1b0, isu_b1, isW2b0, isu_b2, isu_o, 1);

  for (int l=0; l<NLAY; ++l){
    size_t oB = (size_t)l*FF;
    const unsigned short* eqfW1b = wbf + 0*49152 + l*16384;
    const unsigned short* eqfW2b = wbf + 1*49152 + l*16384;
    const unsigned short* emeW1b = wbf + 2*49152 + l*16384;
    const unsigned short* emeW2b = wbf + 3*49152 + l*16384;
    const unsigned short* meWb   = wbf + 196608  + l*4096;
    float* dT_prev = (l & 1) ? eqdrT_B : eqdrT_A;   // unused at l==0 (first)
    float* dT_next = (l & 1) ? eqdrT_A : eqdrT_B;
    int first = (l==0);

    k_layer<<<BA/2, 256, 0, stream>>>(dist, dvec, maskp, nbrs, msg_node,
        meWb, me_b+oB, eqc_W+oB,
        eqfW1b, eqf_b1+oB, emeW1b,
        eqfW2b, eqf_b2+oB, emeW2b,
        dT_prev, dT_next, esu_o, isu_o,
        eqF, eqf, eqdr, inv_node, first);
    if (l < NLAY-1){
      size_t oBn = (size_t)(l+1)*FF;
      k_node_mfma<<<dim3(BA/64, 3), 256, 0, stream>>>(inv_node, nullptr, nullptr, nullptr,
          mnW1b0 + (l+1)*16384, mn_b1+oBn,  mnW2b0 + (l+1)*16384, mn_b2+oBn,  msg_node,
          esW1b0 + (l+1)*16384, esu_b1+oBn, esW2b0 + (l+1)*16384, esu_b2+oBn, esu_o,
          isW1b0 + (l+1)*16384, isu_b1+oBn, isW2b0 + (l+1)*16384, isu_b2+oBn, isu_o, 0);
    }
  }
}

// Round 20
// 134.380 us; speedup vs baseline: 1.7895x; 1.0378x over previous
//
#include <hip/hip_runtime.h>
#include <cstdint>
#include <cstddef>

#define BB   4
#define AA   256
#define NNB  64
#define FF   128
#define NBAS 20
#define NLAY 3
#define BA   (BB*AA)        // 1024 atoms total
#define EDG  (BA*NNB)       // 65536 edges

typedef __attribute__((ext_vector_type(8))) short bf16x8;
typedef __attribute__((ext_vector_type(4))) float f32x4;

__device__ __forceinline__ float silu_f(float x){ return x / (1.0f + __expf(-x)); }

// round-to-nearest-even f32 -> bf16 bits (scalar path)
__device__ __forceinline__ unsigned short f2bf(float x){
  unsigned int u = __float_as_uint(x);
  u += 0x7FFFu + ((u >> 16) & 1u);
  return (unsigned short)(u >> 16);
}
// packed f32 pair -> 2x bf16 in one VALU op (gfx950 v_cvt_pk_bf16_f32)
__device__ __forceinline__ unsigned int pk2(float a, float b){
  unsigned int r;
  asm("v_cvt_pk_bf16_f32 %0, %1, %2" : "=v"(r) : "v"(a), "v"(b));
  return r;
}

// XOR-swizzled index into a linear [128][128]-ushort LDS tile.
// 16B-granular swizzle: ushort offset bits 3-5 ^= row bits 0-2.
__device__ __forceinline__ int swzi(int row, int us){
  return (row << 7) + (us ^ ((row & 7) << 3));
}

// ------------- weight conversion -------------
// Edge tiles (eqfW1,eqfW2,emeW1,emeW2) stored PRE-SWIZZLED so that a linear
// global_load_lds produces the swizzled LDS image (involution).
__global__ void k_cvtw(const float* __restrict__ a, const float* __restrict__ b,
                       const float* __restrict__ c, const float* __restrict__ d,
                       const float* __restrict__ me,
                       const float* __restrict__ mnW1, const float* __restrict__ mnW2,
                       const float* __restrict__ esW1, const float* __restrict__ esW2,
                       const float* __restrict__ isW1, const float* __restrict__ isW2,
                       unsigned short* __restrict__ out){
  int id = blockIdx.x*256 + threadIdx.x;
  if (id < 196608){
    int reg = id / 49152, off = id - reg*49152;
    const float* src = (reg==0)?a:(reg==1)?b:(reg==2)?c:d;
    int lay = off >> 14, us = off & 16383;
    int row = us >> 7, col = us & 127;
    out[id] = f2bf(src[(lay<<14) + (row<<7) + (col ^ ((row&7)<<3))]);
  } else if (id < 208896){
    int p = id - 196608;
    int l = p >> 12;            // layer
    int rem = p & 4095;
    int row = rem >> 5, k = rem & 31;
    float v = (k < NBAS) ? me[((size_t)l*FF + row)*NBAS + k] : 0.0f;
    out[id] = f2bf(v);
  } else if (id < 503808){
    int p = id - 208896;
    int mat = p / 49152, rem = p - mat*49152;
    const float* src = (mat==0)?mnW1:(mat==1)?mnW2:(mat==2)?esW1:(mat==3)?esW2:(mat==4)?isW1:isW2;
    out[id] = f2bf(src[rem]);
  }
}

// =====================================================================
// k_node_mfma: node MLPs via MFMA (R17-proven, unchanged). grid (BA/64,3).
// =====================================================================
__global__ __launch_bounds__(256) void k_node_mfma(
    const float* __restrict__ X, const int* __restrict__ z,
    const float* __restrict__ emb, float* __restrict__ inv_node,
    const unsigned short* W1a, const float* b1a, const unsigned short* W2a, const float* b2a, float* Ya,
    const unsigned short* W1b, const float* b1b, const unsigned short* W2b, const float* b2b, float* Yb,
    const unsigned short* W1c, const float* b1c, const unsigned short* W2c, const float* b2c, float* Yc,
    int do_emb){
  const unsigned short *W1,*W2; const float *b1,*b2; float* Y;
  if (blockIdx.y==0){ W1=W1a;b1=b1a;W2=W2a;b2=b2a;Y=Ya; }
  else if (blockIdx.y==1){ W1=W1b;b1=b1b;W2=W2b;b2=b2b;Y=Yb; }
  else { W1=W1c;b1=b1c;W2=W2c;b2=b2c;Y=Yc; }
  __shared__ unsigned short Ws[128*136];     // 34.8 KB
  __shared__ unsigned short Xs[64*136];      // 17.4 KB (X, then H)
  const int t = threadIdx.x, w = t>>6, l = t&63;
  const int g = l&15, kg = (l>>4)<<3, r0 = (l>>4)<<2;
  const int gr0 = blockIdx.x*64;
  const int le = w*16 + g;

  {
    int row = t>>2, c0 = (t&3)*32;
    const float* src = do_emb ? (emb + (size_t)z[gr0+row]*FF + c0)
                              : (X   + (size_t)(gr0+row)*FF + c0);
    #pragma unroll
    for (int j=0;j<8;++j){
      float4 v = *(const float4*)(src + j*4);
      if (do_emb && blockIdx.y==0)
        *(float4*)(inv_node + (size_t)(gr0+row)*FF + c0 + j*4) = v;
      uint2 u; u.x = pk2(v.x,v.y); u.y = pk2(v.z,v.w);
      *(uint2*)(&Xs[row*136 + c0 + j*4]) = u;
    }
  }
  #pragma unroll
  for (int c=t; c<2048; c+=256){
    int row = c >> 4, ko = (c & 15) << 3;
    *(int4*)(&Ws[row*136 + ko]) = *(const int4*)(W1 + row*FF + ko);
  }
  __syncthreads();
  bf16x8 xf[4];
  #pragma unroll
  for (int ks=0;ks<4;++ks) xf[ks] = *(const bf16x8*)(&Xs[le*136 + ks*32 + kg]);
  __syncthreads();
  f32x4 acc[8];
  #pragma unroll
  for (int nt=0;nt<8;++nt) acc[nt] = f32x4{0.f,0.f,0.f,0.f};
  #pragma unroll
  for (int nt=0;nt<8;++nt)
    #pragma unroll
    for (int ks=0;ks<4;++ks){
      bf16x8 wfr = *(const bf16x8*)(&Ws[(nt*16+g)*136 + ks*32 + kg]);
      acc[nt] = __builtin_amdgcn_mfma_f32_16x16x32_bf16(wfr, xf[ks], acc[nt], 0,0,0);
    }
  #pragma unroll
  for (int nt=0;nt<8;++nt){
    int o0 = nt*16 + r0;
    float4 bb = *(const float4*)(b1 + o0);
    uint2 u;
    u.x = pk2(silu_f(acc[nt][0]+bb.x), silu_f(acc[nt][1]+bb.y));
    u.y = pk2(silu_f(acc[nt][2]+bb.z), silu_f(acc[nt][3]+bb.w));
    *(uint2*)(&Xs[le*136 + o0]) = u;
  }
  __syncthreads();
  #pragma unroll
  for (int c=t; c<2048; c+=256){
    int row = c >> 4, ko = (c & 15) << 3;
    *(int4*)(&Ws[row*136 + ko]) = *(const int4*)(W2 + row*FF + ko);
  }
  __syncthreads();
  bf16x8 hf[4];
  #pragma unroll
  for (int ks=0;ks<4;++ks) hf[ks] = *(const bf16x8*)(&Xs[le*136 + ks*32 + kg]);
  #pragma unroll
  for (int nt=0;nt<8;++nt) acc[nt] = f32x4{0.f,0.f,0.f,0.f};
  #pragma unroll
  for (int nt=0;nt<8;++nt)
    #pragma unroll
    for (int ks=0;ks<4;++ks){
      bf16x8 wfr = *(const bf16x8*)(&Ws[(nt*16+g)*136 + ks*32 + kg]);
      acc[nt] = __builtin_amdgcn_mfma_f32_16x16x32_bf16(wfr, hf[ks], acc[nt], 0,0,0);
    }
  #pragma unroll
  for (int nt=0;nt<8;++nt){
    int o0 = nt*16 + r0;
    float4 bb = *(const float4*)(b2 + o0);
    float4 o;
    o.x = acc[nt][0]+bb.x; o.y = acc[nt][1]+bb.y;
    o.z = acc[nt][2]+bb.z; o.w = acc[nt][3]+bb.w;
    *(float4*)(Y + (size_t)(gr0 + le)*FF + o0) = o;
  }
}

// =====================================================================
// k_layer: H-in-LDS edge pipeline with DMA W staging.
// Tiles are linear [128][128] ushorts + XOR swizzle; the four W matrices
// are pre-swizzled in global, loaded via __builtin_amdgcn_global_load_lds
// (linear dest), and all LDS reads/writes apply swzi().
// Buffer roles: Ws: inv_msg -> H(eqf) -> W1me -> W2me
//               Hs: W1eq   -> W2eq   -> H(eme)
// DMAs issue one phase early and drain under epilogue/flush work.
// =====================================================================
__device__ __forceinline__ void stage_dma(const unsigned short* Gsw,
                                          unsigned short* buf, int w, int l){
  const char* g = (const char*)Gsw;
  char* bp = (char*)buf;
  #pragma unroll
  for (int i=0;i<8;++i){
    __builtin_amdgcn_global_load_lds(
        (const void*)(g + w*8192 + i*1024 + l*16),
        (void*)(bp + w*8192 + i*1024), 16, 0, 0);
  }
}

__global__ __launch_bounds__(256) void k_layer(
    const float* __restrict__ dist, const float* __restrict__ dvec,
    const float* __restrict__ maskp, const int* __restrict__ nbrs,
    const float* __restrict__ msg_node,
    const unsigned short* __restrict__ meWb, const float* __restrict__ meb,
    const float* __restrict__ eqcW,
    const unsigned short* __restrict__ W1eq, const float* __restrict__ b1eq,
    const unsigned short* __restrict__ W1me,
    const unsigned short* __restrict__ W2eq, const float* __restrict__ b2eq,
    const unsigned short* __restrict__ W2me,
    const float* __restrict__ eqdrT_prev, float* __restrict__ eqdrT_next,
    const float* __restrict__ esu, const float* __restrict__ isu,
    float* __restrict__ eqF, float* __restrict__ eqf_out,
    float* __restrict__ eqdr, float* __restrict__ inv_node, int first){
  __shared__ unsigned short Ws[128*128];     // 32 KB
  __shared__ unsigned short Hs[128*128];     // 32 KB
  __shared__ float scal[128][4];
  __shared__ int   nbq[128];
  __shared__ float red[4][384];
  __shared__ float eqFred[4][2][3];
  const int t = threadIdx.x, w = t>>6, l = t&63;
  const int bid = blockIdx.x, a0 = bid*2;
  const int g = l&15, kg = (l>>4)<<3, r0 = (l>>4)<<2;
  const float c5 = 0.6283185307179586f;      // pi/5

  // ---- entry: DMA W1eq -> Hs (drains at B1, hidden under phase A) ----
  stage_dma(W1eq, Hs, w, l);
  if (t < 128){
    int e2 = a0*NNB + t;
    int atomt = a0 + (t>>6);
    nbq[t] = (atomt/AA)*AA + nbrs[e2];
  }

  // ---------------- phase A: geometry + me-MLP + inv_msg -> Ws, scal, eqF ----------------
  #pragma unroll
  for (int p=0;p<2;++p){
    const int atom = a0 + p;
    const int eg = atom*NNB + w*16 + g;
    const float d = dist[eg];
    const float dinv = 1.0f/(d + 1e-8f);
    const float xx = d*0.2f;
    float x2=xx*xx, x4=x2*x2, x6=x4*x2, x7=x6*xx, x8=x7*xx;
    float ct = 1.0f - 28.0f*x6 + 48.0f*x7 - 21.0f*x8;
    ct = (xx < 1.0f) ? ct : 0.0f;
    bf16x8 rfr;
    #pragma unroll
    for (int i=0;i<8;++i){
      int k = kg + i;
      float v = (k < NBAS) ? __sinf((float)(k+1)*c5*d)*dinv : 0.0f;
      rfr[i] = (short)f2bf(v);
    }
    f32x4 acc[8];
    #pragma unroll
    for (int nt=0;nt<8;++nt){
      bf16x8 wfr = *(const bf16x8*)(meWb + (nt*16 + g)*32 + kg);
      acc[nt] = __builtin_amdgcn_mfma_f32_16x16x32_bf16(wfr, rfr, f32x4{0.f,0.f,0.f,0.f}, 0,0,0);
    }
    const int bbase = (atom/AA)*AA;
    const int nbv = bbase + nbrs[eg];
    float pv = 0.f;
    #pragma unroll
    for (int nt=0;nt<8;++nt){
      int o0 = nt*16 + r0;
      float4 mb = *(const float4*)(meb + o0);
      float4 mi = *(const float4*)(msg_node + (size_t)atom*FF + o0);
      float4 mf = *(const float4*)(msg_node + (size_t)nbv*FF + o0);
      float4 ec = *(const float4*)(eqcW + o0);
      float v0 = (acc[nt][0]+mb.x)*ct*mi.x*mf.x;
      float v1 = (acc[nt][1]+mb.y)*ct*mi.y*mf.y;
      float v2 = (acc[nt][2]+mb.z)*ct*mi.z*mf.z;
      float v3 = (acc[nt][3]+mb.w)*ct*mi.w*mf.w;
      pv = fmaf(v0,ec.x, fmaf(v1,ec.y, fmaf(v2,ec.z, fmaf(v3,ec.w, pv))));
      uint2 u; u.x = pk2(v0,v1); u.y = pk2(v2,v3);
      *(uint2*)(&Ws[swzi(p*64 + w*16 + g, o0)]) = u;
    }
    pv += __shfl_xor(pv,16); pv += __shfl_xor(pv,32);
    float cf0=0.f, cf1=0.f, cf2=0.f;
    if (l < 16){
      float m  = maskp[eg];
      float s0 = pv*dvec[(size_t)eg*3+0]*dinv;
      float s1 = pv*dvec[(size_t)eg*3+1]*dinv;
      float s2 = pv*dvec[(size_t)eg*3+2]*dinv;
      int lr = p*64 + w*16 + g;
      scal[lr][0]=s0; scal[lr][1]=s1; scal[lr][2]=s2; scal[lr][3]=m;
      cf0 = s0*m; cf1 = s1*m; cf2 = s2*m;
    }
    #pragma unroll
    for (int s2=1; s2<16; s2<<=1){
      cf0 += __shfl_xor(cf0,s2); cf1 += __shfl_xor(cf1,s2); cf2 += __shfl_xor(cf2,s2);
    }
    if (l == 0){ eqFred[w][p][0]=cf0; eqFred[w][p][1]=cf1; eqFred[w][p][2]=cf2; }
  }
  __syncthreads();                           // B1: Ws(inv_msg)/scal + Hs(W1eq DMA) done

  // X fragments -> registers; eq_F write
  bf16x8 xf[2][4];
  #pragma unroll
  for (int ms=0;ms<2;++ms)
    #pragma unroll
    for (int ks=0;ks<4;++ks)
      xf[ms][ks] = *(const bf16x8*)(&Ws[swzi(w*32 + ms*16 + g, ks*32 + kg)]);
  if (t < 6){
    int p = t/3, c = t - p*3;
    float s = eqFred[0][p][c]+eqFred[1][p][c]+eqFred[2][p][c]+eqFred[3][p][c];
    eqF[(a0+p)*3 + c] = first ? s : (eqF[(a0+p)*3 + c] + s);
  }
  __syncthreads();                           // B2: Ws free (xf extracted)

  // ---- GEMM1-eqf: W from Hs ----
  f32x4 acc2[2][8];
  #pragma unroll
  for (int ms=0;ms<2;++ms)
    #pragma unroll
    for (int nt=0;nt<8;++nt) acc2[ms][nt] = f32x4{0.f,0.f,0.f,0.f};
  #pragma unroll
  for (int nt=0;nt<8;++nt)
    #pragma unroll
    for (int ks=0;ks<4;++ks){
      bf16x8 wfr = *(const bf16x8*)(&Hs[swzi(nt*16+g, ks*32+kg)]);
      #pragma unroll
      for (int ms=0;ms<2;++ms)
        acc2[ms][nt] = __builtin_amdgcn_mfma_f32_16x16x32_bf16(wfr, xf[ms][ks], acc2[ms][nt], 0,0,0);
    }
  __syncthreads();                           // B3: all waves done reading Hs(W1eq)
  stage_dma(W2eq, Hs, w, l);                 // async; drains under epilogue
  #pragma unroll
  for (int ms=0;ms<2;++ms)
    #pragma unroll
    for (int nt=0;nt<8;++nt){
      int o0 = nt*16 + r0;
      float4 bb = *(const float4*)(b1eq + o0);
      uint2 u;
      u.x = pk2(silu_f(acc2[ms][nt][0]+bb.x), silu_f(acc2[ms][nt][1]+bb.y));
      u.y = pk2(silu_f(acc2[ms][nt][2]+bb.z), silu_f(acc2[ms][nt][3]+bb.w));
      *(uint2*)(&Ws[swzi(w*32 + ms*16 + g, o0)]) = u;
    }
  __syncthreads();                           // B4: Ws(H) + Hs(W2eq DMA) complete

  // ---- GEMM2-eqf + masked scal reduce -> red ----
  {
    bf16x8 hfr[2][4];
    #pragma unroll
    for (int ms=0;ms<2;++ms)
      #pragma unroll
      for (int ks=0;ks<4;++ks)
        hfr[ms][ks] = *(const bf16x8*)(&Ws[swzi(w*32 + ms*16 + g, ks*32 + kg)]);
    #pragma unroll
    for (int ms=0;ms<2;++ms)
      #pragma unroll
      for (int nt=0;nt<8;++nt) acc2[ms][nt] = f32x4{0.f,0.f,0.f,0.f};
    #pragma unroll
    for (int nt=0;nt<8;++nt)
      #pragma unroll
      for (int ks=0;ks<4;++ks){
        bf16x8 wfr = *(const bf16x8*)(&Hs[swzi(nt*16+g, ks*32+kg)]);
        #pragma unroll
        for (int ms=0;ms<2;++ms)
          acc2[ms][nt] = __builtin_amdgcn_mfma_f32_16x16x32_bf16(hfr[ms][ks], wfr, acc2[ms][nt], 0,0,0);
      }
    #pragma unroll
    for (int nt=0;nt<8;++nt){
      int col = nt*16 + g;
      float bb = b2eq[col];
      float q0=0.f,q1=0.f,q2=0.f;
      #pragma unroll
      for (int ms=0;ms<2;++ms)
        #pragma unroll
        for (int r=0;r<4;++r){
          int row = w*32 + ms*16 + r0 + r;
          float ym = (acc2[ms][nt][r] + bb) * scal[row][3];
          q0 = fmaf(ym, scal[row][0], q0);
          q1 = fmaf(ym, scal[row][1], q1);
          q2 = fmaf(ym, scal[row][2], q2);
        }
      q0 += __shfl_xor(q0,16); q0 += __shfl_xor(q0,32);
      q1 += __shfl_xor(q1,16); q1 += __shfl_xor(q1,32);
      q2 += __shfl_xor(q2,16); q2 += __shfl_xor(q2,32);
      if (l < 16){
        red[w][0*128+col] = q0; red[w][1*128+col] = q1; red[w][2*128+col] = q2;
      }
    }
  }
  __syncthreads();                           // B5: red complete; Ws/Hs free

  if (!first) stage_dma(W1me, Ws, w, l);     // async; drains under flush

  // ---- flush eqf: ef/s1 to registers, eqf_out to global ----
  float ef_reg[3], s1_reg[3];
  {
    int k = 0;
    for (int i=t; i<768; i+=256, ++k){
      int p = (i >= 384) ? 1 : 0;
      int j = i - p*384;
      float s1 = red[2*p][j] + red[2*p+1][j];
      size_t idx = (size_t)(a0+p)*384 + j;
      float ef = first ? s1 : (eqf_out[idx] + s1);
      eqf_out[idx] = ef;
      ef_reg[k] = ef; s1_reg[k] = s1;
    }
  }
  __syncthreads();                           // B6: red reads done; Ws(W1me DMA) complete

  // ================= eme path =================
  if (!first){
    #pragma unroll
    for (int ms=0;ms<2;++ms)
      #pragma unroll
      for (int nt=0;nt<8;++nt) acc2[ms][nt] = f32x4{0.f,0.f,0.f,0.f};
    #pragma unroll
    for (int nt=0;nt<8;++nt)
      #pragma unroll
      for (int ks=0;ks<4;++ks){
        bf16x8 wfr = *(const bf16x8*)(&Ws[swzi(nt*16+g, ks*32+kg)]);
        #pragma unroll
        for (int ms=0;ms<2;++ms)
          acc2[ms][nt] = __builtin_amdgcn_mfma_f32_16x16x32_bf16(wfr, xf[ms][ks], acc2[ms][nt], 0,0,0);
      }
    __syncthreads();                         // B7: Ws(W1me) reads done
    stage_dma(W2me, Ws, w, l);               // async; drains under epilogue
    #pragma unroll
    for (int ms=0;ms<2;++ms)
      #pragma unroll
      for (int nt=0;nt<8;++nt){
        int o0 = nt*16 + r0;
        uint2 u;
        u.x = pk2(silu_f(acc2[ms][nt][0]), silu_f(acc2[ms][nt][1]));
        u.y = pk2(silu_f(acc2[ms][nt][2]), silu_f(acc2[ms][nt][3]));
        *(uint2*)(&Hs[swzi(w*32 + ms*16 + g, o0)]) = u;
      }
    __syncthreads();                         // B8: Hs(H-eme) + Ws(W2me DMA) complete
    bf16x8 hfr[2][4];
    #pragma unroll
    for (int ms=0;ms<2;++ms)
      #pragma unroll
      for (int ks=0;ks<4;++ks)
        hfr[ms][ks] = *(const bf16x8*)(&Hs[swzi(w*32 + ms*16 + g, ks*32 + kg)]);
    #pragma unroll
    for (int ms=0;ms<2;++ms)
      #pragma unroll
      for (int nt=0;nt<8;++nt) acc2[ms][nt] = f32x4{0.f,0.f,0.f,0.f};
    #pragma unroll
    for (int nt=0;nt<8;++nt)
      #pragma unroll
      for (int ks=0;ks<4;++ks){
        bf16x8 wfr = *(const bf16x8*)(&Ws[swzi(nt*16+g, ks*32+kg)]);
        #pragma unroll
        for (int ms=0;ms<2;++ms)
          acc2[ms][nt] = __builtin_amdgcn_mfma_f32_16x16x32_bf16(hfr[ms][ks], wfr, acc2[ms][nt], 0,0,0);
      }
    #pragma unroll
    for (int nt=0;nt<8;++nt){
      int col = nt*16 + g;
      float q0=0.f,q1=0.f,q2=0.f;
      #pragma unroll
      for (int ms=0;ms<2;++ms)
        #pragma unroll
        for (int r=0;r<4;++r){
          int row = w*32 + ms*16 + r0 + r;
          float ym = acc2[ms][nt][r] * scal[row][3];
          float4 gv = *(const float4*)(eqdrT_prev + ((size_t)nbq[row]*FF + col)*4);
          q0 = fmaf(ym, gv.x, q0);
          q1 = fmaf(ym, gv.y, q1);
          q2 = fmaf(ym, gv.z, q2);
        }
      q0 += __shfl_xor(q0,16); q0 += __shfl_xor(q0,32);
      q1 += __shfl_xor(q1,16); q1 += __shfl_xor(q1,32);
      q2 += __shfl_xor(q2,16); q2 += __shfl_xor(q2,32);
      if (l < 16){
        red[w][0*128+col] = q0; red[w][1*128+col] = q1; red[w][2*128+col] = q2;
      }
    }
    __syncthreads();                         // B9: red(eme) complete
  }

  // ---- finalize: eqdr/eqdrT/prod (prod overlays red[2p]) ----
  {
    int k = 0;
    for (int i=t; i<768; i+=256, ++k){
      int p = (i >= 384) ? 1 : 0;
      int j = i - p*384;
      int o = j & 127;
      int c = j >> 7;
      float s2 = first ? 0.0f : (red[2*p][j] + red[2*p+1][j]);
      size_t idx = (size_t)(a0+p)*384 + j;
      float es = esu[(size_t)(a0+p)*FF + o];
      float v = (first ? 0.0f : eqdr[idx]) + s2 + es*s1_reg[k];
      eqdr[idx] = v;
      eqdrT_next[((size_t)(a0+p)*FF + o)*4 + c] = v;
      red[2*p][j] = ef_reg[k] * v;           // prod
    }
  }
  __syncthreads();                           // B10
  {
    int p = t >> 7, o = t & 127;
    float sum3 = red[2*p][o] + red[2*p][128+o] + red[2*p][256+o];
    size_t idx = (size_t)(a0+p)*FF + o;
    inv_node[idx] = fmaf(-isu[idx], sum3, inv_node[idx]);
  }
}

extern "C" void kernel_launch(void* const* d_in, const int* in_sizes, int n_in,
                              void* d_out, int out_size, void* d_ws, size_t ws_size,
                              hipStream_t stream){
  const int*   z     = (const int*)  d_in[0];
  const int*   nbrs  = (const int*)  d_in[2];
  const float* maskp = (const float*)d_in[3];
  const float* dist  = (const float*)d_in[4];
  const float* dvec  = (const float*)d_in[5];
  const float* emb   = (const float*)d_in[6];
  const float* me_W  = (const float*)d_in[7];
  const float* me_b  = (const float*)d_in[8];
  const float* mn_W1 = (const float*)d_in[9];
  const float* mn_b1 = (const float*)d_in[10];
  const float* mn_W2 = (const float*)d_in[11];
  const float* mn_b2 = (const float*)d_in[12];
  const float* eqc_W = (const float*)d_in[13];
  const float* eqf_W1= (const float*)d_in[14];
  const float* eqf_b1= (const float*)d_in[15];
  const float* eqf_W2= (const float*)d_in[16];
  const float* eqf_b2= (const float*)d_in[17];
  const float* esu_W1= (const float*)d_in[18];
  const float* esu_b1= (const float*)d_in[19];
  const float* esu_W2= (const float*)d_in[20];
  const float* esu_b2= (const float*)d_in[21];
  const float* eme_W1= (const float*)d_in[22];
  const float* eme_W2= (const float*)d_in[23];
  const float* isu_W1= (const float*)d_in[24];
  const float* isu_b1= (const float*)d_in[25];
  const float* isu_W2= (const float*)d_in[26];
  const float* isu_b2= (const float*)d_in[27];

  float* out      = (float*)d_out;
  float* inv_node = out;                        // BA*FF   = 131072
  float* eqF      = out + 131072;               // BA*3    = 3072
  float* eqf      = out + 134144;               // BA*3*FF = 393216
  float* eqdr     = out + 527360;               // BA*3*FF = 393216

  // workspace layout (floats)
  float* w        = (float*)d_ws;
  float* msg_node = w;                          //   131,072
  float* esu_o    = w + 131072;                 //   131,072
  float* isu_o    = w + 262144;                 //   131,072
  float* eqdrT_A  = w + 393216;                 //   524,288 (BA*FF*4)
  float* eqdrT_B  = w + 917504;                 //   524,288
  unsigned short* wbf = (unsigned short*)(w + 1441792); // 503,808 us

  k_cvtw<<<1968, 256, 0, stream>>>(eqf_W1, eqf_W2, eme_W1, eme_W2, me_W,
      mn_W1, mn_W2, esu_W1, esu_W2, isu_W1, isu_W2, wbf);

  const unsigned short* mnW1b0  = wbf + 208896;
  const unsigned short* mnW2b0  = wbf + 258048;
  const unsigned short* esW1b0  = wbf + 307200;
  const unsigned short* esW2b0  = wbf + 356352;
  const unsigned short* isW1b0  = wbf + 405504;
  const unsigned short* isW2b0  = wbf + 454656;

  k_node_mfma<<<dim3(BA/64, 3), 256, 0, stream>>>(nullptr, z, emb, inv_node,
      mnW1b0, mn_b1,  mnW2b0, mn_b2,  msg_node,
      esW1b0, esu_b1, esW2b0, esu_b2, esu_o,
      isW1b0, isu_b1, isW2b0, isu_b2, isu_o, 1);

  for (int l=0; l<NLAY; ++l){
    size_t oB = (size_t)l*FF;
    const unsigned short* eqfW1b = wbf + 0*49152 + l*16384;
    const unsigned short* eqfW2b = wbf + 1*49152 + l*16384;
    const unsigned short* emeW1b = wbf + 2*49152 + l*16384;
    const unsigned short* emeW2b = wbf + 3*49152 + l*16384;
    const unsigned short* meWb   = wbf + 196608  + l*4096;
    float* dT_prev = (l & 1) ? eqdrT_B : eqdrT_A;   // unused at l==0 (first)
    float* dT_next = (l & 1) ? eqdrT_A : eqdrT_B;
    int first = (l==0);

    k_layer<<<BA/2, 256, 0, stream>>>(dist, dvec, maskp, nbrs, msg_node,
        meWb, me_b+oB, eqc_W+oB,
        eqfW1b, eqf_b1+oB, emeW1b,
        eqfW2b, eqf_b2+oB, emeW2b,
        dT_prev, dT_next, esu_o, isu_o,
        eqF, eqf, eqdr, inv_node, first);
    if (l < NLAY-1){
      size_t oBn = (size_t)(l+1)*FF;
      k_node_mfma<<<dim3(BA/64, 3), 256, 0, stream>>>(inv_node, nullptr, nullptr, nullptr,
          mnW1b0 + (l+1)*16384, mn_b1+oBn,  mnW2b0 + (l+1)*16384, mn_b2+oBn,  msg_node,
          esW1b0 + (l+1)*16384, esu_b1+oBn, esW2b0 + (l+1)*16384, esu_b2+oBn, esu_o,
          isW1b0 + (l+1)*16384, isu_b1+oBn, isW2b0 + (l+1)*16384, isu_b2+oBn, isu_o, 0);
    }
  }
}